// Round 2
// baseline (2392.895 us; speedup 1.0000x reference)
//
#include <hip/hip_runtime.h>
#include <hip/hip_bf16.h>

typedef long long ll;
static inline int cdiv(int a, int b) { return (a + b - 1) / b; }

__device__ __forceinline__ float ldf(const float* p) { return *p; }
__device__ __forceinline__ float ldf(const __hip_bfloat16* p) { return __bfloat162float(*p); }
__device__ __forceinline__ void stf(float* p, float v) { *p = v; }
__device__ __forceinline__ void stf(__hip_bfloat16* p, float v) { *p = __float2bfloat16(v); }

// ---------------- histogram of x over V bins ----------------
__global__ void k_hist_x(const int* __restrict__ x, int N, int* __restrict__ cnt, int V) {
    __shared__ int lc[128];
    for (int i = threadIdx.x; i < V; i += blockDim.x) lc[i] = 0;
    __syncthreads();
    int stride = gridDim.x * blockDim.x;
    for (int i = blockIdx.x * blockDim.x + threadIdx.x; i < N; i += stride)
        atomicAdd(&lc[x[i]], 1);
    __syncthreads();
    for (int i = threadIdx.x; i < V; i += blockDim.x) atomicAdd(&cnt[i], lc[i]);
}

// ------- exact GraphNorm0 from histogram + fold into W1: H1pre = T0 @ W1 -------
__global__ void k_table(const int* __restrict__ cnt, const float* __restrict__ emb,
                        const float* __restrict__ n0a, const float* __restrict__ n0g,
                        const float* __restrict__ n0b, const float* __restrict__ W1,
                        float* __restrict__ H1pre, int N, int V) {
    __shared__ float T0[101 * 64];
    __shared__ float W1l[64 * 64];
    __shared__ float A0[64], B0[64];
    __shared__ float rs[256], rq[256];
    __shared__ float cf[128];
    int t = threadIdx.x;
    for (int i = t; i < V; i += 256) cf[i] = (float)cnt[i];
    __syncthreads();
    int d = t & 63, g = t >> 6;
    float s = 0.f, q = 0.f;
    for (int v = g; v < V; v += 4) {
        float c = cf[v]; float e = emb[v * 64 + d];
        s += c * e; q += c * e * e;
    }
    rs[t] = s; rq[t] = q;
    __syncthreads();
    if (t < 64) {
        float sum = rs[t] + rs[t + 64] + rs[t + 128] + rs[t + 192];
        float sq  = rq[t] + rq[t + 64] + rq[t + 128] + rq[t + 192];
        float invN = 1.0f / (float)N;
        float m = sum * invN;
        float a = n0a[t];
        float var = sq * invN - (2.0f * a - a * a) * m * m;
        float A = n0g[t] * rsqrtf(var + 1e-5f);
        A0[t] = A; B0[t] = n0b[t] - A * a * m;
    }
    __syncthreads();
    for (int i = t; i < V * 64; i += 256) {
        int dd = i & 63;
        T0[i] = A0[dd] * emb[i] + B0[dd];
    }
    for (int i = t; i < 64 * 64; i += 256) W1l[i] = W1[i];
    __syncthreads();
    for (int o = t; o < V * 64; o += 256) {
        int v = o >> 6, dd = o & 63;
        float acc = 0.f;
#pragma unroll 8
        for (int k = 0; k < 64; ++k) acc += T0[v * 64 + k] * W1l[k * 64 + dd];
        H1pre[o] = acc;
    }
}

// ---------------- degree histogram over dst ----------------
__global__ void k_deg(const int* __restrict__ dst, int E, int* __restrict__ deg) {
    int stride = gridDim.x * blockDim.x;
    for (int e = blockIdx.x * blockDim.x + threadIdx.x; e < E; e += stride)
        atomicAdd(&deg[dst[e]], 1);
}

// ---------------- 3-kernel exclusive scan (2048 elems/block) ----------------
__global__ void k_scan1(const int* __restrict__ in, int* __restrict__ out,
                        int* __restrict__ bsum, int M) {
    __shared__ int ts[256];
    int t = threadIdx.x;
    int base = blockIdx.x * 2048 + t * 8;
    int v[8]; int s = 0;
#pragma unroll
    for (int j = 0; j < 8; ++j) { int idx = base + j; int val = (idx < M) ? in[idx] : 0; v[j] = val; s += val; }
    ts[t] = s; __syncthreads();
    for (int off = 1; off < 256; off <<= 1) {
        int xv = 0;
        if (t >= off) xv = ts[t - off];
        __syncthreads();
        ts[t] += xv;
        __syncthreads();
    }
    int incl = ts[t];
    int excl = incl - s;
    if (t == 255) bsum[blockIdx.x] = incl;
    int run = excl;
#pragma unroll
    for (int j = 0; j < 8; ++j) { int idx = base + j; if (idx < M) out[idx] = run; run += v[j]; }
}

__global__ void k_scan2(int* bsum, int nb) {
    if (threadIdx.x == 0 && blockIdx.x == 0) {
        int acc = 0;
        for (int i = 0; i < nb; ++i) { int v = bsum[i]; bsum[i] = acc; acc += v; }
        bsum[nb] = acc;
    }
}

__global__ void k_scan3(int* __restrict__ rp, int* __restrict__ cur,
                        const int* __restrict__ bsum, int M, int nb) {
    int stride = gridDim.x * blockDim.x;
    for (int i = blockIdx.x * blockDim.x + threadIdx.x; i < M; i += stride) {
        int v = rp[i] + bsum[i >> 11];
        rp[i] = v; cur[i] = v;
    }
    if (blockIdx.x == 0 && threadIdx.x == 0) rp[M] = bsum[nb];
}

// ---------------- CSR fill (store src per dst-bucket) ----------------
__global__ void k_fill(const int* __restrict__ src, const int* __restrict__ dst, int E,
                       int* __restrict__ cur, int* __restrict__ csr) {
    int stride = gridDim.x * blockDim.x;
    for (int e = blockIdx.x * blockDim.x + threadIdx.x; e < E; e += stride) {
        int d = dst[e];
        int p = atomicAdd(&cur[d], 1);
        csr[p] = src[e];
    }
}

// ------- conv1 aggregation: wave/node (grid-stride), 101x64 table in LDS -------
template <typename TO>
__global__ void k_conv1(const int* __restrict__ x, const int* __restrict__ rp,
                        const int* __restrict__ deg, const int* __restrict__ csr,
                        const float* __restrict__ H1pre, const float* __restrict__ b1,
                        TO* __restrict__ out1, int N, int V) {
    __shared__ float Hl[101 * 64];
    for (int i = threadIdx.x; i < V * 64; i += blockDim.x) Hl[i] = H1pre[i];
    __syncthreads();
    int wid = threadIdx.x >> 6, lane = threadIdx.x & 63;
    for (int node = blockIdx.x * 4 + wid; node < N; node += gridDim.x * 4) {
        int rs = rp[node], re = rp[node + 1];
        float acc = 0.f;
        for (int c = rs; c < re; c += 64) {
            int e = c + lane;
            int sv = 0; float dv = 0.f; int xv = 0;
            if (e < re) {
                sv = csr[e];
                xv = x[sv];
                dv = rsqrtf((float)deg[sv] + 1.0f);
            }
            int cnt = min(64, re - c);
            for (int j = 0; j < cnt; ++j) {
                int   xb = __shfl(xv, j);
                float wb = __shfl(dv, j);
                acc += wb * Hl[xb * 64 + lane];
            }
        }
        float degf = (float)(re - rs) + 1.0f;
        int xi = x[node];
        float val = rsqrtf(degf) * acc + Hl[xi * 64 + lane] * (1.0f / degf) + b1[lane];
        stf(&out1[(ll)node * 64 + lane], val);
    }
}

// ---------------- per-feature sum / sumsq over M x 64 ----------------
template <typename TO>
__global__ void k_stats(const TO* __restrict__ mat, int M,
                        float* __restrict__ gsum, float* __restrict__ gsq) {
    __shared__ float rs[256], rq[256];
    int t = threadIdx.x, d = t & 63, g = t >> 6;
    float s = 0.f, q = 0.f;
    for (int i = blockIdx.x * 4 + g; i < M; i += gridDim.x * 4) {
        float v = ldf(&mat[(ll)i * 64 + d]);
        s += v; q += v * v;
    }
    rs[t] = s; rq[t] = q; __syncthreads();
    if (t < 64) {
        atomicAdd(&gsum[t], rs[t] + rs[t + 64] + rs[t + 128] + rs[t + 192]);
        atomicAdd(&gsq[t],  rq[t] + rq[t + 64] + rq[t + 128] + rq[t + 192]);
    }
}

__global__ void k_norm_final(const float* __restrict__ gsum, const float* __restrict__ gsq,
                             const float* __restrict__ na, const float* __restrict__ ng,
                             const float* __restrict__ nbb,
                             float* __restrict__ A, float* __restrict__ B, int M) {
    int t = threadIdx.x;
    if (t < 64) {
        float invM = 1.0f / (float)M;
        float m = gsum[t] * invM;
        float a = na[t];
        float var = gsq[t] * invM - (2.0f * a - a * a) * m * m;
        float Av = ng[t] * rsqrtf(var + 1e-5f);
        A[t] = Av; B[t] = nbb[t] - Av * a * m;
    }
}

// ------- fused: h2pre[l] = relu(norm1(h1[p0])) @ W2_top + relu(norm1(h1[p1])) @ W2_bot -------
template <typename TO, typename TH>
__global__ void k_h2(const int* __restrict__ pos1, const TO* __restrict__ out1,
                     const float* __restrict__ A, const float* __restrict__ B,
                     const float* __restrict__ W2, TH* __restrict__ h2p, int L) {
    __shared__ float Wl[128 * 64];
    for (int i = threadIdx.x; i < 128 * 64; i += blockDim.x) Wl[i] = W2[i];
    __syncthreads();
    int wid = threadIdx.x >> 6, lane = threadIdx.x & 63;
    float Al = A[lane], Bl = B[lane];
    for (int l = blockIdx.x * 4 + wid; l < L; l += gridDim.x * 4) {
        int p0 = pos1[2 * l], p1 = pos1[2 * l + 1];
        float v0 = fmaxf(Al * ldf(&out1[(ll)p0 * 64 + lane]) + Bl, 0.f);
        float v1 = fmaxf(Al * ldf(&out1[(ll)p1 * 64 + lane]) + Bl, 0.f);
        float acc = 0.f;
#pragma unroll 8
        for (int k = 0; k < 64; ++k) {
            acc += __shfl(v0, k) * Wl[k * 64 + lane];
            acc += __shfl(v1, k) * Wl[(64 + k) * 64 + lane];
        }
        stf(&h2p[(ll)l * 64 + lane], acc);
    }
}

// ------- conv2 aggregation: wave/node, gather h2pre rows from global -------
template <typename TH, typename TO>
__global__ void k_conv2(const int* __restrict__ rp, const int* __restrict__ deg,
                        const int* __restrict__ csr, const TH* __restrict__ h2p,
                        const float* __restrict__ b2, TO* __restrict__ out2, int L) {
    int wid = threadIdx.x >> 6, lane = threadIdx.x & 63;
    int node = blockIdx.x * 4 + wid;
    if (node >= L) return;
    int rs = rp[node], re = rp[node + 1];
    float acc = 0.f;
    for (int c = rs; c < re; c += 64) {
        int e = c + lane;
        int sv = 0; float dv = 0.f;
        if (e < re) {
            sv = csr[e];
            dv = rsqrtf((float)deg[sv] + 1.0f);
        }
        int cnt = min(64, re - c);
        for (int j = 0; j < cnt; ++j) {
            int   sb = __shfl(sv, j);
            float wb = __shfl(dv, j);
            acc += wb * ldf(&h2p[(ll)sb * 64 + lane]);
        }
    }
    float degf = (float)(re - rs) + 1.0f;
    float val = rsqrtf(degf) * acc + ldf(&h2p[(ll)node * 64 + lane]) * (1.0f / degf) + b2[lane];
    stf(&out2[(ll)node * 64 + lane], val);
}

// ------- fused norm2+relu+prediction dot -------
template <typename TO>
__global__ void k_final(const int* __restrict__ pos2, const TO* __restrict__ out2,
                        const float* __restrict__ A, const float* __restrict__ B,
                        const float* __restrict__ pW, const float* __restrict__ pb,
                        float* __restrict__ out, int P) {
    int wid = threadIdx.x >> 6, lane = threadIdx.x & 63;
    int p = blockIdx.x * 4 + wid;
    if (p >= P) return;
    int i = pos2[p];
    float v = ldf(&out2[(ll)i * 64 + lane]);
    v = fmaxf(A[lane] * v + B[lane], 0.f) * pW[lane];
    for (int off = 32; off; off >>= 1) v += __shfl_xor(v, off);
    if (lane == 0) out[p] = v + pb[0];
}

// ---------------- templated pipeline ----------------
template <typename TO, typename TH>
static void run_pipeline(const int* x, const int* edge1, const int* edge2,
                         const int* pos1, const int* pos2,
                         const float* emb, const float* n0a, const float* n0g, const float* n0b,
                         const float* W1, const float* b1,
                         const float* n1a, const float* n1g, const float* n1b,
                         const float* W2, const float* b2,
                         const float* n2a, const float* n2g, const float* n2b,
                         const float* pW, const float* pb,
                         int N, int E1, int E2, int L, int P, int V,
                         int* cnt, float* stats, float* H1pre, int* bsum,
                         int* deg, int* rp, int* cur, int* csr,
                         TO* outb, TH* h2p,
                         float* d_out, hipStream_t stream) {
    float* sum1 = stats + 128; float* sq1 = stats + 192;
    float* A1   = stats + 256; float* B1  = stats + 320;
    float* sum2 = stats + 384; float* sq2 = stats + 448;
    float* A2   = stats + 512; float* B2  = stats + 576;

    hipMemsetAsync(cnt,   0, (size_t)V * 4, stream);
    hipMemsetAsync(stats, 0, 640 * 4, stream);
    hipMemsetAsync(deg,   0, (size_t)N * 4, stream);

    k_hist_x<<<256, 256, 0, stream>>>(x, N, cnt, V);
    k_table<<<1, 256, 0, stream>>>(cnt, emb, n0a, n0g, n0b, W1, H1pre, N, V);

    // ---- conv1 CSR build + aggregate ----
    k_deg<<<1024, 256, 0, stream>>>(edge1 + E1, E1, deg);
    int nb1 = cdiv(N, 2048);
    k_scan1<<<nb1, 256, 0, stream>>>(deg, rp, bsum, N);
    k_scan2<<<1, 64, 0, stream>>>(bsum, nb1);
    k_scan3<<<cdiv(N, 256), 256, 0, stream>>>(rp, cur, bsum, N, nb1);
    k_fill<<<1024, 256, 0, stream>>>(edge1, edge1 + E1, E1, cur, csr);
    k_conv1<TO><<<2048, 256, 0, stream>>>(x, rp, deg, csr, H1pre, b1, outb, N, V);

    // ---- norm1 + relu + pair GEMM -> h2pre ----
    k_stats<TO><<<1024, 256, 0, stream>>>(outb, N, sum1, sq1);
    k_norm_final<<<1, 64, 0, stream>>>(sum1, sq1, n1a, n1g, n1b, A1, B1, N);
    k_h2<TO, TH><<<2048, 256, 0, stream>>>(pos1, outb, A1, B1, W2, h2p, L);

    // ---- conv2 CSR build + aggregate (reuse deg/rp/cur/csr) ----
    hipMemsetAsync(deg, 0, (size_t)L * 4, stream);
    k_deg<<<1024, 256, 0, stream>>>(edge2 + E2, E2, deg);
    int nb2 = cdiv(L, 2048);
    k_scan1<<<nb2, 256, 0, stream>>>(deg, rp, bsum, L);
    k_scan2<<<1, 64, 0, stream>>>(bsum, nb2);
    k_scan3<<<cdiv(L, 256), 256, 0, stream>>>(rp, cur, bsum, L, nb2);
    k_fill<<<1024, 256, 0, stream>>>(edge2, edge2 + E2, E2, cur, csr);
    k_conv2<TH, TO><<<cdiv(L, 4), 256, 0, stream>>>(rp, deg, csr, h2p, b2, outb, L);

    // ---- norm2 + relu + prediction ----
    k_stats<TO><<<1024, 256, 0, stream>>>(outb, L, sum2, sq2);
    k_norm_final<<<1, 64, 0, stream>>>(sum2, sq2, n2a, n2g, n2b, A2, B2, L);
    k_final<TO><<<cdiv(P, 4), 256, 0, stream>>>(pos2, outb, A2, B2, pW, pb, d_out, P);
}

extern "C" void kernel_launch(void* const* d_in, const int* in_sizes, int n_in,
                              void* d_out, int out_size, void* d_ws, size_t ws_size,
                              hipStream_t stream) {
    const int*   x     = (const int*)d_in[0];
    const int*   edge1 = (const int*)d_in[1];
    const int*   edge2 = (const int*)d_in[2];
    const int*   pos1  = (const int*)d_in[3];
    const int*   pos2  = (const int*)d_in[4];
    const float* emb   = (const float*)d_in[5];
    const float* n0a   = (const float*)d_in[6];
    const float* n0g   = (const float*)d_in[7];
    const float* n0b   = (const float*)d_in[8];
    const float* W1    = (const float*)d_in[9];
    const float* b1    = (const float*)d_in[10];
    const float* n1a   = (const float*)d_in[11];
    const float* n1g   = (const float*)d_in[12];
    const float* n1b   = (const float*)d_in[13];
    const float* W2    = (const float*)d_in[14];
    const float* b2    = (const float*)d_in[15];
    const float* n2a   = (const float*)d_in[16];
    const float* n2g   = (const float*)d_in[17];
    const float* n2b   = (const float*)d_in[18];
    const float* pW    = (const float*)d_in[19];
    const float* pb    = (const float*)d_in[20];

    int N  = in_sizes[0];
    int E1 = in_sizes[1] / 2;
    int E2 = in_sizes[2] / 2;
    int L  = in_sizes[3] / 2;
    int P  = in_sizes[4];
    int V  = in_sizes[5] / 64;
    int Emax = (E1 > E2) ? E1 : E2;
    (void)n_in; (void)out_size;

    auto a256 = [](size_t s) { return (s + 255) & ~(size_t)255; };
    size_t smallsz = a256((size_t)V * 4) + a256(640 * 4) + a256((size_t)V * 64 * 4) + a256(1024 * 4);
    size_t degsz   = 3 * a256((size_t)(L + 1) * 4);
    size_t csrsz   = a256((size_t)Emax * 4);
    size_t out_f   = a256((size_t)L * 64 * 4);
    size_t out_h   = a256((size_t)L * 64 * 2);

    size_t need0 = smallsz + degsz + csrsz + out_f + out_f;  // f32 out, f32 h2p
    size_t need1 = smallsz + degsz + csrsz + out_f + out_h;  // f32 out, bf16 h2p
    int mode = (ws_size >= need0) ? 0 : (ws_size >= need1) ? 1 : 2;

    char* w = (char*)d_ws;
    size_t off = 0;
    auto alloc = [&](size_t bytes) { void* p = w + off; off += (bytes + 255) & ~(size_t)255; return p; };

    int*   cnt   = (int*)alloc((size_t)V * 4);
    float* stats = (float*)alloc(640 * 4);
    float* H1pre = (float*)alloc((size_t)V * 64 * 4);
    int*   bsum  = (int*)alloc(1024 * 4);
    int*   deg   = (int*)alloc((size_t)(L + 1) * 4);
    int*   rp    = (int*)alloc((size_t)(L + 1) * 4);
    int*   cur   = (int*)alloc((size_t)(L + 1) * 4);
    int*   csr   = (int*)alloc((size_t)Emax * 4);
    void*  outb  = alloc(mode == 2 ? out_h : out_f);
    void*  h2p   = alloc(mode == 0 ? out_f : out_h);

    if (mode == 0) {
        run_pipeline<float, float>(x, edge1, edge2, pos1, pos2, emb, n0a, n0g, n0b,
                                   W1, b1, n1a, n1g, n1b, W2, b2, n2a, n2g, n2b, pW, pb,
                                   N, E1, E2, L, P, V, cnt, stats, H1pre, bsum,
                                   deg, rp, cur, csr, (float*)outb, (float*)h2p,
                                   (float*)d_out, stream);
    } else if (mode == 1) {
        run_pipeline<float, __hip_bfloat16>(x, edge1, edge2, pos1, pos2, emb, n0a, n0g, n0b,
                                   W1, b1, n1a, n1g, n1b, W2, b2, n2a, n2g, n2b, pW, pb,
                                   N, E1, E2, L, P, V, cnt, stats, H1pre, bsum,
                                   deg, rp, cur, csr, (float*)outb, (__hip_bfloat16*)h2p,
                                   (float*)d_out, stream);
    } else {
        run_pipeline<__hip_bfloat16, __hip_bfloat16>(x, edge1, edge2, pos1, pos2, emb, n0a, n0g, n0b,
                                   W1, b1, n1a, n1g, n1b, W2, b2, n2a, n2g, n2b, pW, pb,
                                   N, E1, E2, L, P, V, cnt, stats, H1pre, bsum,
                                   deg, rp, cur, csr, (__hip_bfloat16*)outb, (__hip_bfloat16*)h2p,
                                   (float*)d_out, stream);
    }
}

// Round 4
// 1964.785 us; speedup vs baseline: 1.2179x; 1.2179x over previous
//
#include <hip/hip_runtime.h>
#include <hip/hip_bf16.h>

typedef long long ll;
static inline int cdiv(int a, int b) { return (a + b - 1) / b; }

__device__ __forceinline__ float ldf(const float* p) { return *p; }
__device__ __forceinline__ float ldf(const __hip_bfloat16* p) { return __bfloat162float(*p); }
__device__ __forceinline__ void stf(float* p, float v) { *p = v; }
__device__ __forceinline__ void stf(__hip_bfloat16* p, float v) { *p = __float2bfloat16(v); }

// wave-uniform broadcast via v_readlane (VALU pipe, no DS traffic)
__device__ __forceinline__ int bcasti(int v, int j) {
    return __builtin_amdgcn_readlane(v, j);
}
__device__ __forceinline__ float bcastf(float v, int j) {
    return __int_as_float(__builtin_amdgcn_readlane(__float_as_int(v), j));
}

// ---------------- histogram of x over V bins ----------------
__global__ void k_hist_x(const int* __restrict__ x, int N, int* __restrict__ cnt, int V) {
    __shared__ int lc[128];
    for (int i = threadIdx.x; i < V; i += blockDim.x) lc[i] = 0;
    __syncthreads();
    int stride = gridDim.x * blockDim.x;
    for (int i = blockIdx.x * blockDim.x + threadIdx.x; i < N; i += stride)
        atomicAdd(&lc[x[i]], 1);
    __syncthreads();
    for (int i = threadIdx.x; i < V; i += blockDim.x) atomicAdd(&cnt[i], lc[i]);
}

// ------- exact GraphNorm0 from histogram + fold into W1: H1pre = T0 @ W1 -------
__global__ void k_table(const int* __restrict__ cnt, const float* __restrict__ emb,
                        const float* __restrict__ n0a, const float* __restrict__ n0g,
                        const float* __restrict__ n0b, const float* __restrict__ W1,
                        float* __restrict__ H1pre, int N, int V) {
    __shared__ float T0[101 * 64];
    __shared__ float W1l[64 * 64];
    __shared__ float A0[64], B0[64];
    __shared__ float rs[256], rq[256];
    __shared__ float cf[128];
    int t = threadIdx.x;
    for (int i = t; i < V; i += 256) cf[i] = (float)cnt[i];
    __syncthreads();
    int d = t & 63, g = t >> 6;
    float s = 0.f, q = 0.f;
    for (int v = g; v < V; v += 4) {
        float c = cf[v]; float e = emb[v * 64 + d];
        s += c * e; q += c * e * e;
    }
    rs[t] = s; rq[t] = q;
    __syncthreads();
    if (t < 64) {
        float sum = rs[t] + rs[t + 64] + rs[t + 128] + rs[t + 192];
        float sq  = rq[t] + rq[t + 64] + rq[t + 128] + rq[t + 192];
        float invN = 1.0f / (float)N;
        float m = sum * invN;
        float a = n0a[t];
        float var = sq * invN - (2.0f * a - a * a) * m * m;
        float A = n0g[t] * rsqrtf(var + 1e-5f);
        A0[t] = A; B0[t] = n0b[t] - A * a * m;
    }
    __syncthreads();
    for (int i = t; i < V * 64; i += 256) {
        int dd = i & 63;
        T0[i] = A0[dd] * emb[i] + B0[dd];
    }
    for (int i = t; i < 64 * 64; i += 256) W1l[i] = W1[i];
    __syncthreads();
    for (int o = t; o < V * 64; o += 256) {
        int v = o >> 6, dd = o & 63;
        float acc = 0.f;
#pragma unroll 8
        for (int k = 0; k < 64; ++k) acc += T0[v * 64 + k] * W1l[k * 64 + dd];
        H1pre[o] = acc;
    }
}

// ---------------- degree histogram over dst ----------------
__global__ void k_deg(const int* __restrict__ dst, int E, int* __restrict__ deg) {
    int stride = gridDim.x * blockDim.x;
    for (int e = blockIdx.x * blockDim.x + threadIdx.x; e < E; e += stride)
        atomicAdd(&deg[dst[e]], 1);
}

// ---------------- pack (deg<<7)|x per node ----------------
__global__ void k_pack(const int* __restrict__ x, const int* __restrict__ deg,
                       int N, int* __restrict__ pk) {
    int i = blockIdx.x * blockDim.x + threadIdx.x;
    if (i < N) pk[i] = (deg[i] << 7) | x[i];
}

// ---------------- scan: per-block exclusive (2048 elems/block) ----------------
__global__ void k_scan1(const int* __restrict__ in, int* __restrict__ out,
                        int* __restrict__ bsum, int M) {
    __shared__ int ts[256];
    int t = threadIdx.x;
    int base = blockIdx.x * 2048 + t * 8;
    int v[8]; int s = 0;
#pragma unroll
    for (int j = 0; j < 8; ++j) { int idx = base + j; int val = (idx < M) ? in[idx] : 0; v[j] = val; s += val; }
    ts[t] = s; __syncthreads();
    for (int off = 1; off < 256; off <<= 1) {
        int xv = 0;
        if (t >= off) xv = ts[t - off];
        __syncthreads();
        ts[t] += xv;
        __syncthreads();
    }
    int incl = ts[t];
    int excl = incl - s;
    if (t == 255) bsum[blockIdx.x] = incl;
    int run = excl;
#pragma unroll
    for (int j = 0; j < 8; ++j) { int idx = base + j; if (idx < M) out[idx] = run; run += v[j]; }
}

// parallel exclusive scan of block sums (nb <= 256)
__global__ void k_scan2(int* __restrict__ bsum, int nb) {
    __shared__ int ts[256];
    int t = threadIdx.x;
    int v = (t < nb) ? bsum[t] : 0;
    ts[t] = v; __syncthreads();
    for (int off = 1; off < 256; off <<= 1) {
        int xv = 0;
        if (t >= off) xv = ts[t - off];
        __syncthreads();
        ts[t] += xv;
        __syncthreads();
    }
    if (t < nb) bsum[t] = ts[t] - v;
}

__global__ void k_scan3(int* __restrict__ A, const int* __restrict__ bsum, int M) {
    int stride = gridDim.x * blockDim.x;
    for (int i = blockIdx.x * blockDim.x + threadIdx.x; i < M; i += stride)
        A[i] += bsum[i >> 11];
}

// ---------------- CSR fill: A doubles as cursor; after fill A[d] = row end ----------------
__global__ void k_fill(const int* __restrict__ src, const int* __restrict__ dst, int E,
                       int* __restrict__ A, int* __restrict__ csr) {
    int stride = gridDim.x * blockDim.x;
    for (int e = blockIdx.x * blockDim.x + threadIdx.x; e < E; e += stride) {
        int d = dst[e];
        int p = atomicAdd(&A[d], 1);
        csr[p] = src[e];
    }
}

// ------- conv1: wave/node, table in LDS, 1 readlane + 1 LDS read per edge; fused stats -------
template <typename TO>
__global__ __launch_bounds__(256) void k_conv1(
        const int* __restrict__ x, const int* __restrict__ A, const int* __restrict__ pk,
        const int* __restrict__ csr, const float* __restrict__ H1pre,
        const float* __restrict__ b1, TO* __restrict__ out1,
        float* __restrict__ gsum, float* __restrict__ gsq, int N, int V) {
    __shared__ float Hl[101 * 64];
    for (int i = threadIdx.x; i < V * 64; i += 256) Hl[i] = H1pre[i];
    __syncthreads();
    int wid = threadIdx.x >> 6, lane = threadIdx.x & 63;
    float b1l = b1[lane];
    float s = 0.f, q = 0.f;
    for (int node = blockIdx.x * 4 + wid; node < N; node += gridDim.x * 4) {
        int re = A[node], rstart = node ? A[node - 1] : 0;
        float acc = 0.f;
        for (int c = rstart; c < re; c += 64) {
            int e = c + lane;
            int pkv = 0;
            if (e < re) pkv = pk[csr[e]];
            int cnt = min(64, re - c);
            for (int j = 0; j < cnt; ++j) {
                int b = bcasti(pkv, j);
                float dv = rsqrtf((float)(b >> 7) + 1.0f);
                acc += dv * Hl[(b & 127) * 64 + lane];
            }
        }
        float degf = (float)(re - rstart) + 1.0f;
        int xi = x[node];
        float val = rsqrtf(degf) * acc + Hl[xi * 64 + lane] * (1.0f / degf) + b1l;
        stf(&out1[(ll)node * 64 + lane], val);
        s += val; q += val * val;
    }
    atomicAdd(&gsum[lane], s);
    atomicAdd(&gsq[lane], q);
}

__global__ void k_norm_final(const float* __restrict__ gsum, const float* __restrict__ gsq,
                             const float* __restrict__ na, const float* __restrict__ ng,
                             const float* __restrict__ nbb,
                             float* __restrict__ A, float* __restrict__ B, int M) {
    int t = threadIdx.x;
    if (t < 64) {
        float invM = 1.0f / (float)M;
        float m = gsum[t] * invM;
        float a = na[t];
        float var = gsq[t] * invM - (2.0f * a - a * a) * m * m;
        float Av = ng[t] * rsqrtf(var + 1e-5f);
        A[t] = Av; B[t] = nbb[t] - Av * a * m;
    }
}

// ------- RS GEMM: W2 (64x128) held in VGPRs, readlane broadcast, zero DS in loop -------
// R[i][c] = relu(norm1(h1[i])) . W2[0:64][c] ;  S[i][c] = ... W2[64:128][c]
template <typename TO, typename TR>
__global__ __launch_bounds__(256, 2) void k_RS(
        const TO* __restrict__ out1, const float* __restrict__ A1, const float* __restrict__ B1,
        const float* __restrict__ W2, TR* __restrict__ RS, int N) {
    int wid = threadIdx.x >> 6, lane = threadIdx.x & 63;
    float Al = A1[lane], Bl = B1[lane];
    float wx[64], wy[64];
#pragma unroll
    for (int k = 0; k < 64; ++k) {
        wx[k] = W2[k * 64 + lane];
        wy[k] = W2[(64 + k) * 64 + lane];
    }
    for (int node = blockIdx.x * 4 + wid; node < N; node += gridDim.x * 4) {
        float v = fmaxf(Al * ldf(&out1[(ll)node * 64 + lane]) + Bl, 0.f);
        float ar = 0.f, asv = 0.f;
#pragma unroll
        for (int k = 0; k < 64; ++k) {
            float hv = bcastf(v, k);
            ar  += hv * wx[k];
            asv += hv * wy[k];
        }
        stf(&RS[(ll)node * 128 + lane], ar);
        stf(&RS[(ll)node * 128 + 64 + lane], asv);
    }
}

// ------- gather: h2ps[l] = dinv2[l] * (R[p0] + S[p1]), stored bf16 -------
template <typename TR>
__global__ void k_h2g(const int* __restrict__ pos1, const TR* __restrict__ RS,
                      const int* __restrict__ A2, __hip_bfloat16* __restrict__ h2ps, int L) {
    int wid = threadIdx.x >> 6, lane = threadIdx.x & 63;
    for (int l = blockIdx.x * 4 + wid; l < L; l += gridDim.x * 4) {
        int re = A2[l], rstart = l ? A2[l - 1] : 0;
        float dv = rsqrtf((float)(re - rstart) + 1.0f);
        int p0 = pos1[2 * l], p1 = pos1[2 * l + 1];
        float r = ldf(&RS[(ll)p0 * 128 + lane]);
        float s = ldf(&RS[(ll)p1 * 128 + 64 + lane]);
        stf(&h2ps[(ll)l * 64 + lane], dv * (r + s));
    }
}

// ------- conv2: pre-scaled rows -> out2[d] = dinv[d]*(sum h2ps[src] + h2ps[d]) + b2; fused stats -------
template <typename TO>
__global__ __launch_bounds__(256) void k_conv2(
        const int* __restrict__ A, const int* __restrict__ csr,
        const __hip_bfloat16* __restrict__ h2ps, const float* __restrict__ b2,
        TO* __restrict__ out2, float* __restrict__ gsum, float* __restrict__ gsq, int L) {
    int wid = threadIdx.x >> 6, lane = threadIdx.x & 63;
    float b2l = b2[lane];
    float s = 0.f, q = 0.f;
    for (int node = blockIdx.x * 4 + wid; node < L; node += gridDim.x * 4) {
        int re = A[node], rstart = node ? A[node - 1] : 0;
        float acc = 0.f;
        for (int c = rstart; c < re; c += 64) {
            int e = c + lane;
            int sv = 0;
            if (e < re) sv = csr[e];
            int cnt = min(64, re - c);
            for (int j = 0; j < cnt; ++j) {
                int sb = bcasti(sv, j);
                acc += ldf(&h2ps[(ll)sb * 64 + lane]);
            }
        }
        float degf = (float)(re - rstart) + 1.0f;
        float val = rsqrtf(degf) * (acc + ldf(&h2ps[(ll)node * 64 + lane])) + b2l;
        stf(&out2[(ll)node * 64 + lane], val);
        s += val; q += val * val;
    }
    atomicAdd(&gsum[lane], s);
    atomicAdd(&gsq[lane], q);
}

// ------- fused norm2+relu+prediction dot -------
template <typename TO>
__global__ void k_final(const int* __restrict__ pos2, const TO* __restrict__ out2,
                        const float* __restrict__ A, const float* __restrict__ B,
                        const float* __restrict__ pW, const float* __restrict__ pb,
                        float* __restrict__ out, int P) {
    int wid = threadIdx.x >> 6, lane = threadIdx.x & 63;
    int p = blockIdx.x * 4 + wid;
    if (p >= P) return;
    int i = pos2[p];
    float v = ldf(&out2[(ll)i * 64 + lane]);
    v = fmaxf(A[lane] * v + B[lane], 0.f) * pW[lane];
    for (int off = 32; off; off >>= 1) v += __shfl_xor(v, off);
    if (lane == 0) out[p] = v + pb[0];
}

// ---------------- templated pipeline ----------------
template <typename TO, typename TR>
static void run_pipeline(const int* x, const int* edge1, const int* edge2,
                         const int* pos1, const int* pos2,
                         const float* emb, const float* n0a, const float* n0g, const float* n0b,
                         const float* W1, const float* b1,
                         const float* n1a, const float* n1g, const float* n1b,
                         const float* W2, const float* b2,
                         const float* n2a, const float* n2g, const float* n2b,
                         const float* pW, const float* pb,
                         int N, int E1, int E2, int L, int P, int V,
                         int* cnt, float* stats, float* H1pre, int* bsum,
                         int* pk, int* deg, int* A, int* csr,
                         void* region1, void* region2,
                         float* d_out, hipStream_t stream) {
    TO* out1 = (TO*)region1;
    __hip_bfloat16* h2ps = (__hip_bfloat16*)region1;   // aliases out1 (out1 dead by then)
    TR* RS   = (TR*)region2;
    TO* out2 = (TO*)region2;                            // aliases RS (RS dead by then)

    float* sum1 = stats + 128; float* sq1 = stats + 192;
    float* A1   = stats + 256; float* B1  = stats + 320;
    float* sum2 = stats + 384; float* sq2 = stats + 448;
    float* A2   = stats + 512; float* B2  = stats + 576;

    hipMemsetAsync(cnt,   0, (size_t)V * 4, stream);
    hipMemsetAsync(stats, 0, 640 * 4, stream);
    hipMemsetAsync(deg,   0, (size_t)N * 4, stream);

    k_hist_x<<<256, 256, 0, stream>>>(x, N, cnt, V);
    k_table<<<1, 256, 0, stream>>>(cnt, emb, n0a, n0g, n0b, W1, H1pre, N, V);

    // ---- conv1 CSR build + aggregate (A doubles as row-pointer & cursor) ----
    k_deg<<<1024, 256, 0, stream>>>(edge1 + E1, E1, deg);
    k_pack<<<cdiv(N, 256), 256, 0, stream>>>(x, deg, N, pk);
    int nb1 = cdiv(N, 2048);
    k_scan1<<<nb1, 256, 0, stream>>>(deg, A, bsum, N);
    k_scan2<<<1, 256, 0, stream>>>(bsum, nb1);
    k_scan3<<<512, 256, 0, stream>>>(A, bsum, N);
    k_fill<<<1024, 256, 0, stream>>>(edge1, edge1 + E1, E1, A, csr);
    k_conv1<TO><<<2048, 256, 0, stream>>>(x, A, pk, csr, H1pre, b1, out1, sum1, sq1, N, V);

    // ---- norm1 + relu + per-node GEMM -> R,S ----
    k_norm_final<<<1, 64, 0, stream>>>(sum1, sq1, n1a, n1g, n1b, A1, B1, N);
    k_RS<TO, TR><<<1024, 256, 0, stream>>>(out1, A1, B1, W2, RS, N);

    // ---- conv2 CSR build ----
    hipMemsetAsync(deg, 0, (size_t)L * 4, stream);
    k_deg<<<1024, 256, 0, stream>>>(edge2 + E2, E2, deg);
    int nb2 = cdiv(L, 2048);
    k_scan1<<<nb2, 256, 0, stream>>>(deg, A, bsum, L);
    k_scan2<<<1, 256, 0, stream>>>(bsum, nb2);
    k_scan3<<<512, 256, 0, stream>>>(A, bsum, L);
    k_fill<<<1024, 256, 0, stream>>>(edge2, edge2 + E2, E2, A, csr);

    // ---- gather h2ps (overwrites out1's region) + aggregate (overwrites RS's region) ----
    k_h2g<TR><<<2048, 256, 0, stream>>>(pos1, RS, A, h2ps, L);
    k_conv2<TO><<<2048, 256, 0, stream>>>(A, csr, h2ps, b2, out2, sum2, sq2, L);

    // ---- norm2 + relu + prediction ----
    k_norm_final<<<1, 64, 0, stream>>>(sum2, sq2, n2a, n2g, n2b, A2, B2, L);
    k_final<TO><<<cdiv(P, 4), 256, 0, stream>>>(pos2, out2, A2, B2, pW, pb, d_out, P);
}

extern "C" void kernel_launch(void* const* d_in, const int* in_sizes, int n_in,
                              void* d_out, int out_size, void* d_ws, size_t ws_size,
                              hipStream_t stream) {
    const int*   x     = (const int*)d_in[0];
    const int*   edge1 = (const int*)d_in[1];
    const int*   edge2 = (const int*)d_in[2];
    const int*   pos1  = (const int*)d_in[3];
    const int*   pos2  = (const int*)d_in[4];
    const float* emb   = (const float*)d_in[5];
    const float* n0a   = (const float*)d_in[6];
    const float* n0g   = (const float*)d_in[7];
    const float* n0b   = (const float*)d_in[8];
    const float* W1    = (const float*)d_in[9];
    const float* b1    = (const float*)d_in[10];
    const float* n1a   = (const float*)d_in[11];
    const float* n1g   = (const float*)d_in[12];
    const float* n1b   = (const float*)d_in[13];
    const float* W2    = (const float*)d_in[14];
    const float* b2    = (const float*)d_in[15];
    const float* n2a   = (const float*)d_in[16];
    const float* n2g   = (const float*)d_in[17];
    const float* n2b   = (const float*)d_in[18];
    const float* pW    = (const float*)d_in[19];
    const float* pb    = (const float*)d_in[20];

    int N  = in_sizes[0];
    int E1 = in_sizes[1] / 2;
    int E2 = in_sizes[2] / 2;
    int L  = in_sizes[3] / 2;
    int P  = in_sizes[4];
    int V  = in_sizes[5] / 64;
    int Emax = (E1 > E2) ? E1 : E2;
    (void)n_in; (void)out_size;

    auto a256 = [](size_t s) { return (s + 255) & ~(size_t)255; };
    auto mx = [](size_t a, size_t b) { return a > b ? a : b; };

    size_t fixed = a256((size_t)V * 4) + a256(640 * 4) + a256((size_t)V * 64 * 4) +
                   a256(1024 * 4) + a256((size_t)N * 4) +
                   a256((size_t)(L + 1) * 4) + a256((size_t)(L + 1) * 4) +
                   a256((size_t)Emax * 4);
    size_t r1_pri = a256(mx((size_t)N * 64 * 4, (size_t)L * 64 * 2));
    size_t r2_pri = a256(mx((size_t)N * 128 * 4, (size_t)L * 64 * 4));
    size_t r1_fb  = a256(mx((size_t)N * 64 * 2, (size_t)L * 64 * 2));
    size_t r2_fb  = a256(mx((size_t)N * 128 * 2, (size_t)L * 64 * 2));
    size_t need_pri = fixed + r1_pri + r2_pri;
    bool primary = (ws_size >= need_pri);
    size_t r1 = primary ? r1_pri : r1_fb;
    size_t r2 = primary ? r2_pri : r2_fb;

    char* w = (char*)d_ws;
    size_t off = 0;
    auto alloc = [&](size_t bytes) { void* p = w + off; off += (bytes + 255) & ~(size_t)255; return p; };

    int*   cnt   = (int*)alloc((size_t)V * 4);
    float* stats = (float*)alloc(640 * 4);
    float* H1pre = (float*)alloc((size_t)V * 64 * 4);
    int*   bsum  = (int*)alloc(1024 * 4);
    int*   pk    = (int*)alloc((size_t)N * 4);
    int*   deg   = (int*)alloc((size_t)(L + 1) * 4);
    int*   A     = (int*)alloc((size_t)(L + 1) * 4);
    int*   csr   = (int*)alloc((size_t)Emax * 4);
    void*  region1 = alloc(r1);
    void*  region2 = alloc(r2);

    if (primary) {
        run_pipeline<float, float>(x, edge1, edge2, pos1, pos2, emb, n0a, n0g, n0b,
                                   W1, b1, n1a, n1g, n1b, W2, b2, n2a, n2g, n2b, pW, pb,
                                   N, E1, E2, L, P, V, cnt, stats, H1pre, bsum,
                                   pk, deg, A, csr, region1, region2,
                                   (float*)d_out, stream);
    } else {
        run_pipeline<__hip_bfloat16, __hip_bfloat16>(x, edge1, edge2, pos1, pos2, emb,
                                   n0a, n0g, n0b,
                                   W1, b1, n1a, n1g, n1b, W2, b2, n2a, n2g, n2b, pW, pb,
                                   N, E1, E2, L, P, V, cnt, stats, H1pre, bsum,
                                   pk, deg, A, csr, region1, region2,
                                   (float*)d_out, stream);
    }
}

// Round 7
// 1465.991 us; speedup vs baseline: 1.6323x; 1.3402x over previous
//
#include <hip/hip_runtime.h>
#include <hip/hip_bf16.h>

typedef long long ll;
static inline int cdiv(int a, int b) { return (a + b - 1) / b; }

__device__ __forceinline__ float ldf(const float* p) { return *p; }
__device__ __forceinline__ float ldf(const __hip_bfloat16* p) { return __bfloat162float(*p); }
__device__ __forceinline__ void stf(float* p, float v) { *p = v; }
__device__ __forceinline__ void stf(__hip_bfloat16* p, float v) { *p = __float2bfloat16(v); }

__device__ __forceinline__ float b2f(unsigned short u) {
    return __int_as_float(((unsigned int)u) << 16);
}
__device__ __forceinline__ unsigned short f2b(float f) {
    __hip_bfloat16 h = __float2bfloat16(f);
    return *reinterpret_cast<unsigned short*>(&h);
}

// store 4 consecutive features at p[0..3]
__device__ __forceinline__ void st4(float* p, float v0, float v1, float v2, float v3) {
    float4 v = make_float4(v0, v1, v2, v3);
    *reinterpret_cast<float4*>(p) = v;
}
__device__ __forceinline__ void st4(__hip_bfloat16* p, float v0, float v1, float v2, float v3) {
    ushort4 v;
    v.x = f2b(v0); v.y = f2b(v1); v.z = f2b(v2); v.w = f2b(v3);
    *reinterpret_cast<ushort4*>(p) = v;
}

// wave-uniform broadcast via v_readlane
__device__ __forceinline__ float bcastf(float v, int j) {
    return __int_as_float(__builtin_amdgcn_readlane(__float_as_int(v), j));
}

// ---------------- histogram of x over V bins ----------------
__global__ void k_hist_x(const int* __restrict__ x, int N, int* __restrict__ cnt, int V) {
    __shared__ int lc[128];
    for (int i = threadIdx.x; i < V; i += blockDim.x) lc[i] = 0;
    __syncthreads();
    int stride = gridDim.x * blockDim.x;
    for (int i = blockIdx.x * blockDim.x + threadIdx.x; i < N; i += stride)
        atomicAdd(&lc[x[i]], 1);
    __syncthreads();
    for (int i = threadIdx.x; i < V; i += blockDim.x) atomicAdd(&cnt[i], lc[i]);
}

// ------- exact GraphNorm0 from histogram + fold into W1: H1pre = T0 @ W1 -------
__global__ void k_table(const int* __restrict__ cnt, const float* __restrict__ emb,
                        const float* __restrict__ n0a, const float* __restrict__ n0g,
                        const float* __restrict__ n0b, const float* __restrict__ W1,
                        float* __restrict__ H1pre, int N, int V) {
    __shared__ float T0[101 * 64];
    __shared__ float W1l[64 * 64];
    __shared__ float A0[64], B0[64];
    __shared__ float rs[256], rq[256];
    __shared__ float cf[128];
    int t = threadIdx.x;
    for (int i = t; i < V; i += 256) cf[i] = (float)cnt[i];
    __syncthreads();
    int d = t & 63, g = t >> 6;
    float s = 0.f, q = 0.f;
    for (int v = g; v < V; v += 4) {
        float c = cf[v]; float e = emb[v * 64 + d];
        s += c * e; q += c * e * e;
    }
    rs[t] = s; rq[t] = q;
    __syncthreads();
    if (t < 64) {
        float sum = rs[t] + rs[t + 64] + rs[t + 128] + rs[t + 192];
        float sq  = rq[t] + rq[t + 64] + rq[t + 128] + rq[t + 192];
        float invN = 1.0f / (float)N;
        float m = sum * invN;
        float a = n0a[t];
        float var = sq * invN - (2.0f * a - a * a) * m * m;
        float A = n0g[t] * rsqrtf(var + 1e-5f);
        A0[t] = A; B0[t] = n0b[t] - A * a * m;
    }
    __syncthreads();
    for (int i = t; i < V * 64; i += 256) {
        int dd = i & 63;
        T0[i] = A0[dd] * emb[i] + B0[dd];
    }
    for (int i = t; i < 64 * 64; i += 256) W1l[i] = W1[i];
    __syncthreads();
    for (int o = t; o < V * 64; o += 256) {
        int v = o >> 6, dd = o & 63;
        float acc = 0.f;
#pragma unroll 8
        for (int k = 0; k < 64; ++k) acc += T0[v * 64 + k] * W1l[k * 64 + dd];
        H1pre[o] = acc;
    }
}

// ---------------- degree histogram over dst ----------------
__global__ void k_deg(const int* __restrict__ dst, int E, int* __restrict__ deg) {
    int stride = gridDim.x * blockDim.x;
    for (int e = blockIdx.x * blockDim.x + threadIdx.x; e < E; e += stride)
        atomicAdd(&deg[dst[e]], 1);
}

// ---------------- pack (deg<<7)|x per node ----------------
__global__ void k_pack(const int* __restrict__ x, const int* __restrict__ deg,
                       int N, int* __restrict__ pk) {
    int i = blockIdx.x * blockDim.x + threadIdx.x;
    if (i < N) pk[i] = (deg[i] << 7) | x[i];
}

// ---------------- scan: per-block exclusive (2048 elems/block) ----------------
__global__ void k_scan1(const int* __restrict__ in, int* __restrict__ out,
                        int* __restrict__ bsum, int M) {
    __shared__ int ts[256];
    int t = threadIdx.x;
    int base = blockIdx.x * 2048 + t * 8;
    int v[8]; int s = 0;
#pragma unroll
    for (int j = 0; j < 8; ++j) { int idx = base + j; int val = (idx < M) ? in[idx] : 0; v[j] = val; s += val; }
    ts[t] = s; __syncthreads();
    for (int off = 1; off < 256; off <<= 1) {
        int xv = 0;
        if (t >= off) xv = ts[t - off];
        __syncthreads();
        ts[t] += xv;
        __syncthreads();
    }
    int incl = ts[t];
    int excl = incl - s;
    if (t == 255) bsum[blockIdx.x] = incl;
    int run = excl;
#pragma unroll
    for (int j = 0; j < 8; ++j) { int idx = base + j; if (idx < M) out[idx] = run; run += v[j]; }
}

// parallel exclusive scan of block sums (nb <= 256)
__global__ void k_scan2(int* __restrict__ bsum, int nb) {
    __shared__ int ts[256];
    int t = threadIdx.x;
    int v = (t < nb) ? bsum[t] : 0;
    ts[t] = v; __syncthreads();
    for (int off = 1; off < 256; off <<= 1) {
        int xv = 0;
        if (t >= off) xv = ts[t - off];
        __syncthreads();
        ts[t] += xv;
        __syncthreads();
    }
    if (t < nb) bsum[t] = ts[t] - v;
}

__global__ void k_scan3(int* __restrict__ A, const int* __restrict__ bsum, int M) {
    int stride = gridDim.x * blockDim.x;
    for (int i = blockIdx.x * blockDim.x + threadIdx.x; i < M; i += stride)
        A[i] += bsum[i >> 11];
}

// ---------------- CSR fill storing src index ----------------
__global__ void k_fill(const int* __restrict__ src, const int* __restrict__ dst, int E,
                       int* __restrict__ A, int* __restrict__ csr) {
    int stride = gridDim.x * blockDim.x;
    for (int e = blockIdx.x * blockDim.x + threadIdx.x; e < E; e += stride) {
        int d = dst[e];
        int p = atomicAdd(&A[d], 1);
        csr[p] = src[e];
    }
}

// ---------------- CSR fill storing packed pk[src] ----------------
__global__ void k_fillpk(const int* __restrict__ src, const int* __restrict__ dst, int E,
                         const int* __restrict__ pk, int* __restrict__ A, int* __restrict__ csr) {
    int stride = gridDim.x * blockDim.x;
    for (int e = blockIdx.x * blockDim.x + threadIdx.x; e < E; e += stride) {
        int d = dst[e];
        int p = atomicAdd(&A[d], 1);
        csr[p] = pk[src[e]];
    }
}

// ------- conv1: wave/node, 4 edges/iter (16-lane groups), LDS table stride 68 -------
template <typename TO>
__global__ __launch_bounds__(256) void k_conv1(
        const int* __restrict__ x, const int* __restrict__ A, const int* __restrict__ csrpk,
        const float* __restrict__ H1pre, const float* __restrict__ b1,
        TO* __restrict__ out1, float* __restrict__ gsum, float* __restrict__ gsq,
        int N, int V) {
    __shared__ float Hl[101 * 68];
    __shared__ float redS[4][64], redQ[4][64];
    for (int i = threadIdx.x; i < V * 64; i += 256) {
        int row = i >> 6, col = i & 63;
        Hl[row * 68 + col] = H1pre[i];
    }
    __syncthreads();
    int wid = threadIdx.x >> 6, lane = threadIdx.x & 63;
    int g = lane >> 4, q = lane & 15;
    float4 b1v = *reinterpret_cast<const float4*>(&b1[4 * q]);
    float s0 = 0.f, s1 = 0.f, s2 = 0.f, s3 = 0.f;
    float q0 = 0.f, q1 = 0.f, q2 = 0.f, q3 = 0.f;
    for (int node = blockIdx.x * 4 + wid; node < N; node += gridDim.x * 4) {
        int re = A[node], rs0 = node ? A[node - 1] : 0;
        float a0 = 0.f, a1 = 0.f, a2 = 0.f, a3 = 0.f;
        int pkcur = -1;
        { int e = rs0 + g; if (e < re) pkcur = csrpk[e]; }
        for (int c = rs0; c < re; c += 4) {
            int pknxt = -1;
            { int en = c + 4 + g; if (en < re) pknxt = csrpk[en]; }
            if (pkcur >= 0) {
                float dv = rsqrtf((float)(pkcur >> 7) + 1.0f);
                const float4 hv = *reinterpret_cast<const float4*>(&Hl[(pkcur & 127) * 68 + 4 * q]);
                a0 += dv * hv.x; a1 += dv * hv.y; a2 += dv * hv.z; a3 += dv * hv.w;
            }
            pkcur = pknxt;
        }
        // reduce across the 4 groups
        a0 += __shfl_xor(a0, 16); a1 += __shfl_xor(a1, 16);
        a2 += __shfl_xor(a2, 16); a3 += __shfl_xor(a3, 16);
        a0 += __shfl_xor(a0, 32); a1 += __shfl_xor(a1, 32);
        a2 += __shfl_xor(a2, 32); a3 += __shfl_xor(a3, 32);
        float degf = (float)(re - rs0) + 1.0f;
        float sc = rsqrtf(degf), si = 1.0f / degf;
        const float4 sv = *reinterpret_cast<const float4*>(&Hl[x[node] * 68 + 4 * q]);
        float v0 = sc * a0 + sv.x * si + b1v.x;
        float v1 = sc * a1 + sv.y * si + b1v.y;
        float v2 = sc * a2 + sv.z * si + b1v.z;
        float v3 = sc * a3 + sv.w * si + b1v.w;
        if (g == 0) {
            st4(&out1[(ll)node * 64 + 4 * q], v0, v1, v2, v3);
            s0 += v0; s1 += v1; s2 += v2; s3 += v3;
            q0 += v0 * v0; q1 += v1 * v1; q2 += v2 * v2; q3 += v3 * v3;
        }
    }
    if (g == 0) {
        redS[wid][4 * q] = s0; redS[wid][4 * q + 1] = s1; redS[wid][4 * q + 2] = s2; redS[wid][4 * q + 3] = s3;
        redQ[wid][4 * q] = q0; redQ[wid][4 * q + 1] = q1; redQ[wid][4 * q + 2] = q2; redQ[wid][4 * q + 3] = q3;
    }
    __syncthreads();
    int t = threadIdx.x;
    if (t < 64) {
        atomicAdd(&gsum[t], redS[0][t] + redS[1][t] + redS[2][t] + redS[3][t]);
        atomicAdd(&gsq[t],  redQ[0][t] + redQ[1][t] + redQ[2][t] + redQ[3][t]);
    }
}

__global__ void k_norm_final(const float* __restrict__ gsum, const float* __restrict__ gsq,
                             const float* __restrict__ na, const float* __restrict__ ng,
                             const float* __restrict__ nbb,
                             float* __restrict__ A, float* __restrict__ B, int M) {
    int t = threadIdx.x;
    if (t < 64) {
        float invM = 1.0f / (float)M;
        float m = gsum[t] * invM;
        float a = na[t];
        float var = gsq[t] * invM - (2.0f * a - a * a) * m * m;
        float Av = ng[t] * rsqrtf(var + 1e-5f);
        A[t] = Av; B[t] = nbb[t] - Av * a * m;
    }
}

// ------- RS GEMM: W2 (64x128) held in VGPRs, readlane broadcast -------
template <typename TO>
__global__ __launch_bounds__(256, 2) void k_RS(
        const TO* __restrict__ out1, const float* __restrict__ A1, const float* __restrict__ B1,
        const float* __restrict__ W2, float* __restrict__ RS, int N) {
    int wid = threadIdx.x >> 6, lane = threadIdx.x & 63;
    float Al = A1[lane], Bl = B1[lane];
    float wx[64], wy[64];
#pragma unroll
    for (int k = 0; k < 64; ++k) {
        wx[k] = W2[k * 64 + lane];
        wy[k] = W2[(64 + k) * 64 + lane];
    }
    for (int node = blockIdx.x * 4 + wid; node < N; node += gridDim.x * 4) {
        float v = fmaxf(Al * ldf(&out1[(ll)node * 64 + lane]) + Bl, 0.f);
        float ar = 0.f, asv = 0.f;
#pragma unroll
        for (int k = 0; k < 64; ++k) {
            float hv = bcastf(v, k);
            ar  += hv * wx[k];
            asv += hv * wy[k];
        }
        RS[(ll)node * 128 + lane] = ar;
        RS[(ll)node * 128 + 64 + lane] = asv;
    }
}

// ------- gather: h2ps[l] = dinv2[l]*(R[p0]+S[p1]) bf16; 4 pairs per wave-iter -------
__global__ __launch_bounds__(256) void k_h2g(
        const int* __restrict__ pos1, const float* __restrict__ RS,
        const int* __restrict__ deg2, unsigned short* __restrict__ h2ps, int L) {
    int wv = (blockIdx.x * 4) + (threadIdx.x >> 6);
    int nw = gridDim.x * 4;
    int lane = threadIdx.x & 63;
    int g = lane >> 4, q = lane & 15;
    for (int base = wv * 4; base < L; base += nw * 4) {
        int l = base + g;
        if (l < L) {
            int p0 = pos1[2 * l], p1 = pos1[2 * l + 1];
            float dv = rsqrtf((float)deg2[l] + 1.0f);
            const float4 r = *reinterpret_cast<const float4*>(&RS[(ll)p0 * 128 + 4 * q]);
            const float4 s = *reinterpret_cast<const float4*>(&RS[(ll)p1 * 128 + 64 + 4 * q]);
            ushort4 o;
            o.x = f2b(dv * (r.x + s.x));
            o.y = f2b(dv * (r.y + s.y));
            o.z = f2b(dv * (r.z + s.z));
            o.w = f2b(dv * (r.w + s.w));
            *reinterpret_cast<ushort4*>(&h2ps[(ll)l * 64 + 4 * q]) = o;
        }
    }
}

// ------- conv2: 4 edges/iter, ushort4 row-gathers, rotate prefetch -------
template <typename TO>
__global__ __launch_bounds__(256) void k_conv2(
        const int* __restrict__ A, const int* __restrict__ csr,
        const unsigned short* __restrict__ h2ps, const float* __restrict__ b2,
        TO* __restrict__ out2, float* __restrict__ gsum, float* __restrict__ gsq, int L) {
    __shared__ float redS[4][64], redQ[4][64];
    int wid = threadIdx.x >> 6, lane = threadIdx.x & 63;
    int g = lane >> 4, q = lane & 15;
    float4 b2v = *reinterpret_cast<const float4*>(&b2[4 * q]);
    float s0 = 0.f, s1 = 0.f, s2 = 0.f, s3 = 0.f;
    float q0 = 0.f, q1 = 0.f, q2 = 0.f, q3 = 0.f;
    for (int node = blockIdx.x * 4 + wid; node < L; node += gridDim.x * 4) {
        int re = A[node], rs0 = node ? A[node - 1] : 0;
        float a0 = 0.f, a1 = 0.f, a2 = 0.f, a3 = 0.f;
        ushort4 cur = make_ushort4(0, 0, 0, 0);
        { int e = rs0 + g; if (e < re) cur = *reinterpret_cast<const ushort4*>(&h2ps[(ll)csr[e] * 64 + 4 * q]); }
        for (int c = rs0; c < re; c += 4) {
            ushort4 nxt = make_ushort4(0, 0, 0, 0);
            { int en = c + 4 + g; if (en < re) nxt = *reinterpret_cast<const ushort4*>(&h2ps[(ll)csr[en] * 64 + 4 * q]); }
            a0 += b2f(cur.x); a1 += b2f(cur.y); a2 += b2f(cur.z); a3 += b2f(cur.w);
            cur = nxt;
        }
        a0 += __shfl_xor(a0, 16); a1 += __shfl_xor(a1, 16);
        a2 += __shfl_xor(a2, 16); a3 += __shfl_xor(a3, 16);
        a0 += __shfl_xor(a0, 32); a1 += __shfl_xor(a1, 32);
        a2 += __shfl_xor(a2, 32); a3 += __shfl_xor(a3, 32);
        float degf = (float)(re - rs0) + 1.0f;
        float sc = rsqrtf(degf);
        const ushort4 sv = *reinterpret_cast<const ushort4*>(&h2ps[(ll)node * 64 + 4 * q]);
        float v0 = sc * (a0 + b2f(sv.x)) + b2v.x;
        float v1 = sc * (a1 + b2f(sv.y)) + b2v.y;
        float v2 = sc * (a2 + b2f(sv.z)) + b2v.z;
        float v3 = sc * (a3 + b2f(sv.w)) + b2v.w;
        if (g == 0) {
            st4(&out2[(ll)node * 64 + 4 * q], v0, v1, v2, v3);
            s0 += v0; s1 += v1; s2 += v2; s3 += v3;
            q0 += v0 * v0; q1 += v1 * v1; q2 += v2 * v2; q3 += v3 * v3;
        }
    }
    if (g == 0) {
        redS[wid][4 * q] = s0; redS[wid][4 * q + 1] = s1; redS[wid][4 * q + 2] = s2; redS[wid][4 * q + 3] = s3;
        redQ[wid][4 * q] = q0; redQ[wid][4 * q + 1] = q1; redQ[wid][4 * q + 2] = q2; redQ[wid][4 * q + 3] = q3;
    }
    __syncthreads();
    int t = threadIdx.x;
    if (t < 64) {
        atomicAdd(&gsum[t], redS[0][t] + redS[1][t] + redS[2][t] + redS[3][t]);
        atomicAdd(&gsq[t],  redQ[0][t] + redQ[1][t] + redQ[2][t] + redQ[3][t]);
    }
}

// ------- fused norm2+relu+prediction dot -------
template <typename TO>
__global__ void k_final(const int* __restrict__ pos2, const TO* __restrict__ out2,
                        const float* __restrict__ A, const float* __restrict__ B,
                        const float* __restrict__ pW, const float* __restrict__ pb,
                        float* __restrict__ out, int P) {
    int wid = threadIdx.x >> 6, lane = threadIdx.x & 63;
    int p = blockIdx.x * 4 + wid;
    if (p >= P) return;
    int i = pos2[p];
    float v = ldf(&out2[(ll)i * 64 + lane]);
    v = fmaxf(A[lane] * v + B[lane], 0.f) * pW[lane];
    for (int off = 32; off; off >>= 1) v += __shfl_xor(v, off);
    if (lane == 0) out[p] = v + pb[0];
}

// ---------------- templated pipeline ----------------
template <typename TO>
static void run_pipeline(const int* x, const int* edge1, const int* edge2,
                         const int* pos1, const int* pos2,
                         const float* emb, const float* n0a, const float* n0g, const float* n0b,
                         const float* W1, const float* b1,
                         const float* n1a, const float* n1g, const float* n1b,
                         const float* W2, const float* b2,
                         const float* n2a, const float* n2g, const float* n2b,
                         const float* pW, const float* pb,
                         int N, int E1, int E2, int L, int P, int V,
                         int* cnt, float* stats, float* H1pre, int* bsum,
                         int* pk, int* deg, int* A, int* csr,
                         void* region1, void* region2,
                         float* d_out, hipStream_t stream) {
    TO* out1 = (TO*)region1;
    unsigned short* h2ps = (unsigned short*)region1;   // aliases out1 (out1 dead by then)
    float* RS = (float*)region2;
    TO* out2  = (TO*)region2;                          // aliases RS (RS dead by then)

    float* sum1 = stats + 128; float* sq1 = stats + 192;
    float* A1   = stats + 256; float* B1  = stats + 320;
    float* sum2 = stats + 384; float* sq2 = stats + 448;
    float* A2   = stats + 512; float* B2  = stats + 576;

    hipMemsetAsync(cnt,   0, (size_t)V * 4, stream);
    hipMemsetAsync(stats, 0, 640 * 4, stream);
    hipMemsetAsync(deg,   0, (size_t)N * 4, stream);

    k_hist_x<<<256, 256, 0, stream>>>(x, N, cnt, V);
    k_table<<<1, 256, 0, stream>>>(cnt, emb, n0a, n0g, n0b, W1, H1pre, N, V);

    // ---- conv1 CSR build + aggregate ----
    k_deg<<<1024, 256, 0, stream>>>(edge1 + E1, E1, deg);
    k_pack<<<cdiv(N, 256), 256, 0, stream>>>(x, deg, N, pk);
    int nb1 = cdiv(N, 2048);
    k_scan1<<<nb1, 256, 0, stream>>>(deg, A, bsum, N);
    k_scan2<<<1, 256, 0, stream>>>(bsum, nb1);
    k_scan3<<<512, 256, 0, stream>>>(A, bsum, N);
    k_fillpk<<<1024, 256, 0, stream>>>(edge1, edge1 + E1, E1, pk, A, csr);
    k_conv1<TO><<<2048, 256, 0, stream>>>(x, A, csr, H1pre, b1, out1, sum1, sq1, N, V);

    // ---- norm1 + relu + per-node GEMM -> R,S ----
    k_norm_final<<<1, 64, 0, stream>>>(sum1, sq1, n1a, n1g, n1b, A1, B1, N);
    k_RS<TO><<<1024, 256, 0, stream>>>(out1, A1, B1, W2, RS, N);

    // ---- conv2 CSR build ----
    hipMemsetAsync(deg, 0, (size_t)L * 4, stream);
    k_deg<<<1024, 256, 0, stream>>>(edge2 + E2, E2, deg);
    int nb2 = cdiv(L, 2048);
    k_scan1<<<nb2, 256, 0, stream>>>(deg, A, bsum, L);
    k_scan2<<<1, 256, 0, stream>>>(bsum, nb2);
    k_scan3<<<512, 256, 0, stream>>>(A, bsum, L);
    k_fill<<<1024, 256, 0, stream>>>(edge2, edge2 + E2, E2, A, csr);

    // ---- gather h2ps (overwrites out1 region) + aggregate (overwrites RS region) ----
    k_h2g<<<2048, 256, 0, stream>>>(pos1, RS, deg, h2ps, L);
    k_conv2<TO><<<2048, 256, 0, stream>>>(A, csr, h2ps, b2, out2, sum2, sq2, L);

    // ---- norm2 + relu + prediction ----
    k_norm_final<<<1, 64, 0, stream>>>(sum2, sq2, n2a, n2g, n2b, A2, B2, L);
    k_final<TO><<<cdiv(P, 4), 256, 0, stream>>>(pos2, out2, A2, B2, pW, pb, d_out, P);
}

extern "C" void kernel_launch(void* const* d_in, const int* in_sizes, int n_in,
                              void* d_out, int out_size, void* d_ws, size_t ws_size,
                              hipStream_t stream) {
    const int*   x     = (const int*)d_in[0];
    const int*   edge1 = (const int*)d_in[1];
    const int*   edge2 = (const int*)d_in[2];
    const int*   pos1  = (const int*)d_in[3];
    const int*   pos2  = (const int*)d_in[4];
    const float* emb   = (const float*)d_in[5];
    const float* n0a   = (const float*)d_in[6];
    const float* n0g   = (const float*)d_in[7];
    const float* n0b   = (const float*)d_in[8];
    const float* W1    = (const float*)d_in[9];
    const float* b1    = (const float*)d_in[10];
    const float* n1a   = (const float*)d_in[11];
    const float* n1g   = (const float*)d_in[12];
    const float* n1b   = (const float*)d_in[13];
    const float* W2    = (const float*)d_in[14];
    const float* b2    = (const float*)d_in[15];
    const float* n2a   = (const float*)d_in[16];
    const float* n2g   = (const float*)d_in[17];
    const float* n2b   = (const float*)d_in[18];
    const float* pW    = (const float*)d_in[19];
    const float* pb    = (const float*)d_in[20];

    int N  = in_sizes[0];
    int E1 = in_sizes[1] / 2;
    int E2 = in_sizes[2] / 2;
    int L  = in_sizes[3] / 2;
    int P  = in_sizes[4];
    int V  = in_sizes[5] / 64;
    int Emax = (E1 > E2) ? E1 : E2;
    (void)n_in; (void)out_size;

    auto a256 = [](size_t s) { return (s + 255) & ~(size_t)255; };
    auto mx = [](size_t a, size_t b) { return a > b ? a : b; };

    size_t fixed = a256((size_t)V * 4) + a256(640 * 4) + a256((size_t)V * 64 * 4) +
                   a256(1024 * 4) + a256((size_t)N * 4) +
                   a256((size_t)(L + 1) * 4) + a256((size_t)(L + 1) * 4) +
                   a256((size_t)Emax * 4);
    size_t r1_pri = a256(mx((size_t)N * 64 * 4, (size_t)L * 64 * 2));
    size_t r2_pri = a256(mx((size_t)N * 128 * 4, (size_t)L * 64 * 4));
    size_t r1_fb  = a256(mx((size_t)N * 64 * 2, (size_t)L * 64 * 2));
    size_t r2_fb  = a256(mx((size_t)N * 128 * 4, (size_t)L * 64 * 2));
    size_t need_pri = fixed + r1_pri + r2_pri;
    bool primary = (ws_size >= need_pri);
    size_t r1 = primary ? r1_pri : r1_fb;
    size_t r2 = primary ? r2_pri : r2_fb;

    char* w = (char*)d_ws;
    size_t off = 0;
    auto alloc = [&](size_t bytes) { void* p = w + off; off += (bytes + 255) & ~(size_t)255; return p; };

    int*   cnt   = (int*)alloc((size_t)V * 4);
    float* stats = (float*)alloc(640 * 4);
    float* H1pre = (float*)alloc((size_t)V * 64 * 4);
    int*   bsum  = (int*)alloc(1024 * 4);
    int*   pk    = (int*)alloc((size_t)N * 4);
    int*   deg   = (int*)alloc((size_t)(L + 1) * 4);
    int*   A     = (int*)alloc((size_t)(L + 1) * 4);
    int*   csr   = (int*)alloc((size_t)Emax * 4);
    void*  region1 = alloc(r1);
    void*  region2 = alloc(r2);

    if (primary) {
        run_pipeline<float>(x, edge1, edge2, pos1, pos2, emb, n0a, n0g, n0b,
                            W1, b1, n1a, n1g, n1b, W2, b2, n2a, n2g, n2b, pW, pb,
                            N, E1, E2, L, P, V, cnt, stats, H1pre, bsum,
                            pk, deg, A, csr, region1, region2,
                            (float*)d_out, stream);
    } else {
        run_pipeline<__hip_bfloat16>(x, edge1, edge2, pos1, pos2, emb, n0a, n0g, n0b,
                            W1, b1, n1a, n1g, n1b, W2, b2, n2a, n2g, n2b, pW, pb,
                            N, E1, E2, L, P, V, cnt, stats, H1pre, bsum,
                            pk, deg, A, csr, region1, region2,
                            (float*)d_out, stream);
    }
}

// Round 9
// 1443.627 us; speedup vs baseline: 1.6576x; 1.0155x over previous
//
#include <hip/hip_runtime.h>
#include <hip/hip_bf16.h>

typedef long long ll;
static inline int cdiv(int a, int b) { return (a + b - 1) / b; }

__device__ __forceinline__ float ldf(const float* p) { return *p; }
__device__ __forceinline__ float ldf(const __hip_bfloat16* p) { return __bfloat162float(*p); }
__device__ __forceinline__ void stf(float* p, float v) { *p = v; }
__device__ __forceinline__ void stf(__hip_bfloat16* p, float v) { *p = __float2bfloat16(v); }

__device__ __forceinline__ float b2f(unsigned short u) {
    return __int_as_float(((unsigned int)u) << 16);
}
__device__ __forceinline__ unsigned short f2b(float f) {
    __hip_bfloat16 h = __float2bfloat16(f);
    return *reinterpret_cast<unsigned short*>(&h);
}

__device__ __forceinline__ void st4(float* p, float v0, float v1, float v2, float v3) {
    float4 v = make_float4(v0, v1, v2, v3);
    *reinterpret_cast<float4*>(p) = v;
}
__device__ __forceinline__ void st4(__hip_bfloat16* p, float v0, float v1, float v2, float v3) {
    ushort4 v;
    v.x = f2b(v0); v.y = f2b(v1); v.z = f2b(v2); v.w = f2b(v3);
    *reinterpret_cast<ushort4*>(p) = v;
}

__device__ __forceinline__ float bcastf(float v, int j) {
    return __int_as_float(__builtin_amdgcn_readlane(__float_as_int(v), j));
}

// ------- fused: histogram of x (blocks [0,HB)) | deg1 over dst1 ILP4 (blocks [HB,..)) -------
__global__ void k_hist_deg(const int* __restrict__ x, int N, int* __restrict__ cnt, int V,
                           const int* __restrict__ dst1, int E1, int* __restrict__ deg, int HB) {
    __shared__ int lc[128];
    if ((int)blockIdx.x < HB) {
        for (int i = threadIdx.x; i < V; i += blockDim.x) lc[i] = 0;
        __syncthreads();
        int stride = HB * blockDim.x;
        for (int i = blockIdx.x * blockDim.x + threadIdx.x; i < N; i += stride)
            atomicAdd(&lc[x[i]], 1);
        __syncthreads();
        for (int i = threadIdx.x; i < V; i += blockDim.x) atomicAdd(&cnt[i], lc[i]);
    } else {
        int rb = blockIdx.x - HB;
        int T = (gridDim.x - HB) * blockDim.x;
        int e = rb * blockDim.x + threadIdx.x;
        for (; e + 3 * T < E1; e += 4 * T) {
            int d0 = dst1[e], d1 = dst1[e + T], d2 = dst1[e + 2 * T], d3 = dst1[e + 3 * T];
            atomicAdd(&deg[d0], 1); atomicAdd(&deg[d1], 1);
            atomicAdd(&deg[d2], 1); atomicAdd(&deg[d3], 1);
        }
        for (; e < E1; e += T) atomicAdd(&deg[dst1[e]], 1);
    }
}

// ------- exact GraphNorm0 from histogram + fold into W1: H1pre = T0 @ W1 -------
__global__ void k_table(const int* __restrict__ cnt, const float* __restrict__ emb,
                        const float* __restrict__ n0a, const float* __restrict__ n0g,
                        const float* __restrict__ n0b, const float* __restrict__ W1,
                        float* __restrict__ H1pre, int N, int V) {
    __shared__ float T0[101 * 64];
    __shared__ float W1l[64 * 64];
    __shared__ float A0[64], B0[64];
    __shared__ float rs[256], rq[256];
    __shared__ float cf[128];
    int t = threadIdx.x;
    for (int i = t; i < V; i += 256) cf[i] = (float)cnt[i];
    __syncthreads();
    int d = t & 63, g = t >> 6;
    float s = 0.f, q = 0.f;
    for (int v = g; v < V; v += 4) {
        float c = cf[v]; float e = emb[v * 64 + d];
        s += c * e; q += c * e * e;
    }
    rs[t] = s; rq[t] = q;
    __syncthreads();
    if (t < 64) {
        float sum = rs[t] + rs[t + 64] + rs[t + 128] + rs[t + 192];
        float sq  = rq[t] + rq[t + 64] + rq[t + 128] + rq[t + 192];
        float invN = 1.0f / (float)N;
        float m = sum * invN;
        float a = n0a[t];
        float var = sq * invN - (2.0f * a - a * a) * m * m;
        float A = n0g[t] * rsqrtf(var + 1e-5f);
        A0[t] = A; B0[t] = n0b[t] - A * a * m;
    }
    __syncthreads();
    for (int i = t; i < V * 64; i += 256) {
        int dd = i & 63;
        T0[i] = A0[dd] * emb[i] + B0[dd];
    }
    for (int i = t; i < 64 * 64; i += 256) W1l[i] = W1[i];
    __syncthreads();
    for (int o = t; o < V * 64; o += 256) {
        int v = o >> 6, dd = o & 63;
        float acc = 0.f;
#pragma unroll 8
        for (int k = 0; k < 64; ++k) acc += T0[v * 64 + k] * W1l[k * 64 + dd];
        H1pre[o] = acc;
    }
}

// ---------------- pack (deg<<7)|x per node ----------------
__global__ void k_pack(const int* __restrict__ x, const int* __restrict__ deg,
                       int N, int* __restrict__ pk) {
    int i = blockIdx.x * blockDim.x + threadIdx.x;
    if (i < N) pk[i] = (deg[i] << 7) | x[i];
}

// ---------------- scan: per-block exclusive (2048 elems/block) ----------------
__global__ void k_scan1(const int* __restrict__ in, int* __restrict__ out,
                        int* __restrict__ bsum, int M) {
    __shared__ int ts[256];
    int t = threadIdx.x;
    int base = blockIdx.x * 2048 + t * 8;
    int v[8]; int s = 0;
#pragma unroll
    for (int j = 0; j < 8; ++j) { int idx = base + j; int val = (idx < M) ? in[idx] : 0; v[j] = val; s += val; }
    ts[t] = s; __syncthreads();
    for (int off = 1; off < 256; off <<= 1) {
        int xv = 0;
        if (t >= off) xv = ts[t - off];
        __syncthreads();
        ts[t] += xv;
        __syncthreads();
    }
    int incl = ts[t];
    int excl = incl - s;
    if (t == 255) bsum[blockIdx.x] = incl;
    int run = excl;
#pragma unroll
    for (int j = 0; j < 8; ++j) { int idx = base + j; if (idx < M) out[idx] = run; run += v[j]; }
}

// parallel exclusive scan of block sums (nb <= 256)
__global__ void k_scan2(int* __restrict__ bsum, int nb) {
    __shared__ int ts[256];
    int t = threadIdx.x;
    int v = (t < nb) ? bsum[t] : 0;
    ts[t] = v; __syncthreads();
    for (int off = 1; off < 256; off <<= 1) {
        int xv = 0;
        if (t >= off) xv = ts[t - off];
        __syncthreads();
        ts[t] += xv;
        __syncthreads();
    }
    if (t < nb) bsum[t] = ts[t] - v;
}

__global__ void k_scan3(int* __restrict__ A, const int* __restrict__ bsum, int M) {
    int stride = gridDim.x * blockDim.x;
    for (int i = blockIdx.x * blockDim.x + threadIdx.x; i < M; i += stride)
        A[i] += bsum[i >> 11];
}

// ------- fused: fillpk(E1) ILP4 (blocks [0,FB)) | deg2 over dst2 ILP4 (blocks [FB,..)) -------
__global__ void k_fillpk_deg(const int* __restrict__ src1, const int* __restrict__ dst1, int E1,
                             const int* __restrict__ pk, int* __restrict__ A, int* __restrict__ csr,
                             const int* __restrict__ dst2, int E2, int* __restrict__ deg2, int FB) {
    if ((int)blockIdx.x < FB) {
        int T = FB * blockDim.x;
        int e = blockIdx.x * blockDim.x + threadIdx.x;
        for (; e + 3 * T < E1; e += 4 * T) {
            int s0 = src1[e],         d0 = dst1[e];
            int s1 = src1[e + T],     d1 = dst1[e + T];
            int s2 = src1[e + 2 * T], d2 = dst1[e + 2 * T];
            int s3 = src1[e + 3 * T], d3 = dst1[e + 3 * T];
            int k0 = pk[s0], k1 = pk[s1], k2 = pk[s2], k3 = pk[s3];
            int p0 = atomicAdd(&A[d0], 1);
            int p1 = atomicAdd(&A[d1], 1);
            int p2 = atomicAdd(&A[d2], 1);
            int p3 = atomicAdd(&A[d3], 1);
            csr[p0] = k0; csr[p1] = k1; csr[p2] = k2; csr[p3] = k3;
        }
        for (; e < E1; e += T) {
            int d = dst1[e];
            int p = atomicAdd(&A[d], 1);
            csr[p] = pk[src1[e]];
        }
    } else {
        int rb = blockIdx.x - FB;
        int T = (gridDim.x - FB) * blockDim.x;
        int e = rb * blockDim.x + threadIdx.x;
        for (; e + 3 * T < E2; e += 4 * T) {
            int d0 = dst2[e], d1 = dst2[e + T], d2 = dst2[e + 2 * T], d3 = dst2[e + 3 * T];
            atomicAdd(&deg2[d0], 1); atomicAdd(&deg2[d1], 1);
            atomicAdd(&deg2[d2], 1); atomicAdd(&deg2[d3], 1);
        }
        for (; e < E2; e += T) atomicAdd(&deg2[dst2[e]], 1);
    }
}

// ---------------- CSR fill storing src index, ILP4 ----------------
__global__ void k_fill(const int* __restrict__ src, const int* __restrict__ dst, int E,
                       int* __restrict__ A, int* __restrict__ csr) {
    int T = gridDim.x * blockDim.x;
    int e = blockIdx.x * blockDim.x + threadIdx.x;
    for (; e + 3 * T < E; e += 4 * T) {
        int s0 = src[e],         d0 = dst[e];
        int s1 = src[e + T],     d1 = dst[e + T];
        int s2 = src[e + 2 * T], d2 = dst[e + 2 * T];
        int s3 = src[e + 3 * T], d3 = dst[e + 3 * T];
        int p0 = atomicAdd(&A[d0], 1);
        int p1 = atomicAdd(&A[d1], 1);
        int p2 = atomicAdd(&A[d2], 1);
        int p3 = atomicAdd(&A[d3], 1);
        csr[p0] = s0; csr[p1] = s1; csr[p2] = s2; csr[p3] = s3;
    }
    for (; e < E; e += T) {
        int d = dst[e];
        int p = atomicAdd(&A[d], 1);
        csr[p] = src[e];
    }
}

// ------- conv1: wave/node, 4 edges/iter (16-lane groups), LDS table stride 68 -------
template <typename TO>
__global__ __launch_bounds__(256) void k_conv1(
        const int* __restrict__ x, const int* __restrict__ A, const int* __restrict__ csrpk,
        const float* __restrict__ H1pre, const float* __restrict__ b1,
        TO* __restrict__ out1, float* __restrict__ gsum, float* __restrict__ gsq,
        int N, int V) {
    __shared__ float Hl[101 * 68];
    __shared__ float redS[4][64], redQ[4][64];
    for (int i = threadIdx.x; i < V * 64; i += 256) {
        int row = i >> 6, col = i & 63;
        Hl[row * 68 + col] = H1pre[i];
    }
    __syncthreads();
    int wid = threadIdx.x >> 6, lane = threadIdx.x & 63;
    int g = lane >> 4, q = lane & 15;
    float4 b1v = *reinterpret_cast<const float4*>(&b1[4 * q]);
    float s0 = 0.f, s1 = 0.f, s2 = 0.f, s3 = 0.f;
    float q0 = 0.f, q1 = 0.f, q2 = 0.f, q3 = 0.f;
    for (int node = blockIdx.x * 4 + wid; node < N; node += gridDim.x * 4) {
        int re = A[node], rs0 = node ? A[node - 1] : 0;
        float a0 = 0.f, a1 = 0.f, a2 = 0.f, a3 = 0.f;
        int pkcur = -1;
        { int e = rs0 + g; if (e < re) pkcur = csrpk[e]; }
        for (int c = rs0; c < re; c += 4) {
            int pknxt = -1;
            { int en = c + 4 + g; if (en < re) pknxt = csrpk[en]; }
            if (pkcur >= 0) {
                float dv = rsqrtf((float)(pkcur >> 7) + 1.0f);
                const float4 hv = *reinterpret_cast<const float4*>(&Hl[(pkcur & 127) * 68 + 4 * q]);
                a0 += dv * hv.x; a1 += dv * hv.y; a2 += dv * hv.z; a3 += dv * hv.w;
            }
            pkcur = pknxt;
        }
        a0 += __shfl_xor(a0, 16); a1 += __shfl_xor(a1, 16);
        a2 += __shfl_xor(a2, 16); a3 += __shfl_xor(a3, 16);
        a0 += __shfl_xor(a0, 32); a1 += __shfl_xor(a1, 32);
        a2 += __shfl_xor(a2, 32); a3 += __shfl_xor(a3, 32);
        float degf = (float)(re - rs0) + 1.0f;
        float sc = rsqrtf(degf), si = 1.0f / degf;
        const float4 sv = *reinterpret_cast<const float4*>(&Hl[x[node] * 68 + 4 * q]);
        float v0 = sc * a0 + sv.x * si + b1v.x;
        float v1 = sc * a1 + sv.y * si + b1v.y;
        float v2 = sc * a2 + sv.z * si + b1v.z;
        float v3 = sc * a3 + sv.w * si + b1v.w;
        if (g == 0) {
            st4(&out1[(ll)node * 64 + 4 * q], v0, v1, v2, v3);
            s0 += v0; s1 += v1; s2 += v2; s3 += v3;
            q0 += v0 * v0; q1 += v1 * v1; q2 += v2 * v2; q3 += v3 * v3;
        }
    }
    if (g == 0) {
        redS[wid][4 * q] = s0; redS[wid][4 * q + 1] = s1; redS[wid][4 * q + 2] = s2; redS[wid][4 * q + 3] = s3;
        redQ[wid][4 * q] = q0; redQ[wid][4 * q + 1] = q1; redQ[wid][4 * q + 2] = q2; redQ[wid][4 * q + 3] = q3;
    }
    __syncthreads();
    int t = threadIdx.x;
    if (t < 64) {
        atomicAdd(&gsum[t], redS[0][t] + redS[1][t] + redS[2][t] + redS[3][t]);
        atomicAdd(&gsq[t],  redQ[0][t] + redQ[1][t] + redQ[2][t] + redQ[3][t]);
    }
}

__global__ void k_norm_final(const float* __restrict__ gsum, const float* __restrict__ gsq,
                             const float* __restrict__ na, const float* __restrict__ ng,
                             const float* __restrict__ nbb,
                             float* __restrict__ A, float* __restrict__ B, int M) {
    int t = threadIdx.x;
    if (t < 64) {
        float invM = 1.0f / (float)M;
        float m = gsum[t] * invM;
        float a = na[t];
        float var = gsq[t] * invM - (2.0f * a - a * a) * m * m;
        float Av = ng[t] * rsqrtf(var + 1e-5f);
        A[t] = Av; B[t] = nbb[t] - Av * a * m;
    }
}

// ------- RS GEMM: W2 (64x128) held in VGPRs, readlane broadcast -------
template <typename TO>
__global__ __launch_bounds__(256, 2) void k_RS(
        const TO* __restrict__ out1, const float* __restrict__ A1, const float* __restrict__ B1,
        const float* __restrict__ W2, float* __restrict__ RS, int N) {
    int wid = threadIdx.x >> 6, lane = threadIdx.x & 63;
    float Al = A1[lane], Bl = B1[lane];
    float wx[64], wy[64];
#pragma unroll
    for (int k = 0; k < 64; ++k) {
        wx[k] = W2[k * 64 + lane];
        wy[k] = W2[(64 + k) * 64 + lane];
    }
    for (int node = blockIdx.x * 4 + wid; node < N; node += gridDim.x * 4) {
        float v = fmaxf(Al * ldf(&out1[(ll)node * 64 + lane]) + Bl, 0.f);
        float ar = 0.f, asv = 0.f;
#pragma unroll
        for (int k = 0; k < 64; ++k) {
            float hv = bcastf(v, k);
            ar  += hv * wx[k];
            asv += hv * wy[k];
        }
        RS[(ll)node * 128 + lane] = ar;
        RS[(ll)node * 128 + 64 + lane] = asv;
    }
}

// ------- gather: h2ps[l] = dinv2[l]*(R[p0]+S[p1]) bf16; 4 pairs per wave-iter -------
__global__ __launch_bounds__(256) void k_h2g(
        const int* __restrict__ pos1, const float* __restrict__ RS,
        const int* __restrict__ deg2, unsigned short* __restrict__ h2ps, int L) {
    int wv = (blockIdx.x * 4) + (threadIdx.x >> 6);
    int nw = gridDim.x * 4;
    int lane = threadIdx.x & 63;
    int g = lane >> 4, q = lane & 15;
    for (int base = wv * 4; base < L; base += nw * 4) {
        int l = base + g;
        if (l < L) {
            int p0 = pos1[2 * l], p1 = pos1[2 * l + 1];
            float dv = rsqrtf((float)deg2[l] + 1.0f);
            const float4 r = *reinterpret_cast<const float4*>(&RS[(ll)p0 * 128 + 4 * q]);
            const float4 s = *reinterpret_cast<const float4*>(&RS[(ll)p1 * 128 + 64 + 4 * q]);
            ushort4 o;
            o.x = f2b(dv * (r.x + s.x));
            o.y = f2b(dv * (r.y + s.y));
            o.z = f2b(dv * (r.z + s.z));
            o.w = f2b(dv * (r.w + s.w));
            *reinterpret_cast<ushort4*>(&h2ps[(ll)l * 64 + 4 * q]) = o;
        }
    }
}

// ------- conv2: 4 edges/iter, ushort4 row-gathers, rotate prefetch -------
template <typename TO>
__global__ __launch_bounds__(256) void k_conv2(
        const int* __restrict__ A, const int* __restrict__ csr,
        const unsigned short* __restrict__ h2ps, const float* __restrict__ b2,
        TO* __restrict__ out2, float* __restrict__ gsum, float* __restrict__ gsq, int L) {
    __shared__ float redS[4][64], redQ[4][64];
    int wid = threadIdx.x >> 6, lane = threadIdx.x & 63;
    int g = lane >> 4, q = lane & 15;
    float4 b2v = *reinterpret_cast<const float4*>(&b2[4 * q]);
    float s0 = 0.f, s1 = 0.f, s2 = 0.f, s3 = 0.f;
    float q0 = 0.f, q1 = 0.f, q2 = 0.f, q3 = 0.f;
    for (int node = blockIdx.x * 4 + wid; node < L; node += gridDim.x * 4) {
        int re = A[node], rs0 = node ? A[node - 1] : 0;
        float a0 = 0.f, a1 = 0.f, a2 = 0.f, a3 = 0.f;
        ushort4 cur = make_ushort4(0, 0, 0, 0);
        { int e = rs0 + g; if (e < re) cur = *reinterpret_cast<const ushort4*>(&h2ps[(ll)csr[e] * 64 + 4 * q]); }
        for (int c = rs0; c < re; c += 4) {
            ushort4 nxt = make_ushort4(0, 0, 0, 0);
            { int en = c + 4 + g; if (en < re) nxt = *reinterpret_cast<const ushort4*>(&h2ps[(ll)csr[en] * 64 + 4 * q]); }
            a0 += b2f(cur.x); a1 += b2f(cur.y); a2 += b2f(cur.z); a3 += b2f(cur.w);
            cur = nxt;
        }
        a0 += __shfl_xor(a0, 16); a1 += __shfl_xor(a1, 16);
        a2 += __shfl_xor(a2, 16); a3 += __shfl_xor(a3, 16);
        a0 += __shfl_xor(a0, 32); a1 += __shfl_xor(a1, 32);
        a2 += __shfl_xor(a2, 32); a3 += __shfl_xor(a3, 32);
        float degf = (float)(re - rs0) + 1.0f;
        float sc = rsqrtf(degf);
        const ushort4 sv = *reinterpret_cast<const ushort4*>(&h2ps[(ll)node * 64 + 4 * q]);
        float v0 = sc * (a0 + b2f(sv.x)) + b2v.x;
        float v1 = sc * (a1 + b2f(sv.y)) + b2v.y;
        float v2 = sc * (a2 + b2f(sv.z)) + b2v.z;
        float v3 = sc * (a3 + b2f(sv.w)) + b2v.w;
        if (g == 0) {
            st4(&out2[(ll)node * 64 + 4 * q], v0, v1, v2, v3);
            s0 += v0; s1 += v1; s2 += v2; s3 += v3;
            q0 += v0 * v0; q1 += v1 * v1; q2 += v2 * v2; q3 += v3 * v3;
        }
    }
    if (g == 0) {
        redS[wid][4 * q] = s0; redS[wid][4 * q + 1] = s1; redS[wid][4 * q + 2] = s2; redS[wid][4 * q + 3] = s3;
        redQ[wid][4 * q] = q0; redQ[wid][4 * q + 1] = q1; redQ[wid][4 * q + 2] = q2; redQ[wid][4 * q + 3] = q3;
    }
    __syncthreads();
    int t = threadIdx.x;
    if (t < 64) {
        atomicAdd(&gsum[t], redS[0][t] + redS[1][t] + redS[2][t] + redS[3][t]);
        atomicAdd(&gsq[t],  redQ[0][t] + redQ[1][t] + redQ[2][t] + redQ[3][t]);
    }
}

// ------- fused norm2+relu+prediction dot -------
template <typename TO>
__global__ void k_final(const int* __restrict__ pos2, const TO* __restrict__ out2,
                        const float* __restrict__ A, const float* __restrict__ B,
                        const float* __restrict__ pW, const float* __restrict__ pb,
                        float* __restrict__ out, int P) {
    int wid = threadIdx.x >> 6, lane = threadIdx.x & 63;
    int p = blockIdx.x * 4 + wid;
    if (p >= P) return;
    int i = pos2[p];
    float v = ldf(&out2[(ll)i * 64 + lane]);
    v = fmaxf(A[lane] * v + B[lane], 0.f) * pW[lane];
    for (int off = 32; off; off >>= 1) v += __shfl_xor(v, off);
    if (lane == 0) out[p] = v + pb[0];
}

// ---------------- templated pipeline ----------------
template <typename TO>
static void run_pipeline(const int* x, const int* edge1, const int* edge2,
                         const int* pos1, const int* pos2,
                         const float* emb, const float* n0a, const float* n0g, const float* n0b,
                         const float* W1, const float* b1,
                         const float* n1a, const float* n1g, const float* n1b,
                         const float* W2, const float* b2,
                         const float* n2a, const float* n2g, const float* n2b,
                         const float* pW, const float* pb,
                         int N, int E1, int E2, int L, int P, int V,
                         int* cnt, float* stats, float* H1pre, int* bsum,
                         int* pk, int* deg, int* A, int* csr,
                         void* region1, void* region2,
                         float* d_out, hipStream_t stream) {
    TO* out1 = (TO*)region1;
    unsigned short* h2ps = (unsigned short*)region1;   // aliases out1 (out1 dead by then)
    float* RS = (float*)region2;
    TO* out2  = (TO*)region2;                          // aliases RS (RS dead by then)

    float* sum1 = stats + 128; float* sq1 = stats + 192;
    float* A1   = stats + 256; float* B1  = stats + 320;
    float* sum2 = stats + 384; float* sq2 = stats + 448;
    float* A2   = stats + 512; float* B2  = stats + 576;

    hipMemsetAsync(cnt,   0, (size_t)V * 4, stream);
    hipMemsetAsync(stats, 0, 640 * 4, stream);
    hipMemsetAsync(deg,   0, (size_t)N * 4, stream);

    // ---- fused: x-histogram | deg1 (ILP4) ----
    k_hist_deg<<<256 + 1024, 256, 0, stream>>>(x, N, cnt, V, edge1 + E1, E1, deg, 256);
    k_table<<<1, 256, 0, stream>>>(cnt, emb, n0a, n0g, n0b, W1, H1pre, N, V);
    k_pack<<<cdiv(N, 256), 256, 0, stream>>>(x, deg, N, pk);

    int nb1 = cdiv(N, 2048);
    k_scan1<<<nb1, 256, 0, stream>>>(deg, A, bsum, N);
    k_scan2<<<1, 256, 0, stream>>>(bsum, nb1);
    k_scan3<<<512, 256, 0, stream>>>(A, bsum, N);

    // deg1 fully consumed (pack + scan) -> reuse for deg2
    hipMemsetAsync(deg, 0, (size_t)L * 4, stream);

    // ---- fused: fillpk(E1, ILP4) | deg2(E2, ILP4) ----
    k_fillpk_deg<<<2048, 256, 0, stream>>>(edge1, edge1 + E1, E1, pk, A, csr,
                                           edge2 + E2, E2, deg, 1024);
    k_conv1<TO><<<2048, 256, 0, stream>>>(x, A, csr, H1pre, b1, out1, sum1, sq1, N, V);
    k_norm_final<<<1, 64, 0, stream>>>(sum1, sq1, n1a, n1g, n1b, A1, B1, N);

    int nb2 = cdiv(L, 2048);
    k_scan1<<<nb2, 256, 0, stream>>>(deg, A, bsum, L);
    k_scan2<<<1, 256, 0, stream>>>(bsum, nb2);
    k_scan3<<<512, 256, 0, stream>>>(A, bsum, L);

    k_RS<TO><<<1024, 256, 0, stream>>>(out1, A1, B1, W2, RS, N);
    k_fill<<<2048, 256, 0, stream>>>(edge2, edge2 + E2, E2, A, csr);

    k_h2g<<<2048, 256, 0, stream>>>(pos1, RS, deg, h2ps, L);
    k_conv2<TO><<<2048, 256, 0, stream>>>(A, csr, h2ps, b2, out2, sum2, sq2, L);

    k_norm_final<<<1, 64, 0, stream>>>(sum2, sq2, n2a, n2g, n2b, A2, B2, L);
    k_final<TO><<<cdiv(P, 4), 256, 0, stream>>>(pos2, out2, A2, B2, pW, pb, d_out, P);
}

extern "C" void kernel_launch(void* const* d_in, const int* in_sizes, int n_in,
                              void* d_out, int out_size, void* d_ws, size_t ws_size,
                              hipStream_t stream) {
    const int*   x     = (const int*)d_in[0];
    const int*   edge1 = (const int*)d_in[1];
    const int*   edge2 = (const int*)d_in[2];
    const int*   pos1  = (const int*)d_in[3];
    const int*   pos2  = (const int*)d_in[4];
    const float* emb   = (const float*)d_in[5];
    const float* n0a   = (const float*)d_in[6];
    const float* n0g   = (const float*)d_in[7];
    const float* n0b   = (const float*)d_in[8];
    const float* W1    = (const float*)d_in[9];
    const float* b1    = (const float*)d_in[10];
    const float* n1a   = (const float*)d_in[11];
    const float* n1g   = (const float*)d_in[12];
    const float* n1b   = (const float*)d_in[13];
    const float* W2    = (const float*)d_in[14];
    const float* b2    = (const float*)d_in[15];
    const float* n2a   = (const float*)d_in[16];
    const float* n2g   = (const float*)d_in[17];
    const float* n2b   = (const float*)d_in[18];
    const float* pW    = (const float*)d_in[19];
    const float* pb    = (const float*)d_in[20];

    int N  = in_sizes[0];
    int E1 = in_sizes[1] / 2;
    int E2 = in_sizes[2] / 2;
    int L  = in_sizes[3] / 2;
    int P  = in_sizes[4];
    int V  = in_sizes[5] / 64;
    int Emax = (E1 > E2) ? E1 : E2;
    (void)n_in; (void)out_size;

    auto a256 = [](size_t s) { return (s + 255) & ~(size_t)255; };
    auto mx = [](size_t a, size_t b) { return a > b ? a : b; };

    size_t fixed = a256((size_t)V * 4) + a256(640 * 4) + a256((size_t)V * 64 * 4) +
                   a256(1024 * 4) + a256((size_t)N * 4) +
                   a256((size_t)(L + 1) * 4) + a256((size_t)(L + 1) * 4) +
                   a256((size_t)Emax * 4);
    size_t r1_pri = a256(mx((size_t)N * 64 * 4, (size_t)L * 64 * 2));
    size_t r2_pri = a256(mx((size_t)N * 128 * 4, (size_t)L * 64 * 4));
    size_t r1_fb  = a256(mx((size_t)N * 64 * 2, (size_t)L * 64 * 2));
    size_t r2_fb  = a256(mx((size_t)N * 128 * 4, (size_t)L * 64 * 2));
    size_t need_pri = fixed + r1_pri + r2_pri;
    bool primary = (ws_size >= need_pri);
    size_t r1 = primary ? r1_pri : r1_fb;
    size_t r2 = primary ? r2_pri : r2_fb;

    char* w = (char*)d_ws;
    size_t off = 0;
    auto alloc = [&](size_t bytes) { void* p = w + off; off += (bytes + 255) & ~(size_t)255; return p; };

    int*   cnt   = (int*)alloc((size_t)V * 4);
    float* stats = (float*)alloc(640 * 4);
    float* H1pre = (float*)alloc((size_t)V * 64 * 4);
    int*   bsum  = (int*)alloc(1024 * 4);
    int*   pk    = (int*)alloc((size_t)N * 4);
    int*   deg   = (int*)alloc((size_t)(L + 1) * 4);
    int*   A     = (int*)alloc((size_t)(L + 1) * 4);
    int*   csr   = (int*)alloc((size_t)Emax * 4);
    void*  region1 = alloc(r1);
    void*  region2 = alloc(r2);

    if (primary) {
        run_pipeline<float>(x, edge1, edge2, pos1, pos2, emb, n0a, n0g, n0b,
                            W1, b1, n1a, n1g, n1b, W2, b2, n2a, n2g, n2b, pW, pb,
                            N, E1, E2, L, P, V, cnt, stats, H1pre, bsum,
                            pk, deg, A, csr, region1, region2,
                            (float*)d_out, stream);
    } else {
        run_pipeline<__hip_bfloat16>(x, edge1, edge2, pos1, pos2, emb, n0a, n0g, n0b,
                            W1, b1, n1a, n1g, n1b, W2, b2, n2a, n2g, n2b, pW, pb,
                            N, E1, E2, L, P, V, cnt, stats, H1pre, bsum,
                            pk, deg, A, csr, region1, region2,
                            (float*)d_out, stream);
    }
}

// Round 10
// 1297.314 us; speedup vs baseline: 1.8445x; 1.1128x over previous
//
#include <hip/hip_runtime.h>
#include <hip/hip_bf16.h>

typedef long long ll;
static inline int cdiv(int a, int b) { return (a + b - 1) / b; }

__device__ __forceinline__ float ldf(const float* p) { return *p; }
__device__ __forceinline__ float ldf(const __hip_bfloat16* p) { return __bfloat162float(*p); }
__device__ __forceinline__ void stf(float* p, float v) { *p = v; }
__device__ __forceinline__ void stf(__hip_bfloat16* p, float v) { *p = __float2bfloat16(v); }

__device__ __forceinline__ float b2f(unsigned short u) {
    return __int_as_float(((unsigned int)u) << 16);
}
__device__ __forceinline__ unsigned short f2b(float f) {
    __hip_bfloat16 h = __float2bfloat16(f);
    return *reinterpret_cast<unsigned short*>(&h);
}

__device__ __forceinline__ void st4(float* p, float v0, float v1, float v2, float v3) {
    float4 v = make_float4(v0, v1, v2, v3);
    *reinterpret_cast<float4*>(p) = v;
}
__device__ __forceinline__ void st4(__hip_bfloat16* p, float v0, float v1, float v2, float v3) {
    ushort4 v;
    v.x = f2b(v0); v.y = f2b(v1); v.z = f2b(v2); v.w = f2b(v3);
    *reinterpret_cast<ushort4*>(p) = v;
}

__device__ __forceinline__ float bcastf(float v, int j) {
    return __int_as_float(__builtin_amdgcn_readlane(__float_as_int(v), j));
}

// ------- fused: histogram of x (blocks [0,HB)) | deg1 over dst1 ILP4 (blocks [HB,..)) -------
__global__ void k_hist_deg(const int* __restrict__ x, int N, int* __restrict__ cnt, int V,
                           const int* __restrict__ dst1, int E1, int* __restrict__ deg, int HB) {
    __shared__ int lc[128];
    if ((int)blockIdx.x < HB) {
        for (int i = threadIdx.x; i < V; i += blockDim.x) lc[i] = 0;
        __syncthreads();
        int stride = HB * blockDim.x;
        for (int i = blockIdx.x * blockDim.x + threadIdx.x; i < N; i += stride)
            atomicAdd(&lc[x[i]], 1);
        __syncthreads();
        for (int i = threadIdx.x; i < V; i += blockDim.x) atomicAdd(&cnt[i], lc[i]);
    } else {
        int rb = blockIdx.x - HB;
        int T = (gridDim.x - HB) * blockDim.x;
        int e = rb * blockDim.x + threadIdx.x;
        for (; e + 3 * T < E1; e += 4 * T) {
            int d0 = dst1[e], d1 = dst1[e + T], d2 = dst1[e + 2 * T], d3 = dst1[e + 3 * T];
            atomicAdd(&deg[d0], 1); atomicAdd(&deg[d1], 1);
            atomicAdd(&deg[d2], 1); atomicAdd(&deg[d3], 1);
        }
        for (; e < E1; e += T) atomicAdd(&deg[dst1[e]], 1);
    }
}

// ------- exact GraphNorm0 from histogram + fold into W1: H1pre = T0 @ W1 -------
__global__ void k_table(const int* __restrict__ cnt, const float* __restrict__ emb,
                        const float* __restrict__ n0a, const float* __restrict__ n0g,
                        const float* __restrict__ n0b, const float* __restrict__ W1,
                        float* __restrict__ H1pre, int N, int V) {
    __shared__ float T0[101 * 64];
    __shared__ float W1l[64 * 64];
    __shared__ float A0[64], B0[64];
    __shared__ float rs[256], rq[256];
    __shared__ float cf[128];
    int t = threadIdx.x;
    for (int i = t; i < V; i += 256) cf[i] = (float)cnt[i];
    __syncthreads();
    int d = t & 63, g = t >> 6;
    float s = 0.f, q = 0.f;
    for (int v = g; v < V; v += 4) {
        float c = cf[v]; float e = emb[v * 64 + d];
        s += c * e; q += c * e * e;
    }
    rs[t] = s; rq[t] = q;
    __syncthreads();
    if (t < 64) {
        float sum = rs[t] + rs[t + 64] + rs[t + 128] + rs[t + 192];
        float sq  = rq[t] + rq[t + 64] + rq[t + 128] + rq[t + 192];
        float invN = 1.0f / (float)N;
        float m = sum * invN;
        float a = n0a[t];
        float var = sq * invN - (2.0f * a - a * a) * m * m;
        float A = n0g[t] * rsqrtf(var + 1e-5f);
        A0[t] = A; B0[t] = n0b[t] - A * a * m;
    }
    __syncthreads();
    for (int i = t; i < V * 64; i += 256) {
        int dd = i & 63;
        T0[i] = A0[dd] * emb[i] + B0[dd];
    }
    for (int i = t; i < 64 * 64; i += 256) W1l[i] = W1[i];
    __syncthreads();
    for (int o = t; o < V * 64; o += 256) {
        int v = o >> 6, dd = o & 63;
        float acc = 0.f;
#pragma unroll 8
        for (int k = 0; k < 64; ++k) acc += T0[v * 64 + k] * W1l[k * 64 + dd];
        H1pre[o] = acc;
    }
}

// ---------------- pack (deg<<7)|x per node ----------------
__global__ void k_pack(const int* __restrict__ x, const int* __restrict__ deg,
                       int N, int* __restrict__ pk) {
    int i = blockIdx.x * blockDim.x + threadIdx.x;
    if (i < N) pk[i] = (deg[i] << 7) | x[i];
}

// ---------------- scan: per-block exclusive (2048 elems/block) ----------------
__global__ void k_scan1(const int* __restrict__ in, int* __restrict__ out,
                        int* __restrict__ bsum, int M) {
    __shared__ int ts[256];
    int t = threadIdx.x;
    int base = blockIdx.x * 2048 + t * 8;
    int v[8]; int s = 0;
#pragma unroll
    for (int j = 0; j < 8; ++j) { int idx = base + j; int val = (idx < M) ? in[idx] : 0; v[j] = val; s += val; }
    ts[t] = s; __syncthreads();
    for (int off = 1; off < 256; off <<= 1) {
        int xv = 0;
        if (t >= off) xv = ts[t - off];
        __syncthreads();
        ts[t] += xv;
        __syncthreads();
    }
    int incl = ts[t];
    int excl = incl - s;
    if (t == 255) bsum[blockIdx.x] = incl;
    int run = excl;
#pragma unroll
    for (int j = 0; j < 8; ++j) { int idx = base + j; if (idx < M) out[idx] = run; run += v[j]; }
}

// parallel exclusive scan of block sums (nb <= 256)
__global__ void k_scan2(int* __restrict__ bsum, int nb) {
    __shared__ int ts[256];
    int t = threadIdx.x;
    int v = (t < nb) ? bsum[t] : 0;
    ts[t] = v; __syncthreads();
    for (int off = 1; off < 256; off <<= 1) {
        int xv = 0;
        if (t >= off) xv = ts[t - off];
        __syncthreads();
        ts[t] += xv;
        __syncthreads();
    }
    if (t < nb) bsum[t] = ts[t] - v;
}

__global__ void k_scan3(int* __restrict__ A, const int* __restrict__ bsum, int M) {
    int stride = gridDim.x * blockDim.x;
    for (int i = blockIdx.x * blockDim.x + threadIdx.x; i < M; i += stride)
        A[i] += bsum[i >> 11];
}

// ------- fused: BUCKETED fillpk(E1) (blocks [0,FB)) | deg2 ILP4 (blocks [FB,..)) -------
// Multi-pass over buckets of dst (dst>>shift == k): per pass, csr writes land in an
// L2-resident ~1MB window -> 4B scatters coalesce in L2 instead of dirtying full lines.
__global__ void k_fillpk_b_deg(const int* __restrict__ src1, const int* __restrict__ dst1, int E1,
                               const int* __restrict__ pk, int* __restrict__ A, int* __restrict__ csr,
                               int shift, int nbk,
                               const int* __restrict__ dst2, int E2, int* __restrict__ deg2, int FB) {
    if ((int)blockIdx.x < FB) {
        int T = FB * blockDim.x;
        int tid = blockIdx.x * blockDim.x + threadIdx.x;
        int G4 = E1 >> 2;
        for (int k = 0; k < nbk; ++k) {
            for (int g = tid; g < G4; g += T) {
                const int4 d4 = *reinterpret_cast<const int4*>(&dst1[g * 4]);
                bool m0 = (d4.x >> shift) == k, m1 = (d4.y >> shift) == k;
                bool m2 = (d4.z >> shift) == k, m3 = (d4.w >> shift) == k;
                if (m0 | m1 | m2 | m3) {
                    const int4 s4 = *reinterpret_cast<const int4*>(&src1[g * 4]);
                    if (m0) { int p = atomicAdd(&A[d4.x], 1); csr[p] = pk[s4.x]; }
                    if (m1) { int p = atomicAdd(&A[d4.y], 1); csr[p] = pk[s4.y]; }
                    if (m2) { int p = atomicAdd(&A[d4.z], 1); csr[p] = pk[s4.z]; }
                    if (m3) { int p = atomicAdd(&A[d4.w], 1); csr[p] = pk[s4.w]; }
                }
            }
        }
        if (tid == 0) {
            for (int e = G4 * 4; e < E1; ++e) {
                int d = dst1[e];
                int p = atomicAdd(&A[d], 1);
                csr[p] = pk[src1[e]];
            }
        }
    } else {
        int rb = blockIdx.x - FB;
        int T = (gridDim.x - FB) * blockDim.x;
        int e = rb * blockDim.x + threadIdx.x;
        for (; e + 3 * T < E2; e += 4 * T) {
            int d0 = dst2[e], d1 = dst2[e + T], d2 = dst2[e + 2 * T], d3 = dst2[e + 3 * T];
            atomicAdd(&deg2[d0], 1); atomicAdd(&deg2[d1], 1);
            atomicAdd(&deg2[d2], 1); atomicAdd(&deg2[d3], 1);
        }
        for (; e < E2; e += T) atomicAdd(&deg2[dst2[e]], 1);
    }
}

// ---------------- BUCKETED CSR fill storing src index ----------------
__global__ void k_fill_b(const int* __restrict__ src, const int* __restrict__ dst, int E,
                         int* __restrict__ A, int* __restrict__ csr, int shift, int nbk) {
    int T = gridDim.x * blockDim.x;
    int tid = blockIdx.x * blockDim.x + threadIdx.x;
    int G4 = E >> 2;
    for (int k = 0; k < nbk; ++k) {
        for (int g = tid; g < G4; g += T) {
            const int4 d4 = *reinterpret_cast<const int4*>(&dst[g * 4]);
            bool m0 = (d4.x >> shift) == k, m1 = (d4.y >> shift) == k;
            bool m2 = (d4.z >> shift) == k, m3 = (d4.w >> shift) == k;
            if (m0 | m1 | m2 | m3) {
                const int4 s4 = *reinterpret_cast<const int4*>(&src[g * 4]);
                if (m0) { int p = atomicAdd(&A[d4.x], 1); csr[p] = s4.x; }
                if (m1) { int p = atomicAdd(&A[d4.y], 1); csr[p] = s4.y; }
                if (m2) { int p = atomicAdd(&A[d4.z], 1); csr[p] = s4.z; }
                if (m3) { int p = atomicAdd(&A[d4.w], 1); csr[p] = s4.w; }
            }
        }
    }
    if (tid == 0) {
        for (int e = G4 * 4; e < E; ++e) {
            int d = dst[e];
            int p = atomicAdd(&A[d], 1);
            csr[p] = src[e];
        }
    }
}

// ------- conv1: wave/node, 4 edges/iter (16-lane groups), LDS table stride 68 -------
template <typename TO>
__global__ __launch_bounds__(256) void k_conv1(
        const int* __restrict__ x, const int* __restrict__ A, const int* __restrict__ csrpk,
        const float* __restrict__ H1pre, const float* __restrict__ b1,
        TO* __restrict__ out1, float* __restrict__ gsum, float* __restrict__ gsq,
        int N, int V) {
    __shared__ float Hl[101 * 68];
    __shared__ float redS[4][64], redQ[4][64];
    for (int i = threadIdx.x; i < V * 64; i += 256) {
        int row = i >> 6, col = i & 63;
        Hl[row * 68 + col] = H1pre[i];
    }
    __syncthreads();
    int wid = threadIdx.x >> 6, lane = threadIdx.x & 63;
    int g = lane >> 4, q = lane & 15;
    float4 b1v = *reinterpret_cast<const float4*>(&b1[4 * q]);
    float s0 = 0.f, s1 = 0.f, s2 = 0.f, s3 = 0.f;
    float q0 = 0.f, q1 = 0.f, q2 = 0.f, q3 = 0.f;
    for (int node = blockIdx.x * 4 + wid; node < N; node += gridDim.x * 4) {
        int re = A[node], rs0 = node ? A[node - 1] : 0;
        float a0 = 0.f, a1 = 0.f, a2 = 0.f, a3 = 0.f;
        int pkcur = -1;
        { int e = rs0 + g; if (e < re) pkcur = csrpk[e]; }
        for (int c = rs0; c < re; c += 4) {
            int pknxt = -1;
            { int en = c + 4 + g; if (en < re) pknxt = csrpk[en]; }
            if (pkcur >= 0) {
                float dv = rsqrtf((float)(pkcur >> 7) + 1.0f);
                const float4 hv = *reinterpret_cast<const float4*>(&Hl[(pkcur & 127) * 68 + 4 * q]);
                a0 += dv * hv.x; a1 += dv * hv.y; a2 += dv * hv.z; a3 += dv * hv.w;
            }
            pkcur = pknxt;
        }
        a0 += __shfl_xor(a0, 16); a1 += __shfl_xor(a1, 16);
        a2 += __shfl_xor(a2, 16); a3 += __shfl_xor(a3, 16);
        a0 += __shfl_xor(a0, 32); a1 += __shfl_xor(a1, 32);
        a2 += __shfl_xor(a2, 32); a3 += __shfl_xor(a3, 32);
        float degf = (float)(re - rs0) + 1.0f;
        float sc = rsqrtf(degf), si = 1.0f / degf;
        const float4 sv = *reinterpret_cast<const float4*>(&Hl[x[node] * 68 + 4 * q]);
        float v0 = sc * a0 + sv.x * si + b1v.x;
        float v1 = sc * a1 + sv.y * si + b1v.y;
        float v2 = sc * a2 + sv.z * si + b1v.z;
        float v3 = sc * a3 + sv.w * si + b1v.w;
        if (g == 0) {
            st4(&out1[(ll)node * 64 + 4 * q], v0, v1, v2, v3);
            s0 += v0; s1 += v1; s2 += v2; s3 += v3;
            q0 += v0 * v0; q1 += v1 * v1; q2 += v2 * v2; q3 += v3 * v3;
        }
    }
    if (g == 0) {
        redS[wid][4 * q] = s0; redS[wid][4 * q + 1] = s1; redS[wid][4 * q + 2] = s2; redS[wid][4 * q + 3] = s3;
        redQ[wid][4 * q] = q0; redQ[wid][4 * q + 1] = q1; redQ[wid][4 * q + 2] = q2; redQ[wid][4 * q + 3] = q3;
    }
    __syncthreads();
    int t = threadIdx.x;
    if (t < 64) {
        atomicAdd(&gsum[t], redS[0][t] + redS[1][t] + redS[2][t] + redS[3][t]);
        atomicAdd(&gsq[t],  redQ[0][t] + redQ[1][t] + redQ[2][t] + redQ[3][t]);
    }
}

__global__ void k_norm_final(const float* __restrict__ gsum, const float* __restrict__ gsq,
                             const float* __restrict__ na, const float* __restrict__ ng,
                             const float* __restrict__ nbb,
                             float* __restrict__ A, float* __restrict__ B, int M) {
    int t = threadIdx.x;
    if (t < 64) {
        float invM = 1.0f / (float)M;
        float m = gsum[t] * invM;
        float a = na[t];
        float var = gsq[t] * invM - (2.0f * a - a * a) * m * m;
        float Av = ng[t] * rsqrtf(var + 1e-5f);
        A[t] = Av; B[t] = nbb[t] - Av * a * m;
    }
}

// ------- RS GEMM: W2 (64x128) held in VGPRs, readlane broadcast -------
template <typename TO>
__global__ __launch_bounds__(256, 2) void k_RS(
        const TO* __restrict__ out1, const float* __restrict__ A1, const float* __restrict__ B1,
        const float* __restrict__ W2, float* __restrict__ RS, int N) {
    int wid = threadIdx.x >> 6, lane = threadIdx.x & 63;
    float Al = A1[lane], Bl = B1[lane];
    float wx[64], wy[64];
#pragma unroll
    for (int k = 0; k < 64; ++k) {
        wx[k] = W2[k * 64 + lane];
        wy[k] = W2[(64 + k) * 64 + lane];
    }
    for (int node = blockIdx.x * 4 + wid; node < N; node += gridDim.x * 4) {
        float v = fmaxf(Al * ldf(&out1[(ll)node * 64 + lane]) + Bl, 0.f);
        float ar = 0.f, asv = 0.f;
#pragma unroll
        for (int k = 0; k < 64; ++k) {
            float hv = bcastf(v, k);
            ar  += hv * wx[k];
            asv += hv * wy[k];
        }
        RS[(ll)node * 128 + lane] = ar;
        RS[(ll)node * 128 + 64 + lane] = asv;
    }
}

// ------- gather: h2ps[l] = dinv2[l]*(R[p0]+S[p1]) bf16; 4 pairs per wave-iter -------
__global__ __launch_bounds__(256) void k_h2g(
        const int* __restrict__ pos1, const float* __restrict__ RS,
        const int* __restrict__ deg2, unsigned short* __restrict__ h2ps, int L) {
    int wv = (blockIdx.x * 4) + (threadIdx.x >> 6);
    int nw = gridDim.x * 4;
    int lane = threadIdx.x & 63;
    int g = lane >> 4, q = lane & 15;
    for (int base = wv * 4; base < L; base += nw * 4) {
        int l = base + g;
        if (l < L) {
            int p0 = pos1[2 * l], p1 = pos1[2 * l + 1];
            float dv = rsqrtf((float)deg2[l] + 1.0f);
            const float4 r = *reinterpret_cast<const float4*>(&RS[(ll)p0 * 128 + 4 * q]);
            const float4 s = *reinterpret_cast<const float4*>(&RS[(ll)p1 * 128 + 64 + 4 * q]);
            ushort4 o;
            o.x = f2b(dv * (r.x + s.x));
            o.y = f2b(dv * (r.y + s.y));
            o.z = f2b(dv * (r.z + s.z));
            o.w = f2b(dv * (r.w + s.w));
            *reinterpret_cast<ushort4*>(&h2ps[(ll)l * 64 + 4 * q]) = o;
        }
    }
}

// ------- conv2: 4 edges/iter, ushort4 row-gathers, rotate prefetch -------
template <typename TO>
__global__ __launch_bounds__(256) void k_conv2(
        const int* __restrict__ A, const int* __restrict__ csr,
        const unsigned short* __restrict__ h2ps, const float* __restrict__ b2,
        TO* __restrict__ out2, float* __restrict__ gsum, float* __restrict__ gsq, int L) {
    __shared__ float redS[4][64], redQ[4][64];
    int wid = threadIdx.x >> 6, lane = threadIdx.x & 63;
    int g = lane >> 4, q = lane & 15;
    float4 b2v = *reinterpret_cast<const float4*>(&b2[4 * q]);
    float s0 = 0.f, s1 = 0.f, s2 = 0.f, s3 = 0.f;
    float q0 = 0.f, q1 = 0.f, q2 = 0.f, q3 = 0.f;
    for (int node = blockIdx.x * 4 + wid; node < L; node += gridDim.x * 4) {
        int re = A[node], rs0 = node ? A[node - 1] : 0;
        float a0 = 0.f, a1 = 0.f, a2 = 0.f, a3 = 0.f;
        ushort4 cur = make_ushort4(0, 0, 0, 0);
        { int e = rs0 + g; if (e < re) cur = *reinterpret_cast<const ushort4*>(&h2ps[(ll)csr[e] * 64 + 4 * q]); }
        for (int c = rs0; c < re; c += 4) {
            ushort4 nxt = make_ushort4(0, 0, 0, 0);
            { int en = c + 4 + g; if (en < re) nxt = *reinterpret_cast<const ushort4*>(&h2ps[(ll)csr[en] * 64 + 4 * q]); }
            a0 += b2f(cur.x); a1 += b2f(cur.y); a2 += b2f(cur.z); a3 += b2f(cur.w);
            cur = nxt;
        }
        a0 += __shfl_xor(a0, 16); a1 += __shfl_xor(a1, 16);
        a2 += __shfl_xor(a2, 16); a3 += __shfl_xor(a3, 16);
        a0 += __shfl_xor(a0, 32); a1 += __shfl_xor(a1, 32);
        a2 += __shfl_xor(a2, 32); a3 += __shfl_xor(a3, 32);
        float degf = (float)(re - rs0) + 1.0f;
        float sc = rsqrtf(degf);
        const ushort4 sv = *reinterpret_cast<const ushort4*>(&h2ps[(ll)node * 64 + 4 * q]);
        float v0 = sc * (a0 + b2f(sv.x)) + b2v.x;
        float v1 = sc * (a1 + b2f(sv.y)) + b2v.y;
        float v2 = sc * (a2 + b2f(sv.z)) + b2v.z;
        float v3 = sc * (a3 + b2f(sv.w)) + b2v.w;
        if (g == 0) {
            st4(&out2[(ll)node * 64 + 4 * q], v0, v1, v2, v3);
            s0 += v0; s1 += v1; s2 += v2; s3 += v3;
            q0 += v0 * v0; q1 += v1 * v1; q2 += v2 * v2; q3 += v3 * v3;
        }
    }
    if (g == 0) {
        redS[wid][4 * q] = s0; redS[wid][4 * q + 1] = s1; redS[wid][4 * q + 2] = s2; redS[wid][4 * q + 3] = s3;
        redQ[wid][4 * q] = q0; redQ[wid][4 * q + 1] = q1; redQ[wid][4 * q + 2] = q2; redQ[wid][4 * q + 3] = q3;
    }
    __syncthreads();
    int t = threadIdx.x;
    if (t < 64) {
        atomicAdd(&gsum[t], redS[0][t] + redS[1][t] + redS[2][t] + redS[3][t]);
        atomicAdd(&gsq[t],  redQ[0][t] + redQ[1][t] + redQ[2][t] + redQ[3][t]);
    }
}

// ------- fused norm2+relu+prediction dot -------
template <typename TO>
__global__ void k_final(const int* __restrict__ pos2, const TO* __restrict__ out2,
                        const float* __restrict__ A, const float* __restrict__ B,
                        const float* __restrict__ pW, const float* __restrict__ pb,
                        float* __restrict__ out, int P) {
    int wid = threadIdx.x >> 6, lane = threadIdx.x & 63;
    int p = blockIdx.x * 4 + wid;
    if (p >= P) return;
    int i = pos2[p];
    float v = ldf(&out2[(ll)i * 64 + lane]);
    v = fmaxf(A[lane] * v + B[lane], 0.f) * pW[lane];
    for (int off = 32; off; off >>= 1) v += __shfl_xor(v, off);
    if (lane == 0) out[p] = v + pb[0];
}

// smallest shift so that (M-1)>>shift < nbk
static inline int bucket_shift(int M, int nbk) {
    int s = 0;
    while (((M - 1) >> s) >= nbk) ++s;
    return s;
}

// ---------------- templated pipeline ----------------
template <typename TO>
static void run_pipeline(const int* x, const int* edge1, const int* edge2,
                         const int* pos1, const int* pos2,
                         const float* emb, const float* n0a, const float* n0g, const float* n0b,
                         const float* W1, const float* b1,
                         const float* n1a, const float* n1g, const float* n1b,
                         const float* W2, const float* b2,
                         const float* n2a, const float* n2g, const float* n2b,
                         const float* pW, const float* pb,
                         int N, int E1, int E2, int L, int P, int V,
                         int* cnt, float* stats, float* H1pre, int* bsum,
                         int* pk, int* deg, int* A, int* csr,
                         void* region1, void* region2,
                         float* d_out, hipStream_t stream) {
    TO* out1 = (TO*)region1;
    unsigned short* h2ps = (unsigned short*)region1;   // aliases out1 (out1 dead by then)
    float* RS = (float*)region2;
    TO* out2  = (TO*)region2;                          // aliases RS (RS dead by then)

    float* sum1 = stats + 128; float* sq1 = stats + 192;
    float* A1   = stats + 256; float* B1  = stats + 320;
    float* sum2 = stats + 384; float* sq2 = stats + 448;
    float* A2   = stats + 512; float* B2  = stats + 576;

    hipMemsetAsync(cnt,   0, (size_t)V * 4, stream);
    hipMemsetAsync(stats, 0, 640 * 4, stream);
    hipMemsetAsync(deg,   0, (size_t)N * 4, stream);

    // ---- fused: x-histogram | deg1 (ILP4) ----
    k_hist_deg<<<256 + 1024, 256, 0, stream>>>(x, N, cnt, V, edge1 + E1, E1, deg, 256);
    k_table<<<1, 256, 0, stream>>>(cnt, emb, n0a, n0g, n0b, W1, H1pre, N, V);
    k_pack<<<cdiv(N, 256), 256, 0, stream>>>(x, deg, N, pk);

    int nb1 = cdiv(N, 2048);
    k_scan1<<<nb1, 256, 0, stream>>>(deg, A, bsum, N);
    k_scan2<<<1, 256, 0, stream>>>(bsum, nb1);
    k_scan3<<<512, 256, 0, stream>>>(A, bsum, N);

    // deg1 fully consumed (pack + scan) -> reuse for deg2
    hipMemsetAsync(deg, 0, (size_t)L * 4, stream);

    // ---- fused: BUCKETED fillpk(E1) | deg2(E2, ILP4) ----
    int sh1 = bucket_shift(N, 16);
    int nbk1 = cdiv(N, 1 << sh1);
    k_fillpk_b_deg<<<2048, 256, 0, stream>>>(edge1, edge1 + E1, E1, pk, A, csr, sh1, nbk1,
                                             edge2 + E2, E2, deg, 1024);
    k_conv1<TO><<<2048, 256, 0, stream>>>(x, A, csr, H1pre, b1, out1, sum1, sq1, N, V);
    k_norm_final<<<1, 64, 0, stream>>>(sum1, sq1, n1a, n1g, n1b, A1, B1, N);

    int nb2 = cdiv(L, 2048);
    k_scan1<<<nb2, 256, 0, stream>>>(deg, A, bsum, L);
    k_scan2<<<1, 256, 0, stream>>>(bsum, nb2);
    k_scan3<<<512, 256, 0, stream>>>(A, bsum, L);

    k_RS<TO><<<1024, 256, 0, stream>>>(out1, A1, B1, W2, RS, N);
    int sh2 = bucket_shift(L, 16);
    int nbk2 = cdiv(L, 1 << sh2);
    k_fill_b<<<2048, 256, 0, stream>>>(edge2, edge2 + E2, E2, A, csr, sh2, nbk2);

    k_h2g<<<2048, 256, 0, stream>>>(pos1, RS, deg, h2ps, L);
    k_conv2<TO><<<2048, 256, 0, stream>>>(A, csr, h2ps, b2, out2, sum2, sq2, L);

    k_norm_final<<<1, 64, 0, stream>>>(sum2, sq2, n2a, n2g, n2b, A2, B2, L);
    k_final<TO><<<cdiv(P, 4), 256, 0, stream>>>(pos2, out2, A2, B2, pW, pb, d_out, P);
}

extern "C" void kernel_launch(void* const* d_in, const int* in_sizes, int n_in,
                              void* d_out, int out_size, void* d_ws, size_t ws_size,
                              hipStream_t stream) {
    const int*   x     = (const int*)d_in[0];
    const int*   edge1 = (const int*)d_in[1];
    const int*   edge2 = (const int*)d_in[2];
    const int*   pos1  = (const int*)d_in[3];
    const int*   pos2  = (const int*)d_in[4];
    const float* emb   = (const float*)d_in[5];
    const float* n0a   = (const float*)d_in[6];
    const float* n0g   = (const float*)d_in[7];
    const float* n0b   = (const float*)d_in[8];
    const float* W1    = (const float*)d_in[9];
    const float* b1    = (const float*)d_in[10];
    const float* n1a   = (const float*)d_in[11];
    const float* n1g   = (const float*)d_in[12];
    const float* n1b   = (const float*)d_in[13];
    const float* W2    = (const float*)d_in[14];
    const float* b2    = (const float*)d_in[15];
    const float* n2a   = (const float*)d_in[16];
    const float* n2g   = (const float*)d_in[17];
    const float* n2b   = (const float*)d_in[18];
    const float* pW    = (const float*)d_in[19];
    const float* pb    = (const float*)d_in[20];

    int N  = in_sizes[0];
    int E1 = in_sizes[1] / 2;
    int E2 = in_sizes[2] / 2;
    int L  = in_sizes[3] / 2;
    int P  = in_sizes[4];
    int V  = in_sizes[5] / 64;
    int Emax = (E1 > E2) ? E1 : E2;
    (void)n_in; (void)out_size;

    auto a256 = [](size_t s) { return (s + 255) & ~(size_t)255; };
    auto mx = [](size_t a, size_t b) { return a > b ? a : b; };

    size_t fixed = a256((size_t)V * 4) + a256(640 * 4) + a256((size_t)V * 64 * 4) +
                   a256(1024 * 4) + a256((size_t)N * 4) +
                   a256((size_t)(L + 1) * 4) + a256((size_t)(L + 1) * 4) +
                   a256((size_t)Emax * 4);
    size_t r1_pri = a256(mx((size_t)N * 64 * 4, (size_t)L * 64 * 2));
    size_t r2_pri = a256(mx((size_t)N * 128 * 4, (size_t)L * 64 * 4));
    size_t r1_fb  = a256(mx((size_t)N * 64 * 2, (size_t)L * 64 * 2));
    size_t r2_fb  = a256(mx((size_t)N * 128 * 4, (size_t)L * 64 * 2));
    size_t need_pri = fixed + r1_pri + r2_pri;
    bool primary = (ws_size >= need_pri);
    size_t r1 = primary ? r1_pri : r1_fb;
    size_t r2 = primary ? r2_pri : r2_fb;

    char* w = (char*)d_ws;
    size_t off = 0;
    auto alloc = [&](size_t bytes) { void* p = w + off; off += (bytes + 255) & ~(size_t)255; return p; };

    int*   cnt   = (int*)alloc((size_t)V * 4);
    float* stats = (float*)alloc(640 * 4);
    float* H1pre = (float*)alloc((size_t)V * 64 * 4);
    int*   bsum  = (int*)alloc(1024 * 4);
    int*   pk    = (int*)alloc((size_t)N * 4);
    int*   deg   = (int*)alloc((size_t)(L + 1) * 4);
    int*   A     = (int*)alloc((size_t)(L + 1) * 4);
    int*   csr   = (int*)alloc((size_t)Emax * 4);
    void*  region1 = alloc(r1);
    void*  region2 = alloc(r2);

    if (primary) {
        run_pipeline<float>(x, edge1, edge2, pos1, pos2, emb, n0a, n0g, n0b,
                            W1, b1, n1a, n1g, n1b, W2, b2, n2a, n2g, n2b, pW, pb,
                            N, E1, E2, L, P, V, cnt, stats, H1pre, bsum,
                            pk, deg, A, csr, region1, region2,
                            (float*)d_out, stream);
    } else {
        run_pipeline<__hip_bfloat16>(x, edge1, edge2, pos1, pos2, emb, n0a, n0g, n0b,
                            W1, b1, n1a, n1g, n1b, W2, b2, n2a, n2g, n2b, pW, pb,
                            N, E1, E2, L, P, V, cnt, stats, H1pre, bsum,
                            pk, deg, A, csr, region1, region2,
                            (float*)d_out, stream);
    }
}

// Round 11
// 1282.609 us; speedup vs baseline: 1.8656x; 1.0115x over previous
//
#include <hip/hip_runtime.h>
#include <hip/hip_bf16.h>

typedef long long ll;
static inline int cdiv(int a, int b) { return (a + b - 1) / b; }

__device__ __forceinline__ float ldf(const float* p) { return *p; }
__device__ __forceinline__ float ldf(const __hip_bfloat16* p) { return __bfloat162float(*p); }
__device__ __forceinline__ void stf(float* p, float v) { *p = v; }
__device__ __forceinline__ void stf(__hip_bfloat16* p, float v) { *p = __float2bfloat16(v); }

__device__ __forceinline__ float b2f(unsigned short u) {
    return __int_as_float(((unsigned int)u) << 16);
}
__device__ __forceinline__ unsigned short f2b(float f) {
    __hip_bfloat16 h = __float2bfloat16(f);
    return *reinterpret_cast<unsigned short*>(&h);
}

__device__ __forceinline__ void st4(float* p, float v0, float v1, float v2, float v3) {
    float4 v = make_float4(v0, v1, v2, v3);
    *reinterpret_cast<float4*>(p) = v;
}
__device__ __forceinline__ void st4(__hip_bfloat16* p, float v0, float v1, float v2, float v3) {
    ushort4 v;
    v.x = f2b(v0); v.y = f2b(v1); v.z = f2b(v2); v.w = f2b(v3);
    *reinterpret_cast<ushort4*>(p) = v;
}

__device__ __forceinline__ float bcastf(float v, int j) {
    return __int_as_float(__builtin_amdgcn_readlane(__float_as_int(v), j));
}

// ------- fused: histogram of x (blocks [0,HB)) | deg1 over dst1 ILP4 (blocks [HB,..)) -------
__global__ void k_hist_deg(const int* __restrict__ x, int N, int* __restrict__ cnt, int V,
                           const int* __restrict__ dst1, int E1, int* __restrict__ deg, int HB) {
    __shared__ int lc[128];
    if ((int)blockIdx.x < HB) {
        for (int i = threadIdx.x; i < V; i += blockDim.x) lc[i] = 0;
        __syncthreads();
        int stride = HB * blockDim.x;
        for (int i = blockIdx.x * blockDim.x + threadIdx.x; i < N; i += stride)
            atomicAdd(&lc[x[i]], 1);
        __syncthreads();
        for (int i = threadIdx.x; i < V; i += blockDim.x) atomicAdd(&cnt[i], lc[i]);
    } else {
        int rb = blockIdx.x - HB;
        int T = (gridDim.x - HB) * blockDim.x;
        int e = rb * blockDim.x + threadIdx.x;
        for (; e + 3 * T < E1; e += 4 * T) {
            int d0 = dst1[e], d1 = dst1[e + T], d2 = dst1[e + 2 * T], d3 = dst1[e + 3 * T];
            atomicAdd(&deg[d0], 1); atomicAdd(&deg[d1], 1);
            atomicAdd(&deg[d2], 1); atomicAdd(&deg[d3], 1);
        }
        for (; e < E1; e += T) atomicAdd(&deg[dst1[e]], 1);
    }
}

// ------- exact GraphNorm0 from histogram + fold into W1: H1pre = T0 @ W1 -------
__global__ void k_table(const int* __restrict__ cnt, const float* __restrict__ emb,
                        const float* __restrict__ n0a, const float* __restrict__ n0g,
                        const float* __restrict__ n0b, const float* __restrict__ W1,
                        float* __restrict__ H1pre, int N, int V) {
    __shared__ float T0[101 * 64];
    __shared__ float W1l[64 * 64];
    __shared__ float A0[64], B0[64];
    __shared__ float rs[256], rq[256];
    __shared__ float cf[128];
    int t = threadIdx.x;
    for (int i = t; i < V; i += 256) cf[i] = (float)cnt[i];
    __syncthreads();
    int d = t & 63, g = t >> 6;
    float s = 0.f, q = 0.f;
    for (int v = g; v < V; v += 4) {
        float c = cf[v]; float e = emb[v * 64 + d];
        s += c * e; q += c * e * e;
    }
    rs[t] = s; rq[t] = q;
    __syncthreads();
    if (t < 64) {
        float sum = rs[t] + rs[t + 64] + rs[t + 128] + rs[t + 192];
        float sq  = rq[t] + rq[t + 64] + rq[t + 128] + rq[t + 192];
        float invN = 1.0f / (float)N;
        float m = sum * invN;
        float a = n0a[t];
        float var = sq * invN - (2.0f * a - a * a) * m * m;
        float A = n0g[t] * rsqrtf(var + 1e-5f);
        A0[t] = A; B0[t] = n0b[t] - A * a * m;
    }
    __syncthreads();
    for (int i = t; i < V * 64; i += 256) {
        int dd = i & 63;
        T0[i] = A0[dd] * emb[i] + B0[dd];
    }
    for (int i = t; i < 64 * 64; i += 256) W1l[i] = W1[i];
    __syncthreads();
    for (int o = t; o < V * 64; o += 256) {
        int v = o >> 6, dd = o & 63;
        float acc = 0.f;
#pragma unroll 8
        for (int k = 0; k < 64; ++k) acc += T0[v * 64 + k] * W1l[k * 64 + dd];
        H1pre[o] = acc;
    }
}

// ---------------- pack (deg<<7)|x per node ----------------
__global__ void k_pack(const int* __restrict__ x, const int* __restrict__ deg,
                       int N, int* __restrict__ pk) {
    int i = blockIdx.x * blockDim.x + threadIdx.x;
    if (i < N) pk[i] = (deg[i] << 7) | x[i];
}

// ---------------- scan: per-block exclusive (2048 elems/block) ----------------
__global__ void k_scan1(const int* __restrict__ in, int* __restrict__ out,
                        int* __restrict__ bsum, int M) {
    __shared__ int ts[256];
    int t = threadIdx.x;
    int base = blockIdx.x * 2048 + t * 8;
    int v[8]; int s = 0;
#pragma unroll
    for (int j = 0; j < 8; ++j) { int idx = base + j; int val = (idx < M) ? in[idx] : 0; v[j] = val; s += val; }
    ts[t] = s; __syncthreads();
    for (int off = 1; off < 256; off <<= 1) {
        int xv = 0;
        if (t >= off) xv = ts[t - off];
        __syncthreads();
        ts[t] += xv;
        __syncthreads();
    }
    int incl = ts[t];
    int excl = incl - s;
    if (t == 255) bsum[blockIdx.x] = incl;
    int run = excl;
#pragma unroll
    for (int j = 0; j < 8; ++j) { int idx = base + j; if (idx < M) out[idx] = run; run += v[j]; }
}

// parallel exclusive scan of block sums (nb <= 256)
__global__ void k_scan2(int* __restrict__ bsum, int nb) {
    __shared__ int ts[256];
    int t = threadIdx.x;
    int v = (t < nb) ? bsum[t] : 0;
    ts[t] = v; __syncthreads();
    for (int off = 1; off < 256; off <<= 1) {
        int xv = 0;
        if (t >= off) xv = ts[t - off];
        __syncthreads();
        ts[t] += xv;
        __syncthreads();
    }
    if (t < nb) bsum[t] = ts[t] - v;
}

__global__ void k_scan3(int* __restrict__ A, const int* __restrict__ bsum, int M) {
    int stride = gridDim.x * blockDim.x;
    for (int i = blockIdx.x * blockDim.x + threadIdx.x; i < M; i += stride)
        A[i] += bsum[i >> 11];
}

// ------- fused: XCD-partitioned single-pass fillpk(E1) (blocks [0,FB)) | deg2 ILP4 -------
// Bucket k of dst-space is processed ONLY by blocks with (blockIdx&7)==(k&7); with the
// round-robin blockIdx->XCD mapping each csr line is written by one XCD's L2 only ->
// no cross-XCD partial-line writebacks. Buckets-per-group ~1 -> single scan of edges.
__global__ void k_fillpk_b_deg(const int* __restrict__ src1, const int* __restrict__ dst1, int E1,
                               const int* __restrict__ pk, int* __restrict__ A, int* __restrict__ csr,
                               int shift, int nbk,
                               const int* __restrict__ dst2, int E2, int* __restrict__ deg2, int FB) {
    if ((int)blockIdx.x < FB) {
        int grp = blockIdx.x & 7;
        int sub = blockIdx.x >> 3;
        int T = (FB >> 3) * blockDim.x;
        int tid = sub * blockDim.x + threadIdx.x;
        int G4 = E1 >> 2;
        for (int k = grp; k < nbk; k += 8) {
            for (int g = tid; g < G4; g += T) {
                const int4 d4 = *reinterpret_cast<const int4*>(&dst1[g * 4]);
                bool m0 = (d4.x >> shift) == k, m1 = (d4.y >> shift) == k;
                bool m2 = (d4.z >> shift) == k, m3 = (d4.w >> shift) == k;
                if (m0 | m1 | m2 | m3) {
                    const int4 s4 = *reinterpret_cast<const int4*>(&src1[g * 4]);
                    if (m0) { int p = atomicAdd(&A[d4.x], 1); csr[p] = pk[s4.x]; }
                    if (m1) { int p = atomicAdd(&A[d4.y], 1); csr[p] = pk[s4.y]; }
                    if (m2) { int p = atomicAdd(&A[d4.z], 1); csr[p] = pk[s4.z]; }
                    if (m3) { int p = atomicAdd(&A[d4.w], 1); csr[p] = pk[s4.w]; }
                }
            }
        }
        if (blockIdx.x == 0 && threadIdx.x == 0) {
            for (int e = G4 * 4; e < E1; ++e) {
                int d = dst1[e];
                int p = atomicAdd(&A[d], 1);
                csr[p] = pk[src1[e]];
            }
        }
    } else {
        int rb = blockIdx.x - FB;
        int T = (gridDim.x - FB) * blockDim.x;
        int e = rb * blockDim.x + threadIdx.x;
        for (; e + 3 * T < E2; e += 4 * T) {
            int d0 = dst2[e], d1 = dst2[e + T], d2 = dst2[e + 2 * T], d3 = dst2[e + 3 * T];
            atomicAdd(&deg2[d0], 1); atomicAdd(&deg2[d1], 1);
            atomicAdd(&deg2[d2], 1); atomicAdd(&deg2[d3], 1);
        }
        for (; e < E2; e += T) atomicAdd(&deg2[dst2[e]], 1);
    }
}

// ---------------- XCD-partitioned single-pass CSR fill (src index) ----------------
__global__ void k_fill_b(const int* __restrict__ src, const int* __restrict__ dst, int E,
                         int* __restrict__ A, int* __restrict__ csr, int shift, int nbk) {
    int grp = blockIdx.x & 7;
    int sub = blockIdx.x >> 3;
    int T = ((int)gridDim.x >> 3) * blockDim.x;
    int tid = sub * blockDim.x + threadIdx.x;
    int G4 = E >> 2;
    for (int k = grp; k < nbk; k += 8) {
        for (int g = tid; g < G4; g += T) {
            const int4 d4 = *reinterpret_cast<const int4*>(&dst[g * 4]);
            bool m0 = (d4.x >> shift) == k, m1 = (d4.y >> shift) == k;
            bool m2 = (d4.z >> shift) == k, m3 = (d4.w >> shift) == k;
            if (m0 | m1 | m2 | m3) {
                const int4 s4 = *reinterpret_cast<const int4*>(&src[g * 4]);
                if (m0) { int p = atomicAdd(&A[d4.x], 1); csr[p] = s4.x; }
                if (m1) { int p = atomicAdd(&A[d4.y], 1); csr[p] = s4.y; }
                if (m2) { int p = atomicAdd(&A[d4.z], 1); csr[p] = s4.z; }
                if (m3) { int p = atomicAdd(&A[d4.w], 1); csr[p] = s4.w; }
            }
        }
    }
    if (blockIdx.x == 0 && threadIdx.x == 0) {
        for (int e = G4 * 4; e < E; ++e) {
            int d = dst[e];
            int p = atomicAdd(&A[d], 1);
            csr[p] = src[e];
        }
    }
}

// ------- conv1: wave/node, 4 edges/iter (16-lane groups), LDS table stride 68 -------
template <typename TO>
__global__ __launch_bounds__(256) void k_conv1(
        const int* __restrict__ x, const int* __restrict__ A, const int* __restrict__ csrpk,
        const float* __restrict__ H1pre, const float* __restrict__ b1,
        TO* __restrict__ out1, float* __restrict__ gsum, float* __restrict__ gsq,
        int N, int V) {
    __shared__ float Hl[101 * 68];
    __shared__ float redS[4][64], redQ[4][64];
    for (int i = threadIdx.x; i < V * 64; i += 256) {
        int row = i >> 6, col = i & 63;
        Hl[row * 68 + col] = H1pre[i];
    }
    __syncthreads();
    int wid = threadIdx.x >> 6, lane = threadIdx.x & 63;
    int g = lane >> 4, q = lane & 15;
    float4 b1v = *reinterpret_cast<const float4*>(&b1[4 * q]);
    float s0 = 0.f, s1 = 0.f, s2 = 0.f, s3 = 0.f;
    float q0 = 0.f, q1 = 0.f, q2 = 0.f, q3 = 0.f;
    for (int node = blockIdx.x * 4 + wid; node < N; node += gridDim.x * 4) {
        int re = A[node], rs0 = node ? A[node - 1] : 0;
        float a0 = 0.f, a1 = 0.f, a2 = 0.f, a3 = 0.f;
        int pkcur = -1;
        { int e = rs0 + g; if (e < re) pkcur = csrpk[e]; }
        for (int c = rs0; c < re; c += 4) {
            int pknxt = -1;
            { int en = c + 4 + g; if (en < re) pknxt = csrpk[en]; }
            if (pkcur >= 0) {
                float dv = rsqrtf((float)(pkcur >> 7) + 1.0f);
                const float4 hv = *reinterpret_cast<const float4*>(&Hl[(pkcur & 127) * 68 + 4 * q]);
                a0 += dv * hv.x; a1 += dv * hv.y; a2 += dv * hv.z; a3 += dv * hv.w;
            }
            pkcur = pknxt;
        }
        a0 += __shfl_xor(a0, 16); a1 += __shfl_xor(a1, 16);
        a2 += __shfl_xor(a2, 16); a3 += __shfl_xor(a3, 16);
        a0 += __shfl_xor(a0, 32); a1 += __shfl_xor(a1, 32);
        a2 += __shfl_xor(a2, 32); a3 += __shfl_xor(a3, 32);
        float degf = (float)(re - rs0) + 1.0f;
        float sc = rsqrtf(degf), si = 1.0f / degf;
        const float4 sv = *reinterpret_cast<const float4*>(&Hl[x[node] * 68 + 4 * q]);
        float v0 = sc * a0 + sv.x * si + b1v.x;
        float v1 = sc * a1 + sv.y * si + b1v.y;
        float v2 = sc * a2 + sv.z * si + b1v.z;
        float v3 = sc * a3 + sv.w * si + b1v.w;
        if (g == 0) {
            st4(&out1[(ll)node * 64 + 4 * q], v0, v1, v2, v3);
            s0 += v0; s1 += v1; s2 += v2; s3 += v3;
            q0 += v0 * v0; q1 += v1 * v1; q2 += v2 * v2; q3 += v3 * v3;
        }
    }
    if (g == 0) {
        redS[wid][4 * q] = s0; redS[wid][4 * q + 1] = s1; redS[wid][4 * q + 2] = s2; redS[wid][4 * q + 3] = s3;
        redQ[wid][4 * q] = q0; redQ[wid][4 * q + 1] = q1; redQ[wid][4 * q + 2] = q2; redQ[wid][4 * q + 3] = q3;
    }
    __syncthreads();
    int t = threadIdx.x;
    if (t < 64) {
        atomicAdd(&gsum[t], redS[0][t] + redS[1][t] + redS[2][t] + redS[3][t]);
        atomicAdd(&gsq[t],  redQ[0][t] + redQ[1][t] + redQ[2][t] + redQ[3][t]);
    }
}

__global__ void k_norm_final(const float* __restrict__ gsum, const float* __restrict__ gsq,
                             const float* __restrict__ na, const float* __restrict__ ng,
                             const float* __restrict__ nbb,
                             float* __restrict__ A, float* __restrict__ B, int M) {
    int t = threadIdx.x;
    if (t < 64) {
        float invM = 1.0f / (float)M;
        float m = gsum[t] * invM;
        float a = na[t];
        float var = gsq[t] * invM - (2.0f * a - a * a) * m * m;
        float Av = ng[t] * rsqrtf(var + 1e-5f);
        A[t] = Av; B[t] = nbb[t] - Av * a * m;
    }
}

// ------- RS GEMM: W2 (64x128) held in VGPRs, readlane broadcast -------
template <typename TO>
__global__ __launch_bounds__(256, 2) void k_RS(
        const TO* __restrict__ out1, const float* __restrict__ A1, const float* __restrict__ B1,
        const float* __restrict__ W2, float* __restrict__ RS, int N) {
    int wid = threadIdx.x >> 6, lane = threadIdx.x & 63;
    float Al = A1[lane], Bl = B1[lane];
    float wx[64], wy[64];
#pragma unroll
    for (int k = 0; k < 64; ++k) {
        wx[k] = W2[k * 64 + lane];
        wy[k] = W2[(64 + k) * 64 + lane];
    }
    for (int node = blockIdx.x * 4 + wid; node < N; node += gridDim.x * 4) {
        float v = fmaxf(Al * ldf(&out1[(ll)node * 64 + lane]) + Bl, 0.f);
        float ar = 0.f, asv = 0.f;
#pragma unroll
        for (int k = 0; k < 64; ++k) {
            float hv = bcastf(v, k);
            ar  += hv * wx[k];
            asv += hv * wy[k];
        }
        RS[(ll)node * 128 + lane] = ar;
        RS[(ll)node * 128 + 64 + lane] = asv;
    }
}

// ------- gather: h2ps[l] = dinv2[l]*(R[p0]+S[p1]) bf16; 4 pairs per wave-iter -------
__global__ __launch_bounds__(256) void k_h2g(
        const int* __restrict__ pos1, const float* __restrict__ RS,
        const int* __restrict__ deg2, unsigned short* __restrict__ h2ps, int L) {
    int wv = (blockIdx.x * 4) + (threadIdx.x >> 6);
    int nw = gridDim.x * 4;
    int lane = threadIdx.x & 63;
    int g = lane >> 4, q = lane & 15;
    for (int base = wv * 4; base < L; base += nw * 4) {
        int l = base + g;
        if (l < L) {
            int p0 = pos1[2 * l], p1 = pos1[2 * l + 1];
            float dv = rsqrtf((float)deg2[l] + 1.0f);
            const float4 r = *reinterpret_cast<const float4*>(&RS[(ll)p0 * 128 + 4 * q]);
            const float4 s = *reinterpret_cast<const float4*>(&RS[(ll)p1 * 128 + 64 + 4 * q]);
            ushort4 o;
            o.x = f2b(dv * (r.x + s.x));
            o.y = f2b(dv * (r.y + s.y));
            o.z = f2b(dv * (r.z + s.z));
            o.w = f2b(dv * (r.w + s.w));
            *reinterpret_cast<ushort4*>(&h2ps[(ll)l * 64 + 4 * q]) = o;
        }
    }
}

// ------- conv2: 4 edges/iter, ushort4 row-gathers, rotate prefetch -------
template <typename TO>
__global__ __launch_bounds__(256) void k_conv2(
        const int* __restrict__ A, const int* __restrict__ csr,
        const unsigned short* __restrict__ h2ps, const float* __restrict__ b2,
        TO* __restrict__ out2, float* __restrict__ gsum, float* __restrict__ gsq, int L) {
    __shared__ float redS[4][64], redQ[4][64];
    int wid = threadIdx.x >> 6, lane = threadIdx.x & 63;
    int g = lane >> 4, q = lane & 15;
    float4 b2v = *reinterpret_cast<const float4*>(&b2[4 * q]);
    float s0 = 0.f, s1 = 0.f, s2 = 0.f, s3 = 0.f;
    float q0 = 0.f, q1 = 0.f, q2 = 0.f, q3 = 0.f;
    for (int node = blockIdx.x * 4 + wid; node < L; node += gridDim.x * 4) {
        int re = A[node], rs0 = node ? A[node - 1] : 0;
        float a0 = 0.f, a1 = 0.f, a2 = 0.f, a3 = 0.f;
        ushort4 cur = make_ushort4(0, 0, 0, 0);
        { int e = rs0 + g; if (e < re) cur = *reinterpret_cast<const ushort4*>(&h2ps[(ll)csr[e] * 64 + 4 * q]); }
        for (int c = rs0; c < re; c += 4) {
            ushort4 nxt = make_ushort4(0, 0, 0, 0);
            { int en = c + 4 + g; if (en < re) nxt = *reinterpret_cast<const ushort4*>(&h2ps[(ll)csr[en] * 64 + 4 * q]); }
            a0 += b2f(cur.x); a1 += b2f(cur.y); a2 += b2f(cur.z); a3 += b2f(cur.w);
            cur = nxt;
        }
        a0 += __shfl_xor(a0, 16); a1 += __shfl_xor(a1, 16);
        a2 += __shfl_xor(a2, 16); a3 += __shfl_xor(a3, 16);
        a0 += __shfl_xor(a0, 32); a1 += __shfl_xor(a1, 32);
        a2 += __shfl_xor(a2, 32); a3 += __shfl_xor(a3, 32);
        float degf = (float)(re - rs0) + 1.0f;
        float sc = rsqrtf(degf);
        const ushort4 sv = *reinterpret_cast<const ushort4*>(&h2ps[(ll)node * 64 + 4 * q]);
        float v0 = sc * (a0 + b2f(sv.x)) + b2v.x;
        float v1 = sc * (a1 + b2f(sv.y)) + b2v.y;
        float v2 = sc * (a2 + b2f(sv.z)) + b2v.z;
        float v3 = sc * (a3 + b2f(sv.w)) + b2v.w;
        if (g == 0) {
            st4(&out2[(ll)node * 64 + 4 * q], v0, v1, v2, v3);
            s0 += v0; s1 += v1; s2 += v2; s3 += v3;
            q0 += v0 * v0; q1 += v1 * v1; q2 += v2 * v2; q3 += v3 * v3;
        }
    }
    if (g == 0) {
        redS[wid][4 * q] = s0; redS[wid][4 * q + 1] = s1; redS[wid][4 * q + 2] = s2; redS[wid][4 * q + 3] = s3;
        redQ[wid][4 * q] = q0; redQ[wid][4 * q + 1] = q1; redQ[wid][4 * q + 2] = q2; redQ[wid][4 * q + 3] = q3;
    }
    __syncthreads();
    int t = threadIdx.x;
    if (t < 64) {
        atomicAdd(&gsum[t], redS[0][t] + redS[1][t] + redS[2][t] + redS[3][t]);
        atomicAdd(&gsq[t],  redQ[0][t] + redQ[1][t] + redQ[2][t] + redQ[3][t]);
    }
}

// ------- fused norm2+relu+prediction dot -------
template <typename TO>
__global__ void k_final(const int* __restrict__ pos2, const TO* __restrict__ out2,
                        const float* __restrict__ A, const float* __restrict__ B,
                        const float* __restrict__ pW, const float* __restrict__ pb,
                        float* __restrict__ out, int P) {
    int wid = threadIdx.x >> 6, lane = threadIdx.x & 63;
    int p = blockIdx.x * 4 + wid;
    if (p >= P) return;
    int i = pos2[p];
    float v = ldf(&out2[(ll)i * 64 + lane]);
    v = fmaxf(A[lane] * v + B[lane], 0.f) * pW[lane];
    for (int off = 32; off; off >>= 1) v += __shfl_xor(v, off);
    if (lane == 0) out[p] = v + pb[0];
}

// smallest shift so that (M-1)>>shift < nbk
static inline int bucket_shift(int M, int nbk) {
    int s = 0;
    while (((M - 1) >> s) >= nbk) ++s;
    return s;
}

// ---------------- templated pipeline ----------------
template <typename TO>
static void run_pipeline(const int* x, const int* edge1, const int* edge2,
                         const int* pos1, const int* pos2,
                         const float* emb, const float* n0a, const float* n0g, const float* n0b,
                         const float* W1, const float* b1,
                         const float* n1a, const float* n1g, const float* n1b,
                         const float* W2, const float* b2,
                         const float* n2a, const float* n2g, const float* n2b,
                         const float* pW, const float* pb,
                         int N, int E1, int E2, int L, int P, int V,
                         int* cnt, float* stats, float* H1pre, int* bsum,
                         int* pk, int* deg, int* A, int* csr,
                         void* region1, void* region2,
                         float* d_out, hipStream_t stream) {
    TO* out1 = (TO*)region1;
    unsigned short* h2ps = (unsigned short*)region1;   // aliases out1 (out1 dead by then)
    float* RS = (float*)region2;
    TO* out2  = (TO*)region2;                          // aliases RS (RS dead by then)

    float* sum1 = stats + 128; float* sq1 = stats + 192;
    float* A1   = stats + 256; float* B1  = stats + 320;
    float* sum2 = stats + 384; float* sq2 = stats + 448;
    float* A2   = stats + 512; float* B2  = stats + 576;

    hipMemsetAsync(cnt,   0, (size_t)V * 4, stream);
    hipMemsetAsync(stats, 0, 640 * 4, stream);
    hipMemsetAsync(deg,   0, (size_t)N * 4, stream);

    // ---- fused: x-histogram | deg1 (ILP4) ----
    k_hist_deg<<<256 + 1024, 256, 0, stream>>>(x, N, cnt, V, edge1 + E1, E1, deg, 256);
    k_table<<<1, 256, 0, stream>>>(cnt, emb, n0a, n0g, n0b, W1, H1pre, N, V);
    k_pack<<<cdiv(N, 256), 256, 0, stream>>>(x, deg, N, pk);

    int nb1 = cdiv(N, 2048);
    k_scan1<<<nb1, 256, 0, stream>>>(deg, A, bsum, N);
    k_scan2<<<1, 256, 0, stream>>>(bsum, nb1);
    k_scan3<<<512, 256, 0, stream>>>(A, bsum, N);

    // deg1 fully consumed (pack + scan) -> reuse for deg2
    hipMemsetAsync(deg, 0, (size_t)L * 4, stream);

    // ---- fused: XCD-partitioned fillpk(E1) | deg2(E2, ILP4) ----
    int sh1 = bucket_shift(N, 8);
    int nbk1 = cdiv(N, 1 << sh1);
    k_fillpk_b_deg<<<2048, 256, 0, stream>>>(edge1, edge1 + E1, E1, pk, A, csr, sh1, nbk1,
                                             edge2 + E2, E2, deg, 1024);
    k_conv1<TO><<<2048, 256, 0, stream>>>(x, A, csr, H1pre, b1, out1, sum1, sq1, N, V);
    k_norm_final<<<1, 64, 0, stream>>>(sum1, sq1, n1a, n1g, n1b, A1, B1, N);

    int nb2 = cdiv(L, 2048);
    k_scan1<<<nb2, 256, 0, stream>>>(deg, A, bsum, L);
    k_scan2<<<1, 256, 0, stream>>>(bsum, nb2);
    k_scan3<<<512, 256, 0, stream>>>(A, bsum, L);

    k_RS<TO><<<1024, 256, 0, stream>>>(out1, A1, B1, W2, RS, N);
    int sh2 = bucket_shift(L, 8);
    int nbk2 = cdiv(L, 1 << sh2);
    k_fill_b<<<2048, 256, 0, stream>>>(edge2, edge2 + E2, E2, A, csr, sh2, nbk2);

    k_h2g<<<2048, 256, 0, stream>>>(pos1, RS, deg, h2ps, L);
    k_conv2<TO><<<2048, 256, 0, stream>>>(A, csr, h2ps, b2, out2, sum2, sq2, L);

    k_norm_final<<<1, 64, 0, stream>>>(sum2, sq2, n2a, n2g, n2b, A2, B2, L);
    k_final<TO><<<cdiv(P, 4), 256, 0, stream>>>(pos2, out2, A2, B2, pW, pb, d_out, P);
}

extern "C" void kernel_launch(void* const* d_in, const int* in_sizes, int n_in,
                              void* d_out, int out_size, void* d_ws, size_t ws_size,
                              hipStream_t stream) {
    const int*   x     = (const int*)d_in[0];
    const int*   edge1 = (const int*)d_in[1];
    const int*   edge2 = (const int*)d_in[2];
    const int*   pos1  = (const int*)d_in[3];
    const int*   pos2  = (const int*)d_in[4];
    const float* emb   = (const float*)d_in[5];
    const float* n0a   = (const float*)d_in[6];
    const float* n0g   = (const float*)d_in[7];
    const float* n0b   = (const float*)d_in[8];
    const float* W1    = (const float*)d_in[9];
    const float* b1    = (const float*)d_in[10];
    const float* n1a   = (const float*)d_in[11];
    const float* n1g   = (const float*)d_in[12];
    const float* n1b   = (const float*)d_in[13];
    const float* W2    = (const float*)d_in[14];
    const float* b2    = (const float*)d_in[15];
    const float* n2a   = (const float*)d_in[16];
    const float* n2g   = (const float*)d_in[17];
    const float* n2b   = (const float*)d_in[18];
    const float* pW    = (const float*)d_in[19];
    const float* pb    = (const float*)d_in[20];

    int N  = in_sizes[0];
    int E1 = in_sizes[1] / 2;
    int E2 = in_sizes[2] / 2;
    int L  = in_sizes[3] / 2;
    int P  = in_sizes[4];
    int V  = in_sizes[5] / 64;
    int Emax = (E1 > E2) ? E1 : E2;
    (void)n_in; (void)out_size;

    auto a256 = [](size_t s) { return (s + 255) & ~(size_t)255; };
    auto mx = [](size_t a, size_t b) { return a > b ? a : b; };

    size_t fixed = a256((size_t)V * 4) + a256(640 * 4) + a256((size_t)V * 64 * 4) +
                   a256(1024 * 4) + a256((size_t)N * 4) +
                   a256((size_t)(L + 1) * 4) + a256((size_t)(L + 1) * 4) +
                   a256((size_t)Emax * 4);
    size_t r1_pri = a256(mx((size_t)N * 64 * 4, (size_t)L * 64 * 2));
    size_t r2_pri = a256(mx((size_t)N * 128 * 4, (size_t)L * 64 * 4));
    size_t r1_fb  = a256(mx((size_t)N * 64 * 2, (size_t)L * 64 * 2));
    size_t r2_fb  = a256(mx((size_t)N * 128 * 4, (size_t)L * 64 * 2));
    size_t need_pri = fixed + r1_pri + r2_pri;
    bool primary = (ws_size >= need_pri);
    size_t r1 = primary ? r1_pri : r1_fb;
    size_t r2 = primary ? r2_pri : r2_fb;

    char* w = (char*)d_ws;
    size_t off = 0;
    auto alloc = [&](size_t bytes) { void* p = w + off; off += (bytes + 255) & ~(size_t)255; return p; };

    int*   cnt   = (int*)alloc((size_t)V * 4);
    float* stats = (float*)alloc(640 * 4);
    float* H1pre = (float*)alloc((size_t)V * 64 * 4);
    int*   bsum  = (int*)alloc(1024 * 4);
    int*   pk    = (int*)alloc((size_t)N * 4);
    int*   deg   = (int*)alloc((size_t)(L + 1) * 4);
    int*   A     = (int*)alloc((size_t)(L + 1) * 4);
    int*   csr   = (int*)alloc((size_t)Emax * 4);
    void*  region1 = alloc(r1);
    void*  region2 = alloc(r2);

    if (primary) {
        run_pipeline<float>(x, edge1, edge2, pos1, pos2, emb, n0a, n0g, n0b,
                            W1, b1, n1a, n1g, n1b, W2, b2, n2a, n2g, n2b, pW, pb,
                            N, E1, E2, L, P, V, cnt, stats, H1pre, bsum,
                            pk, deg, A, csr, region1, region2,
                            (float*)d_out, stream);
    } else {
        run_pipeline<__hip_bfloat16>(x, edge1, edge2, pos1, pos2, emb, n0a, n0g, n0b,
                            W1, b1, n1a, n1g, n1b, W2, b2, n2a, n2g, n2b, pW, pb,
                            N, E1, E2, L, P, V, cnt, stats, H1pre, bsum,
                            pk, deg, A, csr, region1, region2,
                            (float*)d_out, stream);
    }
}

// Round 12
// 1065.270 us; speedup vs baseline: 2.2463x; 1.2040x over previous
//
#include <hip/hip_runtime.h>
#include <hip/hip_bf16.h>

typedef long long ll;
static inline int cdiv(int a, int b) { return (a + b - 1) / b; }

__device__ __forceinline__ float ldf(const float* p) { return *p; }
__device__ __forceinline__ float ldf(const __hip_bfloat16* p) { return __bfloat162float(*p); }
__device__ __forceinline__ void stf(float* p, float v) { *p = v; }
__device__ __forceinline__ void stf(__hip_bfloat16* p, float v) { *p = __float2bfloat16(v); }

__device__ __forceinline__ float b2f(unsigned short u) {
    return __int_as_float(((unsigned int)u) << 16);
}
__device__ __forceinline__ unsigned short f2b(float f) {
    __hip_bfloat16 h = __float2bfloat16(f);
    return *reinterpret_cast<unsigned short*>(&h);
}

__device__ __forceinline__ void st4(float* p, float v0, float v1, float v2, float v3) {
    float4 v = make_float4(v0, v1, v2, v3);
    *reinterpret_cast<float4*>(p) = v;
}
__device__ __forceinline__ void st4(__hip_bfloat16* p, float v0, float v1, float v2, float v3) {
    ushort4 v;
    v.x = f2b(v0); v.y = f2b(v1); v.z = f2b(v2); v.w = f2b(v3);
    *reinterpret_cast<ushort4*>(p) = v;
}

__device__ __forceinline__ float bcastf(float v, int j) {
    return __int_as_float(__builtin_amdgcn_readlane(__float_as_int(v), j));
}

// ------- fused: histogram of x (blocks [0,HB)) | deg1 over dst1 ILP4 (blocks [HB,..)) -------
__global__ void k_hist_deg(const int* __restrict__ x, int N, int* __restrict__ cnt, int V,
                           const int* __restrict__ dst1, int E1, int* __restrict__ deg, int HB) {
    __shared__ int lc[128];
    if ((int)blockIdx.x < HB) {
        for (int i = threadIdx.x; i < V; i += blockDim.x) lc[i] = 0;
        __syncthreads();
        int stride = HB * blockDim.x;
        for (int i = blockIdx.x * blockDim.x + threadIdx.x; i < N; i += stride)
            atomicAdd(&lc[x[i]], 1);
        __syncthreads();
        for (int i = threadIdx.x; i < V; i += blockDim.x) atomicAdd(&cnt[i], lc[i]);
    } else {
        int rb = blockIdx.x - HB;
        int T = (gridDim.x - HB) * blockDim.x;
        int e = rb * blockDim.x + threadIdx.x;
        for (; e + 3 * T < E1; e += 4 * T) {
            int d0 = dst1[e], d1 = dst1[e + T], d2 = dst1[e + 2 * T], d3 = dst1[e + 3 * T];
            atomicAdd(&deg[d0], 1); atomicAdd(&deg[d1], 1);
            atomicAdd(&deg[d2], 1); atomicAdd(&deg[d3], 1);
        }
        for (; e < E1; e += T) atomicAdd(&deg[dst1[e]], 1);
    }
}

// ------- exact GraphNorm0 from histogram + fold into W1: H1pre = T0 @ W1 -------
__global__ void k_table(const int* __restrict__ cnt, const float* __restrict__ emb,
                        const float* __restrict__ n0a, const float* __restrict__ n0g,
                        const float* __restrict__ n0b, const float* __restrict__ W1,
                        float* __restrict__ H1pre, int N, int V) {
    __shared__ float T0[101 * 64];
    __shared__ float W1l[64 * 64];
    __shared__ float A0[64], B0[64];
    __shared__ float rs[256], rq[256];
    __shared__ float cf[128];
    int t = threadIdx.x;
    for (int i = t; i < V; i += 256) cf[i] = (float)cnt[i];
    __syncthreads();
    int d = t & 63, g = t >> 6;
    float s = 0.f, q = 0.f;
    for (int v = g; v < V; v += 4) {
        float c = cf[v]; float e = emb[v * 64 + d];
        s += c * e; q += c * e * e;
    }
    rs[t] = s; rq[t] = q;
    __syncthreads();
    if (t < 64) {
        float sum = rs[t] + rs[t + 64] + rs[t + 128] + rs[t + 192];
        float sq  = rq[t] + rq[t + 64] + rq[t + 128] + rq[t + 192];
        float invN = 1.0f / (float)N;
        float m = sum * invN;
        float a = n0a[t];
        float var = sq * invN - (2.0f * a - a * a) * m * m;
        float A = n0g[t] * rsqrtf(var + 1e-5f);
        A0[t] = A; B0[t] = n0b[t] - A * a * m;
    }
    __syncthreads();
    for (int i = t; i < V * 64; i += 256) {
        int dd = i & 63;
        T0[i] = A0[dd] * emb[i] + B0[dd];
    }
    for (int i = t; i < 64 * 64; i += 256) W1l[i] = W1[i];
    __syncthreads();
    for (int o = t; o < V * 64; o += 256) {
        int v = o >> 6, dd = o & 63;
        float acc = 0.f;
#pragma unroll 8
        for (int k = 0; k < 64; ++k) acc += T0[v * 64 + k] * W1l[k * 64 + dd];
        H1pre[o] = acc;
    }
}

// ---------------- pack (deg<<7)|x per node ----------------
__global__ void k_pack(const int* __restrict__ x, const int* __restrict__ deg,
                       int N, int* __restrict__ pk) {
    int i = blockIdx.x * blockDim.x + threadIdx.x;
    if (i < N) pk[i] = (deg[i] << 7) | x[i];
}

// ---------------- scan: per-block exclusive (2048 elems/block) ----------------
__global__ void k_scan1(const int* __restrict__ in, int* __restrict__ out,
                        int* __restrict__ bsum, int M) {
    __shared__ int ts[256];
    int t = threadIdx.x;
    int base = blockIdx.x * 2048 + t * 8;
    int v[8]; int s = 0;
#pragma unroll
    for (int j = 0; j < 8; ++j) { int idx = base + j; int val = (idx < M) ? in[idx] : 0; v[j] = val; s += val; }
    ts[t] = s; __syncthreads();
    for (int off = 1; off < 256; off <<= 1) {
        int xv = 0;
        if (t >= off) xv = ts[t - off];
        __syncthreads();
        ts[t] += xv;
        __syncthreads();
    }
    int incl = ts[t];
    int excl = incl - s;
    if (t == 255) bsum[blockIdx.x] = incl;
    int run = excl;
#pragma unroll
    for (int j = 0; j < 8; ++j) { int idx = base + j; if (idx < M) out[idx] = run; run += v[j]; }
}

// parallel exclusive scan of block sums (nb <= 256); bsum[nb] = grand total
__global__ void k_scan2(int* __restrict__ bsum, int nb) {
    __shared__ int ts[256];
    int t = threadIdx.x;
    int v = (t < nb) ? bsum[t] : 0;
    ts[t] = v; __syncthreads();
    for (int off = 1; off < 256; off <<= 1) {
        int xv = 0;
        if (t >= off) xv = ts[t - off];
        __syncthreads();
        ts[t] += xv;
        __syncthreads();
    }
    if (t < nb) bsum[t] = ts[t] - v;
    if (t == nb - 1) bsum[nb] = ts[t];
}

__global__ void k_scan3(int* __restrict__ A, const int* __restrict__ bsum, int M, int nb) {
    int stride = gridDim.x * blockDim.x;
    for (int i = blockIdx.x * blockDim.x + threadIdx.x; i < M; i += stride)
        A[i] += bsum[i >> 11];
    if (blockIdx.x == 0 && threadIdx.x == 0) A[M] = bsum[nb];
}

// ---------------- init per-bucket global cursors from node scan ----------------
__global__ void k_gcur(const int* __restrict__ A, int M, int shift, int nbk,
                       int* __restrict__ gcur) {
    int b = threadIdx.x;
    if (b < nbk) {
        int nd = b << shift;
        gcur[b] = A[nd < M ? nd : M];
    } else if (b < 256) gcur[b] = 0;
}

// ------- phase 1: bucket edges by dst>>shift into pairs (dst,payload), coalesced -------
// blocks [0,FB): bucketing; blocks [FB,..): deg2 ILP4 (pass E2d=0 to disable)
#define BK_CHUNK 4096
__global__ __launch_bounds__(256) void k_bucket_deg(
        const int* __restrict__ src, const int* __restrict__ dst, int E,
        const int* __restrict__ pk, int* __restrict__ gcur, uint2* __restrict__ pairs,
        int shift,
        const int* __restrict__ dst2, int E2d, int* __restrict__ deg2, int FB) {
    __shared__ uint2 stage[BK_CHUNK];
    __shared__ unsigned short binOf[BK_CHUNK];
    __shared__ int hist[256], scanex[256], curb[256], baseb[256], sbuf[256];
    if ((int)blockIdx.x < FB) {
        int tid = threadIdx.x;
        int nchunk = (E + BK_CHUNK - 1) / BK_CHUNK;
        for (int c = blockIdx.x; c < nchunk; c += FB) {
            int base = c * BK_CHUNK;
            int cnt = min(BK_CHUNK, E - base);
            hist[tid] = 0;
            __syncthreads();
            int d[16], pl[16];
#pragma unroll
            for (int j = 0; j < 16; ++j) {
                int lo = j * 256 + tid;
                if (lo < cnt) {
                    int idx = base + lo;
                    d[j] = dst[idx];
                    int s = src[idx];
                    pl[j] = pk ? pk[s] : s;
                    atomicAdd(&hist[d[j] >> shift], 1);
                } else d[j] = -1;
            }
            __syncthreads();
            int v = hist[tid];
            sbuf[tid] = v;
            __syncthreads();
            for (int off = 1; off < 256; off <<= 1) {
                int xv = (tid >= off) ? sbuf[tid - off] : 0;
                __syncthreads();
                sbuf[tid] += xv;
                __syncthreads();
            }
            int ex = sbuf[tid] - v;
            scanex[tid] = ex;
            curb[tid] = ex;
            baseb[tid] = (v > 0) ? atomicAdd(&gcur[tid], v) : 0;
            __syncthreads();
#pragma unroll
            for (int j = 0; j < 16; ++j) {
                if (d[j] >= 0) {
                    int b = d[j] >> shift;
                    int pos = atomicAdd(&curb[b], 1);
                    stage[pos] = make_uint2((unsigned)d[j], (unsigned)pl[j]);
                    binOf[pos] = (unsigned short)b;
                }
            }
            __syncthreads();
            for (int s = tid; s < cnt; s += 256) {
                int b = binOf[s];
                pairs[baseb[b] + (s - scanex[b])] = stage[s];
            }
            __syncthreads();
        }
    } else {
        int rb = blockIdx.x - FB;
        int T = (gridDim.x - FB) * blockDim.x;
        int e = rb * blockDim.x + threadIdx.x;
        for (; e + 3 * T < E2d; e += 4 * T) {
            int d0 = dst2[e], d1 = dst2[e + T], d2 = dst2[e + 2 * T], d3 = dst2[e + 3 * T];
            atomicAdd(&deg2[d0], 1); atomicAdd(&deg2[d1], 1);
            atomicAdd(&deg2[d2], 1); atomicAdd(&deg2[d3], 1);
        }
        for (; e < E2d; e += T) atomicAdd(&deg2[dst2[e]], 1);
    }
}

// ------- phase 2: per-bucket LDS scatter -> contiguous coalesced csr write -------
#define SC_CAP 28672
__global__ __launch_bounds__(256) void k_scatter(
        const uint2* __restrict__ pairs, const int* __restrict__ A,
        int* __restrict__ csr, int M, int shift, int nbk) {
    __shared__ int ldscsr[SC_CAP];
    __shared__ int lcur[2048];
    int tid = threadIdx.x;
    for (int b = blockIdx.x; b < nbk; b += gridDim.x) {
        int nodebase = b << shift;
        int nn = min(1 << shift, M - nodebase);
        int astart = A[nodebase];
        int aend = A[nodebase + nn];
        int cntE = aend - astart;
        for (int i = tid; i < nn; i += 256) lcur[i] = A[nodebase + i] - astart;
        __syncthreads();
        if (cntE <= SC_CAP) {
            for (int e = astart + tid; e < aend; e += 256) {
                uint2 p = pairs[e];
                int pos = atomicAdd(&lcur[(int)p.x - nodebase], 1);
                ldscsr[pos] = (int)p.y;
            }
            __syncthreads();
            for (int s = tid; s < cntE; s += 256) csr[astart + s] = ldscsr[s];
        } else {
            for (int e = astart + tid; e < aend; e += 256) {
                uint2 p = pairs[e];
                int pos = atomicAdd(&lcur[(int)p.x - nodebase], 1);
                csr[astart + pos] = (int)p.y;
            }
        }
        __syncthreads();
    }
}

// ------- conv1: wave/node, 4 edges/iter (16-lane groups), LDS table stride 68 -------
template <typename TO>
__global__ __launch_bounds__(256) void k_conv1(
        const int* __restrict__ x, const int* __restrict__ A, const int* __restrict__ csrpk,
        const float* __restrict__ H1pre, const float* __restrict__ b1,
        TO* __restrict__ out1, float* __restrict__ gsum, float* __restrict__ gsq,
        int N, int V) {
    __shared__ float Hl[101 * 68];
    __shared__ float redS[4][64], redQ[4][64];
    for (int i = threadIdx.x; i < V * 64; i += 256) {
        int row = i >> 6, col = i & 63;
        Hl[row * 68 + col] = H1pre[i];
    }
    __syncthreads();
    int wid = threadIdx.x >> 6, lane = threadIdx.x & 63;
    int g = lane >> 4, q = lane & 15;
    float4 b1v = *reinterpret_cast<const float4*>(&b1[4 * q]);
    float s0 = 0.f, s1 = 0.f, s2 = 0.f, s3 = 0.f;
    float q0 = 0.f, q1 = 0.f, q2 = 0.f, q3 = 0.f;
    for (int node = blockIdx.x * 4 + wid; node < N; node += gridDim.x * 4) {
        int rs0 = A[node], re = A[node + 1];
        float a0 = 0.f, a1 = 0.f, a2 = 0.f, a3 = 0.f;
        int pkcur = -1;
        { int e = rs0 + g; if (e < re) pkcur = csrpk[e]; }
        for (int c = rs0; c < re; c += 4) {
            int pknxt = -1;
            { int en = c + 4 + g; if (en < re) pknxt = csrpk[en]; }
            if (pkcur >= 0) {
                float dv = rsqrtf((float)(pkcur >> 7) + 1.0f);
                const float4 hv = *reinterpret_cast<const float4*>(&Hl[(pkcur & 127) * 68 + 4 * q]);
                a0 += dv * hv.x; a1 += dv * hv.y; a2 += dv * hv.z; a3 += dv * hv.w;
            }
            pkcur = pknxt;
        }
        a0 += __shfl_xor(a0, 16); a1 += __shfl_xor(a1, 16);
        a2 += __shfl_xor(a2, 16); a3 += __shfl_xor(a3, 16);
        a0 += __shfl_xor(a0, 32); a1 += __shfl_xor(a1, 32);
        a2 += __shfl_xor(a2, 32); a3 += __shfl_xor(a3, 32);
        float degf = (float)(re - rs0) + 1.0f;
        float sc = rsqrtf(degf), si = 1.0f / degf;
        const float4 sv = *reinterpret_cast<const float4*>(&Hl[x[node] * 68 + 4 * q]);
        float v0 = sc * a0 + sv.x * si + b1v.x;
        float v1 = sc * a1 + sv.y * si + b1v.y;
        float v2 = sc * a2 + sv.z * si + b1v.z;
        float v3 = sc * a3 + sv.w * si + b1v.w;
        if (g == 0) {
            st4(&out1[(ll)node * 64 + 4 * q], v0, v1, v2, v3);
            s0 += v0; s1 += v1; s2 += v2; s3 += v3;
            q0 += v0 * v0; q1 += v1 * v1; q2 += v2 * v2; q3 += v3 * v3;
        }
    }
    if (g == 0) {
        redS[wid][4 * q] = s0; redS[wid][4 * q + 1] = s1; redS[wid][4 * q + 2] = s2; redS[wid][4 * q + 3] = s3;
        redQ[wid][4 * q] = q0; redQ[wid][4 * q + 1] = q1; redQ[wid][4 * q + 2] = q2; redQ[wid][4 * q + 3] = q3;
    }
    __syncthreads();
    int t = threadIdx.x;
    if (t < 64) {
        atomicAdd(&gsum[t], redS[0][t] + redS[1][t] + redS[2][t] + redS[3][t]);
        atomicAdd(&gsq[t],  redQ[0][t] + redQ[1][t] + redQ[2][t] + redQ[3][t]);
    }
}

__global__ void k_norm_final(const float* __restrict__ gsum, const float* __restrict__ gsq,
                             const float* __restrict__ na, const float* __restrict__ ng,
                             const float* __restrict__ nbb,
                             float* __restrict__ A, float* __restrict__ B, int M) {
    int t = threadIdx.x;
    if (t < 64) {
        float invM = 1.0f / (float)M;
        float m = gsum[t] * invM;
        float a = na[t];
        float var = gsq[t] * invM - (2.0f * a - a * a) * m * m;
        float Av = ng[t] * rsqrtf(var + 1e-5f);
        A[t] = Av; B[t] = nbb[t] - Av * a * m;
    }
}

// ------- RS GEMM: W2 (64x128) held in VGPRs, readlane broadcast -------
template <typename TO>
__global__ __launch_bounds__(256, 2) void k_RS(
        const TO* __restrict__ out1, const float* __restrict__ A1, const float* __restrict__ B1,
        const float* __restrict__ W2, float* __restrict__ RS, int N) {
    int wid = threadIdx.x >> 6, lane = threadIdx.x & 63;
    float Al = A1[lane], Bl = B1[lane];
    float wx[64], wy[64];
#pragma unroll
    for (int k = 0; k < 64; ++k) {
        wx[k] = W2[k * 64 + lane];
        wy[k] = W2[(64 + k) * 64 + lane];
    }
    for (int node = blockIdx.x * 4 + wid; node < N; node += gridDim.x * 4) {
        float v = fmaxf(Al * ldf(&out1[(ll)node * 64 + lane]) + Bl, 0.f);
        float ar = 0.f, asv = 0.f;
#pragma unroll
        for (int k = 0; k < 64; ++k) {
            float hv = bcastf(v, k);
            ar  += hv * wx[k];
            asv += hv * wy[k];
        }
        RS[(ll)node * 128 + lane] = ar;
        RS[(ll)node * 128 + 64 + lane] = asv;
    }
}

// ------- gather: h2ps[l] = dinv2[l]*(R[p0]+S[p1]) bf16; 4 pairs per wave-iter -------
__global__ __launch_bounds__(256) void k_h2g(
        const int* __restrict__ pos1, const float* __restrict__ RS,
        const int* __restrict__ deg2, unsigned short* __restrict__ h2ps, int L) {
    int wv = (blockIdx.x * 4) + (threadIdx.x >> 6);
    int nw = gridDim.x * 4;
    int lane = threadIdx.x & 63;
    int g = lane >> 4, q = lane & 15;
    for (int base = wv * 4; base < L; base += nw * 4) {
        int l = base + g;
        if (l < L) {
            int p0 = pos1[2 * l], p1 = pos1[2 * l + 1];
            float dv = rsqrtf((float)deg2[l] + 1.0f);
            const float4 r = *reinterpret_cast<const float4*>(&RS[(ll)p0 * 128 + 4 * q]);
            const float4 s = *reinterpret_cast<const float4*>(&RS[(ll)p1 * 128 + 64 + 4 * q]);
            ushort4 o;
            o.x = f2b(dv * (r.x + s.x));
            o.y = f2b(dv * (r.y + s.y));
            o.z = f2b(dv * (r.z + s.z));
            o.w = f2b(dv * (r.w + s.w));
            *reinterpret_cast<ushort4*>(&h2ps[(ll)l * 64 + 4 * q]) = o;
        }
    }
}

// ------- conv2: 4 edges/iter, ushort4 row-gathers, rotate prefetch -------
template <typename TO>
__global__ __launch_bounds__(256) void k_conv2(
        const int* __restrict__ A, const int* __restrict__ csr,
        const unsigned short* __restrict__ h2ps, const float* __restrict__ b2,
        TO* __restrict__ out2, float* __restrict__ gsum, float* __restrict__ gsq, int L) {
    __shared__ float redS[4][64], redQ[4][64];
    int wid = threadIdx.x >> 6, lane = threadIdx.x & 63;
    int g = lane >> 4, q = lane & 15;
    float4 b2v = *reinterpret_cast<const float4*>(&b2[4 * q]);
    float s0 = 0.f, s1 = 0.f, s2 = 0.f, s3 = 0.f;
    float q0 = 0.f, q1 = 0.f, q2 = 0.f, q3 = 0.f;
    for (int node = blockIdx.x * 4 + wid; node < L; node += gridDim.x * 4) {
        int rs0 = A[node], re = A[node + 1];
        float a0 = 0.f, a1 = 0.f, a2 = 0.f, a3 = 0.f;
        ushort4 cur = make_ushort4(0, 0, 0, 0);
        { int e = rs0 + g; if (e < re) cur = *reinterpret_cast<const ushort4*>(&h2ps[(ll)csr[e] * 64 + 4 * q]); }
        for (int c = rs0; c < re; c += 4) {
            ushort4 nxt = make_ushort4(0, 0, 0, 0);
            { int en = c + 4 + g; if (en < re) nxt = *reinterpret_cast<const ushort4*>(&h2ps[(ll)csr[en] * 64 + 4 * q]); }
            a0 += b2f(cur.x); a1 += b2f(cur.y); a2 += b2f(cur.z); a3 += b2f(cur.w);
            cur = nxt;
        }
        a0 += __shfl_xor(a0, 16); a1 += __shfl_xor(a1, 16);
        a2 += __shfl_xor(a2, 16); a3 += __shfl_xor(a3, 16);
        a0 += __shfl_xor(a0, 32); a1 += __shfl_xor(a1, 32);
        a2 += __shfl_xor(a2, 32); a3 += __shfl_xor(a3, 32);
        float degf = (float)(re - rs0) + 1.0f;
        float sc = rsqrtf(degf);
        const ushort4 sv = *reinterpret_cast<const ushort4*>(&h2ps[(ll)node * 64 + 4 * q]);
        float v0 = sc * (a0 + b2f(sv.x)) + b2v.x;
        float v1 = sc * (a1 + b2f(sv.y)) + b2v.y;
        float v2 = sc * (a2 + b2f(sv.z)) + b2v.z;
        float v3 = sc * (a3 + b2f(sv.w)) + b2v.w;
        if (g == 0) {
            st4(&out2[(ll)node * 64 + 4 * q], v0, v1, v2, v3);
            s0 += v0; s1 += v1; s2 += v2; s3 += v3;
            q0 += v0 * v0; q1 += v1 * v1; q2 += v2 * v2; q3 += v3 * v3;
        }
    }
    if (g == 0) {
        redS[wid][4 * q] = s0; redS[wid][4 * q + 1] = s1; redS[wid][4 * q + 2] = s2; redS[wid][4 * q + 3] = s3;
        redQ[wid][4 * q] = q0; redQ[wid][4 * q + 1] = q1; redQ[wid][4 * q + 2] = q2; redQ[wid][4 * q + 3] = q3;
    }
    __syncthreads();
    int t = threadIdx.x;
    if (t < 64) {
        atomicAdd(&gsum[t], redS[0][t] + redS[1][t] + redS[2][t] + redS[3][t]);
        atomicAdd(&gsq[t],  redQ[0][t] + redQ[1][t] + redQ[2][t] + redQ[3][t]);
    }
}

// ------- fused norm2+relu+prediction dot -------
template <typename TO>
__global__ void k_final(const int* __restrict__ pos2, const TO* __restrict__ out2,
                        const float* __restrict__ A, const float* __restrict__ B,
                        const float* __restrict__ pW, const float* __restrict__ pb,
                        float* __restrict__ out, int P) {
    int wid = threadIdx.x >> 6, lane = threadIdx.x & 63;
    int p = blockIdx.x * 4 + wid;
    if (p >= P) return;
    int i = pos2[p];
    float v = ldf(&out2[(ll)i * 64 + lane]);
    v = fmaxf(A[lane] * v + B[lane], 0.f) * pW[lane];
    for (int off = 32; off; off >>= 1) v += __shfl_xor(v, off);
    if (lane == 0) out[p] = v + pb[0];
}

// smallest shift so that (M-1)>>shift < nbk
static inline int bucket_shift(int M, int nbk) {
    int s = 0;
    while (((M - 1) >> s) >= nbk) ++s;
    return s;
}

// ---------------- templated pipeline ----------------
template <typename TO>
static void run_pipeline(const int* x, const int* edge1, const int* edge2,
                         const int* pos1, const int* pos2,
                         const float* emb, const float* n0a, const float* n0g, const float* n0b,
                         const float* W1, const float* b1,
                         const float* n1a, const float* n1g, const float* n1b,
                         const float* W2, const float* b2,
                         const float* n2a, const float* n2g, const float* n2b,
                         const float* pW, const float* pb,
                         int N, int E1, int E2, int L, int P, int V,
                         int* cnt, float* stats, float* H1pre, int* bsum, int* gcur,
                         int* pk, int* deg, int* A, int* csr,
                         void* region1, void* region2,
                         float* d_out, hipStream_t stream) {
    TO* out1 = (TO*)region1;
    unsigned short* h2ps = (unsigned short*)region1;   // aliases out1 (out1 dead by then)
    float* RS = (float*)region2;
    TO* out2  = (TO*)region2;                          // aliases RS (RS dead by then)
    uint2* pairs = (uint2*)region2;                    // phase-1 buffer, dead before k_RS

    float* sum1 = stats + 128; float* sq1 = stats + 192;
    float* A1   = stats + 256; float* B1  = stats + 320;
    float* sum2 = stats + 384; float* sq2 = stats + 448;
    float* A2   = stats + 512; float* B2  = stats + 576;

    hipMemsetAsync(cnt,   0, (size_t)V * 4, stream);
    hipMemsetAsync(stats, 0, 640 * 4, stream);
    hipMemsetAsync(deg,   0, (size_t)N * 4, stream);

    // ---- fused: x-histogram | deg1 (ILP4) ----
    k_hist_deg<<<256 + 1024, 256, 0, stream>>>(x, N, cnt, V, edge1 + E1, E1, deg, 256);
    k_table<<<1, 256, 0, stream>>>(cnt, emb, n0a, n0g, n0b, W1, H1pre, N, V);
    k_pack<<<cdiv(N, 256), 256, 0, stream>>>(x, deg, N, pk);

    int nb1 = cdiv(N, 2048);
    k_scan1<<<nb1, 256, 0, stream>>>(deg, A, bsum, N);
    k_scan2<<<1, 256, 0, stream>>>(bsum, nb1);
    k_scan3<<<512, 256, 0, stream>>>(A, bsum, N, nb1);

    // deg1 consumed (pack + scan) -> reuse for deg2
    hipMemsetAsync(deg, 0, (size_t)L * 4, stream);

    // ---- graph1 fill: bucket (fused w/ deg2) + LDS scatter ----
    int sh1 = bucket_shift(N, 256);
    int nbk1 = cdiv(N, 1 << sh1);
    k_gcur<<<1, 256, 0, stream>>>(A, N, sh1, nbk1, gcur);
    k_bucket_deg<<<2048, 256, 0, stream>>>(edge1, edge1 + E1, E1, pk, gcur, pairs, sh1,
                                           edge2 + E2, E2, deg, 1024);
    k_scatter<<<nbk1, 256, 0, stream>>>(pairs, A, csr, N, sh1, nbk1);
    k_conv1<TO><<<2048, 256, 0, stream>>>(x, A, csr, H1pre, b1, out1, sum1, sq1, N, V);
    k_norm_final<<<1, 64, 0, stream>>>(sum1, sq1, n1a, n1g, n1b, A1, B1, N);

    int nb2 = cdiv(L, 2048);
    k_scan1<<<nb2, 256, 0, stream>>>(deg, A, bsum, L);
    k_scan2<<<1, 256, 0, stream>>>(bsum, nb2);
    k_scan3<<<512, 256, 0, stream>>>(A, bsum, L, nb2);

    // ---- graph2 fill: bucket + LDS scatter (pairs dead before k_RS) ----
    int sh2 = bucket_shift(L, 256);
    int nbk2 = cdiv(L, 1 << sh2);
    k_gcur<<<1, 256, 0, stream>>>(A, L, sh2, nbk2, gcur);
    k_bucket_deg<<<2048, 256, 0, stream>>>(edge2, edge2 + E2, E2, nullptr, gcur, pairs, sh2,
                                           nullptr, 0, nullptr, 2048);
    k_scatter<<<nbk2, 256, 0, stream>>>(pairs, A, csr, L, sh2, nbk2);

    k_RS<TO><<<1024, 256, 0, stream>>>(out1, A1, B1, W2, RS, N);
    k_h2g<<<2048, 256, 0, stream>>>(pos1, RS, deg, h2ps, L);
    k_conv2<TO><<<2048, 256, 0, stream>>>(A, csr, h2ps, b2, out2, sum2, sq2, L);

    k_norm_final<<<1, 64, 0, stream>>>(sum2, sq2, n2a, n2g, n2b, A2, B2, L);
    k_final<TO><<<cdiv(P, 4), 256, 0, stream>>>(pos2, out2, A2, B2, pW, pb, d_out, P);
}

extern "C" void kernel_launch(void* const* d_in, const int* in_sizes, int n_in,
                              void* d_out, int out_size, void* d_ws, size_t ws_size,
                              hipStream_t stream) {
    const int*   x     = (const int*)d_in[0];
    const int*   edge1 = (const int*)d_in[1];
    const int*   edge2 = (const int*)d_in[2];
    const int*   pos1  = (const int*)d_in[3];
    const int*   pos2  = (const int*)d_in[4];
    const float* emb   = (const float*)d_in[5];
    const float* n0a   = (const float*)d_in[6];
    const float* n0g   = (const float*)d_in[7];
    const float* n0b   = (const float*)d_in[8];
    const float* W1    = (const float*)d_in[9];
    const float* b1    = (const float*)d_in[10];
    const float* n1a   = (const float*)d_in[11];
    const float* n1g   = (const float*)d_in[12];
    const float* n1b   = (const float*)d_in[13];
    const float* W2    = (const float*)d_in[14];
    const float* b2    = (const float*)d_in[15];
    const float* n2a   = (const float*)d_in[16];
    const float* n2g   = (const float*)d_in[17];
    const float* n2b   = (const float*)d_in[18];
    const float* pW    = (const float*)d_in[19];
    const float* pb    = (const float*)d_in[20];

    int N  = in_sizes[0];
    int E1 = in_sizes[1] / 2;
    int E2 = in_sizes[2] / 2;
    int L  = in_sizes[3] / 2;
    int P  = in_sizes[4];
    int V  = in_sizes[5] / 64;
    int Emax = (E1 > E2) ? E1 : E2;
    (void)n_in; (void)out_size;

    auto a256 = [](size_t s) { return (s + 255) & ~(size_t)255; };
    auto mx = [](size_t a, size_t b) { return a > b ? a : b; };

    size_t fixed = a256((size_t)V * 4) + a256(640 * 4) + a256((size_t)V * 64 * 4) +
                   a256(1040 * 4) + a256(512 * 4) + a256((size_t)N * 4) +
                   a256((size_t)(L + 1) * 4) + a256((size_t)(L + 1) * 4) +
                   a256((size_t)Emax * 4);
    size_t r1_pri = a256(mx((size_t)N * 64 * 4, (size_t)L * 64 * 2));
    size_t r2_pri = a256(mx(mx((size_t)N * 128 * 4, (size_t)L * 64 * 4), (size_t)Emax * 8));
    size_t r1_fb  = a256(mx((size_t)N * 64 * 2, (size_t)L * 64 * 2));
    size_t r2_fb  = a256(mx((size_t)N * 128 * 4, (size_t)Emax * 8));
    size_t need_pri = fixed + r1_pri + r2_pri;
    bool primary = (ws_size >= need_pri);
    size_t r1 = primary ? r1_pri : r1_fb;
    size_t r2 = primary ? r2_pri : r2_fb;

    char* w = (char*)d_ws;
    size_t off = 0;
    auto alloc = [&](size_t bytes) { void* p = w + off; off += (bytes + 255) & ~(size_t)255; return p; };

    int*   cnt   = (int*)alloc((size_t)V * 4);
    float* stats = (float*)alloc(640 * 4);
    float* H1pre = (float*)alloc((size_t)V * 64 * 4);
    int*   bsum  = (int*)alloc(1040 * 4);
    int*   gcur  = (int*)alloc(512 * 4);
    int*   pk    = (int*)alloc((size_t)N * 4);
    int*   deg   = (int*)alloc((size_t)(L + 1) * 4);
    int*   A     = (int*)alloc((size_t)(L + 1) * 4);
    int*   csr   = (int*)alloc((size_t)Emax * 4);
    void*  region1 = alloc(r1);
    void*  region2 = alloc(r2);

    if (primary) {
        run_pipeline<float>(x, edge1, edge2, pos1, pos2, emb, n0a, n0g, n0b,
                            W1, b1, n1a, n1g, n1b, W2, b2, n2a, n2g, n2b, pW, pb,
                            N, E1, E2, L, P, V, cnt, stats, H1pre, bsum, gcur,
                            pk, deg, A, csr, region1, region2,
                            (float*)d_out, stream);
    } else {
        run_pipeline<__hip_bfloat16>(x, edge1, edge2, pos1, pos2, emb, n0a, n0g, n0b,
                            W1, b1, n1a, n1g, n1b, W2, b2, n2a, n2g, n2b, pW, pb,
                            N, E1, E2, L, P, V, cnt, stats, H1pre, bsum, gcur,
                            pk, deg, A, csr, region1, region2,
                            (float*)d_out, stream);
    }
}

// Round 15
// 950.597 us; speedup vs baseline: 2.5173x; 1.1206x over previous
//
#include <hip/hip_runtime.h>
#include <hip/hip_bf16.h>

typedef long long ll;
static inline int cdiv(int a, int b) { return (a + b - 1) / b; }

__device__ __forceinline__ float ldf(const float* p) { return *p; }
__device__ __forceinline__ float ldf(const __hip_bfloat16* p) { return __bfloat162float(*p); }
__device__ __forceinline__ void stf(float* p, float v) { *p = v; }
__device__ __forceinline__ void stf(__hip_bfloat16* p, float v) { *p = __float2bfloat16(v); }

__device__ __forceinline__ float b2f(unsigned short u) {
    return __int_as_float(((unsigned int)u) << 16);
}
__device__ __forceinline__ unsigned short f2b(float f) {
    __hip_bfloat16 h = __float2bfloat16(f);
    return *reinterpret_cast<unsigned short*>(&h);
}

__device__ __forceinline__ void st4(float* p, float v0, float v1, float v2, float v3) {
    float4 v = make_float4(v0, v1, v2, v3);
    *reinterpret_cast<float4*>(p) = v;
}
__device__ __forceinline__ void st4(__hip_bfloat16* p, float v0, float v1, float v2, float v3) {
    ushort4 v;
    v.x = f2b(v0); v.y = f2b(v1); v.z = f2b(v2); v.w = f2b(v3);
    *reinterpret_cast<ushort4*>(p) = v;
}

__device__ __forceinline__ float bcastf(float v, int j) {
    return __int_as_float(__builtin_amdgcn_readlane(__float_as_int(v), j));
}

// ------- fused: histogram of x (blocks [0,HB)) | deg1 over dst1 ILP4 (blocks [HB,..)) -------
__global__ void k_hist_deg(const int* __restrict__ x, int N, int* __restrict__ cnt, int V,
                           const int* __restrict__ dst1, int E1, int* __restrict__ deg, int HB) {
    __shared__ int lc[128];
    if ((int)blockIdx.x < HB) {
        for (int i = threadIdx.x; i < V; i += blockDim.x) lc[i] = 0;
        __syncthreads();
        int stride = HB * blockDim.x;
        for (int i = blockIdx.x * blockDim.x + threadIdx.x; i < N; i += stride)
            atomicAdd(&lc[x[i]], 1);
        __syncthreads();
        for (int i = threadIdx.x; i < V; i += blockDim.x) atomicAdd(&cnt[i], lc[i]);
    } else {
        int rb = blockIdx.x - HB;
        int T = (gridDim.x - HB) * blockDim.x;
        int e = rb * blockDim.x + threadIdx.x;
        for (; e + 3 * T < E1; e += 4 * T) {
            int d0 = dst1[e], d1 = dst1[e + T], d2 = dst1[e + 2 * T], d3 = dst1[e + 3 * T];
            atomicAdd(&deg[d0], 1); atomicAdd(&deg[d1], 1);
            atomicAdd(&deg[d2], 1); atomicAdd(&deg[d3], 1);
        }
        for (; e < E1; e += T) atomicAdd(&deg[dst1[e]], 1);
    }
}

// ------- exact GraphNorm0 from histogram + fold into W1: H1pre = T0 @ W1 -------
__global__ void k_table(const int* __restrict__ cnt, const float* __restrict__ emb,
                        const float* __restrict__ n0a, const float* __restrict__ n0g,
                        const float* __restrict__ n0b, const float* __restrict__ W1,
                        float* __restrict__ H1pre, int N, int V) {
    __shared__ float T0[101 * 64];
    __shared__ float W1l[64 * 64];
    __shared__ float A0[64], B0[64];
    __shared__ float rs[256], rq[256];
    __shared__ float cf[128];
    int t = threadIdx.x;
    for (int i = t; i < V; i += 256) cf[i] = (float)cnt[i];
    __syncthreads();
    int d = t & 63, g = t >> 6;
    float s = 0.f, q = 0.f;
    for (int v = g; v < V; v += 4) {
        float c = cf[v]; float e = emb[v * 64 + d];
        s += c * e; q += c * e * e;
    }
    rs[t] = s; rq[t] = q;
    __syncthreads();
    if (t < 64) {
        float sum = rs[t] + rs[t + 64] + rs[t + 128] + rs[t + 192];
        float sq  = rq[t] + rq[t + 64] + rq[t + 128] + rq[t + 192];
        float invN = 1.0f / (float)N;
        float m = sum * invN;
        float a = n0a[t];
        float var = sq * invN - (2.0f * a - a * a) * m * m;
        float A = n0g[t] * rsqrtf(var + 1e-5f);
        A0[t] = A; B0[t] = n0b[t] - A * a * m;
    }
    __syncthreads();
    for (int i = t; i < V * 64; i += 256) {
        int dd = i & 63;
        T0[i] = A0[dd] * emb[i] + B0[dd];
    }
    for (int i = t; i < 64 * 64; i += 256) W1l[i] = W1[i];
    __syncthreads();
    for (int o = t; o < V * 64; o += 256) {
        int v = o >> 6, dd = o & 63;
        float acc = 0.f;
#pragma unroll 8
        for (int k = 0; k < 64; ++k) acc += T0[v * 64 + k] * W1l[k * 64 + dd];
        H1pre[o] = acc;
    }
}

// ---------------- pack (deg<<7)|x per node ----------------
__global__ void k_pack(const int* __restrict__ x, const int* __restrict__ deg,
                       int N, int* __restrict__ pk) {
    int i = blockIdx.x * blockDim.x + threadIdx.x;
    if (i < N) pk[i] = (deg[i] << 7) | x[i];
}

// ---------------- scan: per-block exclusive (2048 elems/block) ----------------
__global__ void k_scan1(const int* __restrict__ in, int* __restrict__ out,
                        int* __restrict__ bsum, int M) {
    __shared__ int ts[256];
    int t = threadIdx.x;
    int base = blockIdx.x * 2048 + t * 8;
    int v[8]; int s = 0;
#pragma unroll
    for (int j = 0; j < 8; ++j) { int idx = base + j; int val = (idx < M) ? in[idx] : 0; v[j] = val; s += val; }
    ts[t] = s; __syncthreads();
    for (int off = 1; off < 256; off <<= 1) {
        int xv = 0;
        if (t >= off) xv = ts[t - off];
        __syncthreads();
        ts[t] += xv;
        __syncthreads();
    }
    int incl = ts[t];
    int excl = incl - s;
    if (t == 255) bsum[blockIdx.x] = incl;
    int run = excl;
#pragma unroll
    for (int j = 0; j < 8; ++j) { int idx = base + j; if (idx < M) out[idx] = run; run += v[j]; }
}

// parallel exclusive scan of block sums (nb <= 256); bsum[nb] = grand total
__global__ void k_scan2(int* __restrict__ bsum, int nb) {
    __shared__ int ts[256];
    int t = threadIdx.x;
    int v = (t < nb) ? bsum[t] : 0;
    ts[t] = v; __syncthreads();
    for (int off = 1; off < 256; off <<= 1) {
        int xv = 0;
        if (t >= off) xv = ts[t - off];
        __syncthreads();
        ts[t] += xv;
        __syncthreads();
    }
    if (t < nb) bsum[t] = ts[t] - v;
    if (t == nb - 1) bsum[nb] = ts[t];
}

__global__ void k_scan3(int* __restrict__ A, const int* __restrict__ bsum, int M, int nb) {
    int stride = gridDim.x * blockDim.x;
    for (int i = blockIdx.x * blockDim.x + threadIdx.x; i < M; i += stride)
        A[i] += bsum[i >> 11];
    if (blockIdx.x == 0 && threadIdx.x == 0) A[M] = bsum[nb];
}

// ---------------- init per-bucket global cursors from node scan (graph1) ----------------
__global__ void k_gcur(const int* __restrict__ A, int M, int shift, int nbk,
                       int* __restrict__ gcur) {
    int b = threadIdx.x;
    if (b < nbk) {
        int nd = b << shift;
        gcur[b] = A[nd < M ? nd : M];
    } else if (b < 256) gcur[b] = 0;
}

// ---------------- exclusive scan of 256 bucket counts -> gcur (cursor) + bbase ----------------
__global__ void k_scan_b(const int* __restrict__ bcnt, int* __restrict__ gcur,
                         int* __restrict__ bbase) {
    __shared__ int ts[256];
    int t = threadIdx.x;
    int v = bcnt[t];
    ts[t] = v; __syncthreads();
    for (int off = 1; off < 256; off <<= 1) {
        int xv = (t >= off) ? ts[t - off] : 0;
        __syncthreads();
        ts[t] += xv;
        __syncthreads();
    }
    int ex = ts[t] - v;
    gcur[t] = ex;
    bbase[t] = ex;
    if (t == 255) bbase[256] = ts[t];
}

// ------- phase 1: bucket edges by dst>>shift into pairs (dst,payload), coalesced -------
// blocks [0,FB): bucketing; blocks [FB,..): 256-bin bucket-count histogram of dst2>>sh2c
#define BK_CHUNK 4096
__global__ __launch_bounds__(256) void k_bucket_deg(
        const int* __restrict__ src, const int* __restrict__ dst, int E,
        const int* __restrict__ pk, int* __restrict__ gcur, uint2* __restrict__ pairs,
        int shift,
        const int* __restrict__ dst2, int E2d, int* __restrict__ bcnt, int sh2c, int FB) {
    __shared__ uint2 stage[BK_CHUNK];
    __shared__ unsigned short binOf[BK_CHUNK];
    __shared__ int hist[256], scanex[256], curb[256], baseb[256], sbuf[256];
    if ((int)blockIdx.x < FB) {
        int tid = threadIdx.x;
        int nchunk = (E + BK_CHUNK - 1) / BK_CHUNK;
        for (int c = blockIdx.x; c < nchunk; c += FB) {
            int base = c * BK_CHUNK;
            int cnt = min(BK_CHUNK, E - base);
            hist[tid] = 0;
            __syncthreads();
            int d[16], pl[16];
#pragma unroll
            for (int j = 0; j < 16; ++j) {
                int lo = j * 256 + tid;
                if (lo < cnt) {
                    int idx = base + lo;
                    d[j] = dst[idx];
                    int s = src[idx];
                    pl[j] = pk ? pk[s] : s;
                    atomicAdd(&hist[d[j] >> shift], 1);
                } else d[j] = -1;
            }
            __syncthreads();
            int v = hist[tid];
            sbuf[tid] = v;
            __syncthreads();
            for (int off = 1; off < 256; off <<= 1) {
                int xv = (tid >= off) ? sbuf[tid - off] : 0;
                __syncthreads();
                sbuf[tid] += xv;
                __syncthreads();
            }
            int ex = sbuf[tid] - v;
            scanex[tid] = ex;
            curb[tid] = ex;
            baseb[tid] = (v > 0) ? atomicAdd(&gcur[tid], v) : 0;
            __syncthreads();
#pragma unroll
            for (int j = 0; j < 16; ++j) {
                if (d[j] >= 0) {
                    int b = d[j] >> shift;
                    int pos = atomicAdd(&curb[b], 1);
                    stage[pos] = make_uint2((unsigned)d[j], (unsigned)pl[j]);
                    binOf[pos] = (unsigned short)b;
                }
            }
            __syncthreads();
            for (int s = tid; s < cnt; s += 256) {
                int b = binOf[s];
                pairs[baseb[b] + (s - scanex[b])] = stage[s];
            }
            __syncthreads();
        }
    } else if (bcnt) {
        int rb = blockIdx.x - FB;
        int T = (gridDim.x - FB) * blockDim.x;
        int tid2 = rb * blockDim.x + threadIdx.x;
        hist[threadIdx.x] = 0;
        __syncthreads();
        int G4 = E2d >> 2;
        for (int g = tid2; g < G4; g += T) {
            const int4 d4 = *reinterpret_cast<const int4*>(&dst2[g * 4]);
            atomicAdd(&hist[d4.x >> sh2c], 1);
            atomicAdd(&hist[d4.y >> sh2c], 1);
            atomicAdd(&hist[d4.z >> sh2c], 1);
            atomicAdd(&hist[d4.w >> sh2c], 1);
        }
        if (rb == 0 && threadIdx.x == 0) {
            for (int e = G4 * 4; e < E2d; ++e) atomicAdd(&bcnt[dst2[e] >> sh2c], 1);
        }
        __syncthreads();
        if (hist[threadIdx.x] > 0) atomicAdd(&bcnt[threadIdx.x], hist[threadIdx.x]);
    }
}

// ------- phase 2 (graph1): per-bucket LDS scatter using precomputed A -------
#define SC_CAP 28672
__global__ __launch_bounds__(256) void k_scatter(
        const uint2* __restrict__ pairs, const int* __restrict__ A,
        int* __restrict__ csr, int M, int shift, int nbk) {
    __shared__ int ldscsr[SC_CAP];
    __shared__ int lcur[2048];
    int tid = threadIdx.x;
    for (int b = blockIdx.x; b < nbk; b += gridDim.x) {
        int nodebase = b << shift;
        int nn = min(1 << shift, M - nodebase);
        int astart = A[nodebase];
        int aend = A[nodebase + nn];
        int cntE = aend - astart;
        for (int i = tid; i < nn; i += 256) lcur[i] = A[nodebase + i] - astart;
        __syncthreads();
        if (cntE <= SC_CAP) {
            for (int e = astart + tid; e < aend; e += 256) {
                uint2 p = pairs[e];
                int pos = atomicAdd(&lcur[(int)p.x - nodebase], 1);
                ldscsr[pos] = (int)p.y;
            }
            __syncthreads();
            for (int s = tid; s < cntE; s += 256) csr[astart + s] = ldscsr[s];
        } else {
            for (int e = astart + tid; e < aend; e += 256) {
                uint2 p = pairs[e];
                int pos = atomicAdd(&lcur[(int)p.x - nodebase], 1);
                csr[astart + pos] = (int)p.y;
            }
        }
        __syncthreads();
    }
}

// ------- phase 2 (graph2): derive per-node rowptr A in-block, then LDS scatter -------
__global__ __launch_bounds__(256) void k_scatter2(
        const uint2* __restrict__ pairs, const int* __restrict__ bbase,
        int* __restrict__ A, int* __restrict__ csr, int M, int shift, int nbk) {
    __shared__ int ldscsr[SC_CAP];
    __shared__ int lcnt[2048];
    __shared__ int sbuf[256];
    int tid = threadIdx.x;
    for (int b = blockIdx.x; b < nbk; b += gridDim.x) {
        int nodebase = b << shift;
        int nn = min(1 << shift, M - nodebase);
        int bstart = bbase[b], bend = bbase[b + 1];
        int cntE = bend - bstart;
        for (int i = tid; i < nn; i += 256) lcnt[i] = 0;
        __syncthreads();
        for (int e = bstart + tid; e < bend; e += 256)
            atomicAdd(&lcnt[(int)pairs[e].x - nodebase], 1);
        __syncthreads();
        // block exclusive scan of lcnt[0..nn) (8 elems/thread)
        int base8 = tid * 8;
        int v[8]; int s = 0;
#pragma unroll
        for (int j = 0; j < 8; ++j) { int idx = base8 + j; int val = (idx < nn) ? lcnt[idx] : 0; v[j] = val; s += val; }
        sbuf[tid] = s; __syncthreads();
        for (int off = 1; off < 256; off <<= 1) {
            int xv = (tid >= off) ? sbuf[tid - off] : 0;
            __syncthreads();
            sbuf[tid] += xv;
            __syncthreads();
        }
        int run = sbuf[tid] - s;
#pragma unroll
        for (int j = 0; j < 8; ++j) {
            int idx = base8 + j;
            if (idx < nn) {
                lcnt[idx] = run;
                A[nodebase + idx] = bstart + run;
            }
            run += v[j];
        }
        __syncthreads();
        if (tid == 0 && nodebase + nn == M) A[M] = bend;
        if (cntE <= SC_CAP) {
            for (int e = bstart + tid; e < bend; e += 256) {
                uint2 p = pairs[e];
                int pos = atomicAdd(&lcnt[(int)p.x - nodebase], 1);
                ldscsr[pos] = (int)p.y;
            }
            __syncthreads();
            for (int s2 = tid; s2 < cntE; s2 += 256) csr[bstart + s2] = ldscsr[s2];
        } else {
            for (int e = bstart + tid; e < bend; e += 256) {
                uint2 p = pairs[e];
                int pos = atomicAdd(&lcnt[(int)p.x - nodebase], 1);
                csr[bstart + pos] = (int)p.y;
            }
        }
        __syncthreads();
    }
}

// ------- conv1: wave/node, 4 edges/iter (16-lane groups), LDS table stride 68 -------
template <typename TO>
__global__ __launch_bounds__(256) void k_conv1(
        const int* __restrict__ x, const int* __restrict__ A, const int* __restrict__ csrpk,
        const float* __restrict__ H1pre, const float* __restrict__ b1,
        TO* __restrict__ out1, float* __restrict__ gsum, float* __restrict__ gsq,
        int N, int V) {
    __shared__ float Hl[101 * 68];
    __shared__ float redS[4][64], redQ[4][64];
    for (int i = threadIdx.x; i < V * 64; i += 256) {
        int row = i >> 6, col = i & 63;
        Hl[row * 68 + col] = H1pre[i];
    }
    __syncthreads();
    int wid = threadIdx.x >> 6, lane = threadIdx.x & 63;
    int g = lane >> 4, q = lane & 15;
    float4 b1v = *reinterpret_cast<const float4*>(&b1[4 * q]);
    float s0 = 0.f, s1 = 0.f, s2 = 0.f, s3 = 0.f;
    float q0 = 0.f, q1 = 0.f, q2 = 0.f, q3 = 0.f;
    for (int node = blockIdx.x * 4 + wid; node < N; node += gridDim.x * 4) {
        int rs0 = A[node], re = A[node + 1];
        float a0 = 0.f, a1 = 0.f, a2 = 0.f, a3 = 0.f;
        int pkcur = -1;
        { int e = rs0 + g; if (e < re) pkcur = csrpk[e]; }
        for (int c = rs0; c < re; c += 4) {
            int pknxt = -1;
            { int en = c + 4 + g; if (en < re) pknxt = csrpk[en]; }
            if (pkcur >= 0) {
                float dv = rsqrtf((float)(pkcur >> 7) + 1.0f);
                const float4 hv = *reinterpret_cast<const float4*>(&Hl[(pkcur & 127) * 68 + 4 * q]);
                a0 += dv * hv.x; a1 += dv * hv.y; a2 += dv * hv.z; a3 += dv * hv.w;
            }
            pkcur = pknxt;
        }
        a0 += __shfl_xor(a0, 16); a1 += __shfl_xor(a1, 16);
        a2 += __shfl_xor(a2, 16); a3 += __shfl_xor(a3, 16);
        a0 += __shfl_xor(a0, 32); a1 += __shfl_xor(a1, 32);
        a2 += __shfl_xor(a2, 32); a3 += __shfl_xor(a3, 32);
        float degf = (float)(re - rs0) + 1.0f;
        float sc = rsqrtf(degf), si = 1.0f / degf;
        const float4 sv = *reinterpret_cast<const float4*>(&Hl[x[node] * 68 + 4 * q]);
        float v0 = sc * a0 + sv.x * si + b1v.x;
        float v1 = sc * a1 + sv.y * si + b1v.y;
        float v2 = sc * a2 + sv.z * si + b1v.z;
        float v3 = sc * a3 + sv.w * si + b1v.w;
        if (g == 0) {
            st4(&out1[(ll)node * 64 + 4 * q], v0, v1, v2, v3);
            s0 += v0; s1 += v1; s2 += v2; s3 += v3;
            q0 += v0 * v0; q1 += v1 * v1; q2 += v2 * v2; q3 += v3 * v3;
        }
    }
    if (g == 0) {
        redS[wid][4 * q] = s0; redS[wid][4 * q + 1] = s1; redS[wid][4 * q + 2] = s2; redS[wid][4 * q + 3] = s3;
        redQ[wid][4 * q] = q0; redQ[wid][4 * q + 1] = q1; redQ[wid][4 * q + 2] = q2; redQ[wid][4 * q + 3] = q3;
    }
    __syncthreads();
    int t = threadIdx.x;
    if (t < 64) {
        atomicAdd(&gsum[t], redS[0][t] + redS[1][t] + redS[2][t] + redS[3][t]);
        atomicAdd(&gsq[t],  redQ[0][t] + redQ[1][t] + redQ[2][t] + redQ[3][t]);
    }
}

__global__ void k_norm_final(const float* __restrict__ gsum, const float* __restrict__ gsq,
                             const float* __restrict__ na, const float* __restrict__ ng,
                             const float* __restrict__ nbb,
                             float* __restrict__ A, float* __restrict__ B, int M) {
    int t = threadIdx.x;
    if (t < 64) {
        float invM = 1.0f / (float)M;
        float m = gsum[t] * invM;
        float a = na[t];
        float var = gsq[t] * invM - (2.0f * a - a * a) * m * m;
        float Av = ng[t] * rsqrtf(var + 1e-5f);
        A[t] = Av; B[t] = nbb[t] - Av * a * m;
    }
}

// ------- RS GEMM: W2 (64x128) held in VGPRs, readlane broadcast -------
template <typename TO>
__global__ __launch_bounds__(256, 2) void k_RS(
        const TO* __restrict__ out1, const float* __restrict__ A1, const float* __restrict__ B1,
        const float* __restrict__ W2, float* __restrict__ RS, int N) {
    int wid = threadIdx.x >> 6, lane = threadIdx.x & 63;
    float Al = A1[lane], Bl = B1[lane];
    float wx[64], wy[64];
#pragma unroll
    for (int k = 0; k < 64; ++k) {
        wx[k] = W2[k * 64 + lane];
        wy[k] = W2[(64 + k) * 64 + lane];
    }
    for (int node = blockIdx.x * 4 + wid; node < N; node += gridDim.x * 4) {
        float v = fmaxf(Al * ldf(&out1[(ll)node * 64 + lane]) + Bl, 0.f);
        float ar = 0.f, asv = 0.f;
#pragma unroll
        for (int k = 0; k < 64; ++k) {
            float hv = bcastf(v, k);
            ar  += hv * wx[k];
            asv += hv * wy[k];
        }
        RS[(ll)node * 128 + lane] = ar;
        RS[(ll)node * 128 + 64 + lane] = asv;
    }
}

// ------- gather: h2ps[l] = dinv2[l]*(R[p0]+S[p1]) bf16; deg2 from rowptr A -------
__global__ __launch_bounds__(256) void k_h2g(
        const int* __restrict__ pos1, const float* __restrict__ RS,
        const int* __restrict__ A, unsigned short* __restrict__ h2ps, int L) {
    int wv = (blockIdx.x * 4) + (threadIdx.x >> 6);
    int nw = gridDim.x * 4;
    int lane = threadIdx.x & 63;
    int g = lane >> 4, q = lane & 15;
    for (int base = wv * 4; base < L; base += nw * 4) {
        int l = base + g;
        if (l < L) {
            int p0 = pos1[2 * l], p1 = pos1[2 * l + 1];
            float dv = rsqrtf((float)(A[l + 1] - A[l]) + 1.0f);
            const float4 r = *reinterpret_cast<const float4*>(&RS[(ll)p0 * 128 + 4 * q]);
            const float4 s = *reinterpret_cast<const float4*>(&RS[(ll)p1 * 128 + 64 + 4 * q]);
            ushort4 o;
            o.x = f2b(dv * (r.x + s.x));
            o.y = f2b(dv * (r.y + s.y));
            o.z = f2b(dv * (r.z + s.z));
            o.w = f2b(dv * (r.w + s.w));
            *reinterpret_cast<ushort4*>(&h2ps[(ll)l * 64 + 4 * q]) = o;
        }
    }
}

// ------- conv2: 4 edges/iter, ushort4 row-gathers, rotate prefetch -------
template <typename TO>
__global__ __launch_bounds__(256) void k_conv2(
        const int* __restrict__ A, const int* __restrict__ csr,
        const unsigned short* __restrict__ h2ps, const float* __restrict__ b2,
        TO* __restrict__ out2, float* __restrict__ gsum, float* __restrict__ gsq, int L) {
    __shared__ float redS[4][64], redQ[4][64];
    int wid = threadIdx.x >> 6, lane = threadIdx.x & 63;
    int g = lane >> 4, q = lane & 15;
    float4 b2v = *reinterpret_cast<const float4*>(&b2[4 * q]);
    float s0 = 0.f, s1 = 0.f, s2 = 0.f, s3 = 0.f;
    float q0 = 0.f, q1 = 0.f, q2 = 0.f, q3 = 0.f;
    for (int node = blockIdx.x * 4 + wid; node < L; node += gridDim.x * 4) {
        int rs0 = A[node], re = A[node + 1];
        float a0 = 0.f, a1 = 0.f, a2 = 0.f, a3 = 0.f;
        ushort4 cur = make_ushort4(0, 0, 0, 0);
        { int e = rs0 + g; if (e < re) cur = *reinterpret_cast<const ushort4*>(&h2ps[(ll)csr[e] * 64 + 4 * q]); }
        for (int c = rs0; c < re; c += 4) {
            ushort4 nxt = make_ushort4(0, 0, 0, 0);
            { int en = c + 4 + g; if (en < re) nxt = *reinterpret_cast<const ushort4*>(&h2ps[(ll)csr[en] * 64 + 4 * q]); }
            a0 += b2f(cur.x); a1 += b2f(cur.y); a2 += b2f(cur.z); a3 += b2f(cur.w);
            cur = nxt;
        }
        a0 += __shfl_xor(a0, 16); a1 += __shfl_xor(a1, 16);
        a2 += __shfl_xor(a2, 16); a3 += __shfl_xor(a3, 16);
        a0 += __shfl_xor(a0, 32); a1 += __shfl_xor(a1, 32);
        a2 += __shfl_xor(a2, 32); a3 += __shfl_xor(a3, 32);
        float degf = (float)(re - rs0) + 1.0f;
        float sc = rsqrtf(degf);
        const ushort4 sv = *reinterpret_cast<const ushort4*>(&h2ps[(ll)node * 64 + 4 * q]);
        float v0 = sc * (a0 + b2f(sv.x)) + b2v.x;
        float v1 = sc * (a1 + b2f(sv.y)) + b2v.y;
        float v2 = sc * (a2 + b2f(sv.z)) + b2v.z;
        float v3 = sc * (a3 + b2f(sv.w)) + b2v.w;
        if (g == 0) {
            st4(&out2[(ll)node * 64 + 4 * q], v0, v1, v2, v3);
            s0 += v0; s1 += v1; s2 += v2; s3 += v3;
            q0 += v0 * v0; q1 += v1 * v1; q2 += v2 * v2; q3 += v3 * v3;
        }
    }
    if (g == 0) {
        redS[wid][4 * q] = s0; redS[wid][4 * q + 1] = s1; redS[wid][4 * q + 2] = s2; redS[wid][4 * q + 3] = s3;
        redQ[wid][4 * q] = q0; redQ[wid][4 * q + 1] = q1; redQ[wid][4 * q + 2] = q2; redQ[wid][4 * q + 3] = q3;
    }
    __syncthreads();
    int t = threadIdx.x;
    if (t < 64) {
        atomicAdd(&gsum[t], redS[0][t] + redS[1][t] + redS[2][t] + redS[3][t]);
        atomicAdd(&gsq[t],  redQ[0][t] + redQ[1][t] + redQ[2][t] + redQ[3][t]);
    }
}

// ------- fused norm2+relu+prediction dot -------
template <typename TO>
__global__ void k_final(const int* __restrict__ pos2, const TO* __restrict__ out2,
                        const float* __restrict__ A, const float* __restrict__ B,
                        const float* __restrict__ pW, const float* __restrict__ pb,
                        float* __restrict__ out, int P) {
    int wid = threadIdx.x >> 6, lane = threadIdx.x & 63;
    int p = blockIdx.x * 4 + wid;
    if (p >= P) return;
    int i = pos2[p];
    float v = ldf(&out2[(ll)i * 64 + lane]);
    v = fmaxf(A[lane] * v + B[lane], 0.f) * pW[lane];
    for (int off = 32; off; off >>= 1) v += __shfl_xor(v, off);
    if (lane == 0) out[p] = v + pb[0];
}

// smallest shift so that (M-1)>>shift < nbk
static inline int bucket_shift(int M, int nbk) {
    int s = 0;
    while (((M - 1) >> s) >= nbk) ++s;
    return s;
}

// ---------------- templated pipeline ----------------
template <typename TO>
static void run_pipeline(const int* x, const int* edge1, const int* edge2,
                         const int* pos1, const int* pos2,
                         const float* emb, const float* n0a, const float* n0g, const float* n0b,
                         const float* W1, const float* b1,
                         const float* n1a, const float* n1g, const float* n1b,
                         const float* W2, const float* b2,
                         const float* n2a, const float* n2g, const float* n2b,
                         const float* pW, const float* pb,
                         int N, int E1, int E2, int L, int P, int V,
                         int* cnt, float* stats, float* H1pre, int* bsum, int* gcur,
                         int* pk, int* deg, int* A, int* csr,
                         void* region1, void* region2,
                         float* d_out, hipStream_t stream) {
    TO* out1 = (TO*)region1;
    unsigned short* h2ps = (unsigned short*)region1;   // aliases out1 (out1 dead by then)
    float* RS = (float*)region2;
    TO* out2  = (TO*)region2;                          // aliases RS (RS dead by then)
    uint2* pairs = (uint2*)region2;                    // phase-1 buffer, dead before k_RS

    int* bcnt  = gcur + 256;   // 256 bucket counts for graph2
    int* bbase = gcur + 512;   // 257 bucket bases for graph2

    float* sum1 = stats + 128; float* sq1 = stats + 192;
    float* A1   = stats + 256; float* B1  = stats + 320;
    float* sum2 = stats + 384; float* sq2 = stats + 448;
    float* A2   = stats + 512; float* B2  = stats + 576;

    int sh1 = bucket_shift(N, 256);
    int nbk1 = cdiv(N, 1 << sh1);
    int sh2 = bucket_shift(L, 256);
    int nbk2 = cdiv(L, 1 << sh2);

    hipMemsetAsync(cnt,   0, (size_t)V * 4, stream);
    hipMemsetAsync(stats, 0, 640 * 4, stream);
    hipMemsetAsync(deg,   0, (size_t)N * 4, stream);
    hipMemsetAsync(bcnt,  0, 256 * 4, stream);

    // ---- fused: x-histogram | deg1 (ILP4) ----
    k_hist_deg<<<256 + 1024, 256, 0, stream>>>(x, N, cnt, V, edge1 + E1, E1, deg, 256);
    k_table<<<1, 256, 0, stream>>>(cnt, emb, n0a, n0g, n0b, W1, H1pre, N, V);
    k_pack<<<cdiv(N, 256), 256, 0, stream>>>(x, deg, N, pk);

    int nb1 = cdiv(N, 2048);
    k_scan1<<<nb1, 256, 0, stream>>>(deg, A, bsum, N);
    k_scan2<<<1, 256, 0, stream>>>(bsum, nb1);
    k_scan3<<<512, 256, 0, stream>>>(A, bsum, N, nb1);

    // ---- graph1 fill: bucket (fused w/ graph2 bucket-count) + LDS scatter ----
    k_gcur<<<1, 256, 0, stream>>>(A, N, sh1, nbk1, gcur);
    k_bucket_deg<<<2048, 256, 0, stream>>>(edge1, edge1 + E1, E1, pk, gcur, pairs, sh1,
                                           edge2 + E2, E2, bcnt, sh2, 1024);
    k_scatter<<<nbk1, 256, 0, stream>>>(pairs, A, csr, N, sh1, nbk1);
    k_conv1<TO><<<2048, 256, 0, stream>>>(x, A, csr, H1pre, b1, out1, sum1, sq1, N, V);
    k_norm_final<<<1, 64, 0, stream>>>(sum1, sq1, n1a, n1g, n1b, A1, B1, N);

    // ---- graph2 fill: bucket bases from counts, bucket, scatter (derives A) ----
    k_scan_b<<<1, 256, 0, stream>>>(bcnt, gcur, bbase);
    k_bucket_deg<<<2048, 256, 0, stream>>>(edge2, edge2 + E2, E2, nullptr, gcur, pairs, sh2,
                                           nullptr, 0, nullptr, 0, 2048);
    k_scatter2<<<nbk2, 256, 0, stream>>>(pairs, bbase, A, csr, L, sh2, nbk2);

    k_RS<TO><<<1024, 256, 0, stream>>>(out1, A1, B1, W2, RS, N);
    k_h2g<<<2048, 256, 0, stream>>>(pos1, RS, A, h2ps, L);
    k_conv2<TO><<<2048, 256, 0, stream>>>(A, csr, h2ps, b2, out2, sum2, sq2, L);

    k_norm_final<<<1, 64, 0, stream>>>(sum2, sq2, n2a, n2g, n2b, A2, B2, L);
    k_final<TO><<<cdiv(P, 4), 256, 0, stream>>>(pos2, out2, A2, B2, pW, pb, d_out, P);
}

extern "C" void kernel_launch(void* const* d_in, const int* in_sizes, int n_in,
                              void* d_out, int out_size, void* d_ws, size_t ws_size,
                              hipStream_t stream) {
    const int*   x     = (const int*)d_in[0];
    const int*   edge1 = (const int*)d_in[1];
    const int*   edge2 = (const int*)d_in[2];
    const int*   pos1  = (const int*)d_in[3];
    const int*   pos2  = (const int*)d_in[4];
    const float* emb   = (const float*)d_in[5];
    const float* n0a   = (const float*)d_in[6];
    const float* n0g   = (const float*)d_in[7];
    const float* n0b   = (const float*)d_in[8];
    const float* W1    = (const float*)d_in[9];
    const float* b1    = (const float*)d_in[10];
    const float* n1a   = (const float*)d_in[11];
    const float* n1g   = (const float*)d_in[12];
    const float* n1b   = (const float*)d_in[13];
    const float* W2    = (const float*)d_in[14];
    const float* b2    = (const float*)d_in[15];
    const float* n2a   = (const float*)d_in[16];
    const float* n2g   = (const float*)d_in[17];
    const float* n2b   = (const float*)d_in[18];
    const float* pW    = (const float*)d_in[19];
    const float* pb    = (const float*)d_in[20];

    int N  = in_sizes[0];
    int E1 = in_sizes[1] / 2;
    int E2 = in_sizes[2] / 2;
    int L  = in_sizes[3] / 2;
    int P  = in_sizes[4];
    int V  = in_sizes[5] / 64;
    int Emax = (E1 > E2) ? E1 : E2;
    (void)n_in; (void)out_size;

    auto a256 = [](size_t s) { return (s + 255) & ~(size_t)255; };
    auto mx = [](size_t a, size_t b) { return a > b ? a : b; };

    size_t fixed = a256((size_t)V * 4) + a256(640 * 4) + a256((size_t)V * 64 * 4) +
                   a256(1040 * 4) + a256(1024 * 4) + a256((size_t)N * 4) +
                   a256((size_t)(L + 1) * 4) + a256((size_t)(L + 1) * 4) +
                   a256((size_t)Emax * 4);
    size_t r1_pri = a256(mx((size_t)N * 64 * 4, (size_t)L * 64 * 2));
    size_t r2_pri = a256(mx(mx((size_t)N * 128 * 4, (size_t)L * 64 * 4), (size_t)Emax * 8));
    size_t r1_fb  = a256(mx((size_t)N * 64 * 2, (size_t)L * 64 * 2));
    size_t r2_fb  = a256(mx((size_t)N * 128 * 4, (size_t)Emax * 8));
    size_t need_pri = fixed + r1_pri + r2_pri;
    bool primary = (ws_size >= need_pri);
    size_t r1 = primary ? r1_pri : r1_fb;
    size_t r2 = primary ? r2_pri : r2_fb;

    char* w = (char*)d_ws;
    size_t off = 0;
    auto alloc = [&](size_t bytes) { void* p = w + off; off += (bytes + 255) & ~(size_t)255; return p; };

    int*   cnt   = (int*)alloc((size_t)V * 4);
    float* stats = (float*)alloc(640 * 4);
    float* H1pre = (float*)alloc((size_t)V * 64 * 4);
    int*   bsum  = (int*)alloc(1040 * 4);
    int*   gcur  = (int*)alloc(1024 * 4);
    int*   pk    = (int*)alloc((size_t)N * 4);
    int*   deg   = (int*)alloc((size_t)(L + 1) * 4);
    int*   A     = (int*)alloc((size_t)(L + 1) * 4);
    int*   csr   = (int*)alloc((size_t)Emax * 4);
    void*  region1 = alloc(r1);
    void*  region2 = alloc(r2);

    if (primary) {
        run_pipeline<float>(x, edge1, edge2, pos1, pos2, emb, n0a, n0g, n0b,
                            W1, b1, n1a, n1g, n1b, W2, b2, n2a, n2g, n2b, pW, pb,
                            N, E1, E2, L, P, V, cnt, stats, H1pre, bsum, gcur,
                            pk, deg, A, csr, region1, region2,
                            (float*)d_out, stream);
    } else {
        run_pipeline<__hip_bfloat16>(x, edge1, edge2, pos1, pos2, emb, n0a, n0g, n0b,
                            W1, b1, n1a, n1g, n1b, W2, b2, n2a, n2g, n2b, pW, pb,
                            N, E1, E2, L, P, V, cnt, stats, H1pre, bsum, gcur,
                            pk, deg, A, csr, region1, region2,
                            (float*)d_out, stream);
    }
}